// Round 4
// baseline (3564.114 us; speedup 1.0000x reference)
//
#include <hip/hip_runtime.h>
#include <hip/hip_bf16.h>
#include <math.h>

typedef __bf16 bf16x8 __attribute__((ext_vector_type(8)));
typedef float f32x4 __attribute__((ext_vector_type(4)));

#define NPTS 8192
#define SGRP 512
#define KNBR 32
#define CCH 384
#define LDSP 392   // padded ushort row stride for [l][c] LDS tiles

static __device__ __forceinline__ unsigned short f2b(float f) {
  union { float f; unsigned u; } v; v.f = f;
  return (unsigned short)((v.u + 0x7fffu + ((v.u >> 16) & 1u)) >> 16);
}
static __device__ __forceinline__ float b2f(unsigned short u) {
  union { unsigned u; float f; } v; v.u = ((unsigned)u) << 16;
  return v.f;
}
static __device__ __forceinline__ unsigned pk2(float a, float b) {
  return (unsigned)f2b(a) | ((unsigned)f2b(b) << 16);
}

// fmax with DPP-shifted self (identity 0 for invalid lanes: distances are >= 0)
#define DPPMAX(v, ctrl) \
  fmaxf((v), __int_as_float(__builtin_amdgcn_update_dpp(0, __float_as_int(v), (ctrl), 0xf, 0xf, false)))

// ---------------- weight folding: bn(conv(x)) = (W*s)x + (b*s+bb) ----------------
struct FoldArgs {
  const float *W, *b, *g, *bb;
  unsigned short* Wd;
  float* bd;
};
__global__ void fold4_bf16(FoldArgs a0, FoldArgs a1, FoldArgs a2, FoldArgs a3) {
  FoldArgs a = (blockIdx.y == 0) ? a0 : (blockIdx.y == 1) ? a1 : (blockIdx.y == 2) ? a2 : a3;
  int o = blockIdx.x;
  float sc = a.g[o] / sqrtf(1.0f + 1e-5f);
  for (int c = threadIdx.x; c < CCH; c += blockDim.x)
    a.Wd[o * CCH + c] = f2b(a.W[o * CCH + c] * sc);
  if (threadIdx.x == 0) a.bd[o] = a.b[o] * sc + a.bb[o];
}
__global__ void fold_w_f32(const float* __restrict__ W, const float* __restrict__ b,
                           const float* __restrict__ g, const float* __restrict__ bb,
                           float* __restrict__ Wd, float* __restrict__ bd, int Cin) {
  int o = blockIdx.x;
  float sc = g[o] / sqrtf(1.0f + 1e-5f);
  for (int c = threadIdx.x; c < Cin; c += blockDim.x)
    Wd[o * Cin + c] = W[o * Cin + c] * sc;
  if (threadIdx.x == 0) bd[o] = b[o] * sc + bb[o];
}

// ---------------- FPS v4: 4 CUs per batch, device-scope atomic handshake ----------
// 32 blocks x 256 threads; block (b,w) owns points [w*2048, w*2048+2048) of batch b.
// Contiguous ownership => lane order == index order; strict > everywhere => numpy
// first-max tie semantics. Winner coords travel through the reduction (no LDS
// broadcast read on the critical path). Pub slots are double-buffered by step
// parity; handshake back-pressure makes reuse race-free. pub must be zeroed per
// launch (hipMemsetAsync) so graph replays never see stale seq values.
__global__ __launch_bounds__(256) void fps_kernel(const float* __restrict__ xyz,
                                                  int* __restrict__ cIdx,
                                                  unsigned long long* __restrict__ pub) {
  #pragma clang fp contract(off)
  __shared__ uint4 slotA[2][4];
  __shared__ unsigned slotB[2][4];
  const int tid = threadIdx.x, lane = tid & 63, wid = tid >> 6;
  const int blk = blockIdx.x;
  const int b = blk >> 2, w = blk & 3;
  const float* xb = xyz + (size_t)b * NPTS * 3;
  const int base = w * 2048;

  float X[8], Y[8], Z[8], D[8];
  {
    const float4* src = (const float4*)(xb + (size_t)base * 3) + tid * 6;
    float tmp[24];
    #pragma unroll
    for (int q = 0; q < 6; ++q) {
      float4 t = src[q];
      tmp[q * 4 + 0] = t.x; tmp[q * 4 + 1] = t.y;
      tmp[q * 4 + 2] = t.z; tmp[q * 4 + 3] = t.w;
    }
    #pragma unroll
    for (int j = 0; j < 8; ++j) {
      X[j] = tmp[j * 3 + 0]; Y[j] = tmp[j * 3 + 1]; Z[j] = tmp[j * 3 + 2];
      D[j] = __builtin_inff();
    }
  }
  if (w == 0 && tid == 0) cIdx[b * SGRP] = 0;
  float cx = xb[0], cy = xb[1], cz = xb[2];

  for (int step = 1; step < SGRP; ++step) {
    const int par = step & 1;
    float bv = -1.0f; int bi = 0; float bx = 0.f, by = 0.f, bz = 0.f;
    #pragma unroll
    for (int j = 0; j < 8; ++j) {
      float dx = X[j] - cx, dy = Y[j] - cy, dz = Z[j] - cz;
      float d = (dx * dx + dy * dy) + dz * dz;   // contract off: numpy ulp-exact
      float nd = fminf(D[j], d);
      D[j] = nd;
      if (nd > bv) { bv = nd; bi = base + tid * 8 + j; bx = X[j]; by = Y[j]; bz = Z[j]; }
    }
    // wave prefix-max (value only), pure VALU
    float m = bv;
    m = DPPMAX(m, 0x111);   // row_shr:1
    m = DPPMAX(m, 0x112);   // row_shr:2
    m = DPPMAX(m, 0x114);   // row_shr:4
    m = DPPMAX(m, 0x118);   // row_shr:8
    m = DPPMAX(m, 0x142);   // row_bcast:15
    m = DPPMAX(m, 0x143);   // row_bcast:31
    float wmax = __uint_as_float(__builtin_amdgcn_readlane(__float_as_uint(m), 63));
    unsigned long long msk = __ballot(bv == wmax);
    int srcLane = (int)__builtin_ctzll(msk);          // lowest lane == lowest index
    unsigned wbi = (unsigned)__builtin_amdgcn_readlane(bi, srcLane);
    unsigned wx = (unsigned)__builtin_amdgcn_readlane(__float_as_int(bx), srcLane);
    unsigned wy = (unsigned)__builtin_amdgcn_readlane(__float_as_int(by), srcLane);
    unsigned wz = (unsigned)__builtin_amdgcn_readlane(__float_as_int(bz), srcLane);
    if (lane == 0) {
      slotA[par][wid] = make_uint4(__float_as_uint(wmax), wbi, wx, wy);
      slotB[par][wid] = wz;
    }
    __syncthreads();
    // block combine (ascending wave id, strict > => lowest index on ties)
    float kv = -1.0f; unsigned ki = 0, kx = 0, ky = 0, kz = 0;
    #pragma unroll
    for (int w4 = 0; w4 < 4; ++w4) {
      uint4 s = slotA[par][w4];
      float fv = __uint_as_float(s.x);
      if (fv > kv) { kv = fv; ki = s.y; kx = s.z; ky = s.w; kz = slotB[par][w4]; }
    }
    // publish block winner (device-scope: pubs cross XCDs)
    if (tid == 0) {
      unsigned long long* P = pub + (((size_t)par * 8 + b) * 4 + w) * 3;
      __hip_atomic_store(P + 0, (((unsigned long long)__float_as_uint(kv)) << 32) | ki,
                         __ATOMIC_RELAXED, __HIP_MEMORY_SCOPE_AGENT);
      __hip_atomic_store(P + 1, ((unsigned long long)kx) | (((unsigned long long)ky) << 32),
                         __ATOMIC_RELAXED, __HIP_MEMORY_SCOPE_AGENT);
      __hip_atomic_store(P + 2, ((unsigned long long)kz) | (((unsigned long long)(unsigned)step) << 32),
                         __ATOMIC_RELEASE, __HIP_MEMORY_SCOPE_AGENT);
    }
    // spin-combine all 4 blocks' pubs (ascending block id => lowest index on ties)
    float gv = -1.0f; unsigned gi = 0; float nx = 0.f, ny = 0.f, nz = 0.f;
    #pragma unroll 1
    for (int pw = 0; pw < 4; ++pw) {
      const unsigned long long* P = pub + (((size_t)par * 8 + b) * 4 + pw) * 3;
      unsigned long long zsv;
      do {
        zsv = __hip_atomic_load(P + 2, __ATOMIC_ACQUIRE, __HIP_MEMORY_SCOPE_AGENT);
      } while ((unsigned)(zsv >> 32) != (unsigned)step);
      unsigned long long vi = __hip_atomic_load(P + 0, __ATOMIC_RELAXED, __HIP_MEMORY_SCOPE_AGENT);
      unsigned long long xy = __hip_atomic_load(P + 1, __ATOMIC_RELAXED, __HIP_MEMORY_SCOPE_AGENT);
      float fv = __uint_as_float((unsigned)(vi >> 32));
      if (fv > gv) {
        gv = fv; gi = (unsigned)vi;
        nx = __uint_as_float((unsigned)xy); ny = __uint_as_float((unsigned)(xy >> 32));
        nz = __uint_as_float((unsigned)zsv);
      }
    }
    if (w == 0 && tid == 0) cIdx[b * SGRP + step] = (int)gi;
    cx = nx; cy = ny; cz = nz;
  }
}

// ---------------- kNN v2: cached per-thread min, winner-only rescan, 1 barrier/iter ----
__global__ __launch_bounds__(256) void knn_kernel(const float* __restrict__ xyz,
                                                  const int* __restrict__ cIdx,
                                                  float* __restrict__ nbrDiff,
                                                  float* __restrict__ ctrW,
                                                  float* __restrict__ partials) {
  #pragma clang fp contract(off)
  __shared__ unsigned long long keyBuf[4];
  __shared__ int winners[KNBR];
  const int cid = blockIdx.x;
  const int b = cid >> 9;
  const int tid = threadIdx.x;
  const float* xb = xyz + (size_t)b * NPTS * 3;
  const int cI = cIdx[cid];
  const float cx = xb[cI * 3], cy = xb[cI * 3 + 1], cz = xb[cI * 3 + 2];
  const float cs = (cx * cx + cy * cy) + cz * cz;

  float d2[32];
  float mv = __builtin_inff(); int mi = 0;
  #pragma unroll
  for (int j = 0; j < 32; ++j) {
    int p = tid + (j << 8);
    float x = xb[p * 3], y = xb[p * 3 + 1], z = xb[p * 3 + 2];
    float ps = (x * x + y * y) + z * z;
    float dot = (cx * x + cy * y) + cz * z;
    d2[j] = (cs + ps) - 2.0f * dot;
    if (d2[j] < mv) { mv = d2[j]; mi = p; }   // strict <: lowest p on tie
  }
  if (tid < 4) keyBuf[tid] = 0xFFFFFFFFFFFFFFFFull;
  __syncthreads();

  for (int it = 0; it < KNBR; ++it) {
    if (tid == 0) keyBuf[(it + 2) & 3] = 0xFFFFFFFFFFFFFFFFull;
    float bv = mv; int bi = mi;
    #pragma unroll
    for (int s = 1; s < 64; s <<= 1) {
      float ov = __shfl_xor(bv, s); int oi = __shfl_xor(bi, s);
      if (ov < bv || (ov == bv && oi < bi)) { bv = ov; bi = oi; }
    }
    if ((tid & 63) == 0) {
      unsigned u = __float_as_uint(bv);
      unsigned m = u ^ (unsigned)(((int)u >> 31) | 0x80000000);   // monotone float->uint
      unsigned long long key = (((unsigned long long)m) << 32) | (unsigned long long)bi;
      atomicMin(&keyBuf[it & 3], key);
    }
    __syncthreads();
    unsigned long long k = keyBuf[it & 3];
    int wi = (int)(k & 0x1FFFu);
    if (tid == 0) winners[it] = wi;
    if (tid == (wi & 255)) {     // only the owner rescans its 32 values
      #pragma unroll
      for (int j = 0; j < 32; ++j)
        if (wi == tid + (j << 8)) d2[j] = __builtin_inff();
      mv = __builtin_inff(); mi = 0;
      #pragma unroll
      for (int j = 0; j < 32; ++j)
        if (d2[j] < mv) { mv = d2[j]; mi = tid + (j << 8); }
    }
  }
  __syncthreads();

  // gather diffs + per-center stats partials
  float sum = 0.f, sq = 0.f;
  if (tid < KNBR) {
    int w = winners[tid];
    float dx = xb[w * 3] - cx, dy = xb[w * 3 + 1] - cy, dz = xb[w * 3 + 2] - cz;
    size_t o = ((size_t)cid * KNBR + tid) * 3;
    nbrDiff[o + 0] = dx; nbrDiff[o + 1] = dy; nbrDiff[o + 2] = dz;
    sum = (dx + dy) + dz;
    sq = (dx * dx + dy * dy) + dz * dz;
  }
  if (tid < 64) {
    #pragma unroll
    for (int s = 1; s < 64; s <<= 1) { sum += __shfl_xor(sum, s); sq += __shfl_xor(sq, s); }
    if (tid == 0) { partials[cid * 2] = sum; partials[cid * 2 + 1] = sq; }
  }
  if (tid < 3) ctrW[(size_t)cid * 3 + tid] = xb[cI * 3 + tid];
}

// ---------------- per-batch std (ddof=1), deterministic fp64 tree ----------------
__global__ __launch_bounds__(256) void std_kernel(const float* __restrict__ partials,
                                                  float* __restrict__ stdv) {
  __shared__ double sd[256], sq[256];
  const int b = blockIdx.x, t = threadIdx.x;
  int i0 = (b * 512 + t) * 2;
  sd[t] = (double)partials[i0] + (double)partials[i0 + 512];
  sq[t] = (double)partials[i0 + 1] + (double)partials[i0 + 513];
  for (int st = 128; st > 0; st >>= 1) {
    __syncthreads();
    if (t < st) { sd[t] += sd[t + st]; sq[t] += sq[t + st]; }
  }
  if (t == 0) {
    double n = (double)(SGRP * KNBR * 3);
    double mean = sd[0] / n;
    double var = (sq[0] - sd[0] * mean) / (n - 1.0);
    stdv[b] = (float)sqrt(var);
  }
}

// ---------------- fused group MLP (t-net + pre res_block + maxpool) ----------------
// one block = 4 groups (128 l-columns), 8 waves, MFMA 16x16x32 bf16
static __device__ __forceinline__ void gemm_half(const unsigned short* __restrict__ W,
                                                 const unsigned short* ht,
                                                 int oBase, int n0, int r16, int g4,
                                                 f32x4 acc[3][4]) {
  for (int ks = 0; ks < 12; ++ks) {
    const int kOff = ks * 32 + g4 * 8;
    bf16x8 a[3], bb[4];
    #pragma unroll
    for (int i = 0; i < 3; ++i)
      a[i] = *(const bf16x8*)(W + (size_t)(oBase + i * 16 + r16) * CCH + kOff);
    #pragma unroll
    for (int j = 0; j < 4; ++j)
      bb[j] = *(const bf16x8*)(ht + (n0 + j * 16 + r16) * LDSP + kOff);
    #pragma unroll
    for (int i = 0; i < 3; ++i) {
      #pragma unroll
      for (int j = 0; j < 4; ++j)
        acc[i][j] = __builtin_amdgcn_mfma_f32_16x16x32_bf16(a[i], bb[j], acc[i][j], 0, 0, 0);
    }
  }
}

__global__ __launch_bounds__(512) void group_mlp_kernel(
    const float* __restrict__ alpha, const float* __restrict__ beta,
    const float* __restrict__ WtF, const float* __restrict__ btF,
    const unsigned short* __restrict__ W1, const float* __restrict__ b1,
    const unsigned short* __restrict__ W2, const float* __restrict__ b2,
    const float* __restrict__ nbrDiff, const float* __restrict__ ctrW,
    const float* __restrict__ stdv, unsigned short* __restrict__ feat) {
  __shared__ unsigned short ht[128 * LDSP];
  __shared__ float xtw[128 * 8];
  __shared__ float wtl[CCH * 6];
  __shared__ float btl[CCH];

  const int tid = threadIdx.x;
  const int lane = tid & 63, wid = tid >> 6;
  const int r16 = lane & 15, g4 = lane >> 4;
  const int bid = blockIdx.x;
  const int b = bid >> 7;
  const int sBase = (bid & 127) << 2;

  for (int i = tid; i < CCH * 6; i += 512) wtl[i] = WtF[i];
  for (int i = tid; i < CCH; i += 512) btl[i] = btF[i];

  const float inv = 1.0f / (stdv[b] + 1e-5f);
  if (tid < 128) {
    int g = tid >> 5, kk = tid & 31;
    int cid = b * SGRP + sBase + g;
    const float* nb = nbrDiff + ((size_t)cid * KNBR + kk) * 3;
    const float* cc = ctrW + (size_t)cid * 3;
    #pragma unroll
    for (int c = 0; c < 3; ++c) {
      xtw[tid * 8 + c] = alpha[c] * (nb[c] * inv) + beta[c];
      xtw[tid * 8 + 3 + c] = cc[c];
    }
  }
  __syncthreads();

  // conv1 (t-net, K=6) -> h0 bf16 into ht[l][o]
  {
    int l = tid & 127, oi = tid >> 7;
    float xv[6];
    #pragma unroll
    for (int c = 0; c < 6; ++c) xv[c] = xtw[l * 8 + c];
    for (int j = 0; j < 96; ++j) {
      int o = oi * 96 + j;
      float v = btl[o];
      #pragma unroll
      for (int c = 0; c < 6; ++c) v += wtl[o * 6 + c] * xv[c];
      ht[l * LDSP + o] = f2b(fmaxf(v, 0.0f));
    }
  }
  __syncthreads();

  const int oBase = wid * 48;

  // conv2: h1 = relu(W1 h0 + b1), overwrite ht by l-halves (disjoint rows)
  for (int half = 0; half < 2; ++half) {
    const int n0 = half * 64;
    f32x4 acc[3][4];
    #pragma unroll
    for (int i = 0; i < 3; ++i) {
      #pragma unroll
      for (int j = 0; j < 4; ++j) acc[i][j] = (f32x4){0.f, 0.f, 0.f, 0.f};
    }
    gemm_half(W1, ht, oBase, n0, r16, g4, acc);
    __syncthreads();   // all waves done reading this half's h0 rows
    #pragma unroll
    for (int i = 0; i < 3; ++i) {
      int o4 = oBase + i * 16 + g4 * 4;
      float bs0 = b1[o4], bs1 = b1[o4 + 1], bs2 = b1[o4 + 2], bs3 = b1[o4 + 3];
      #pragma unroll
      for (int j = 0; j < 4; ++j) {
        int row = n0 + j * 16 + r16;
        unsigned u0 = pk2(fmaxf(acc[i][j][0] + bs0, 0.f), fmaxf(acc[i][j][1] + bs1, 0.f));
        unsigned u1 = pk2(fmaxf(acc[i][j][2] + bs2, 0.f), fmaxf(acc[i][j][3] + bs3, 0.f));
        *(uint2*)(ht + row * LDSP + o4) = make_uint2(u0, u1);
      }
    }
    __syncthreads();
  }

  // conv3 + bias + residual(h0 recomputed) + relu + maxpool over K=32
  for (int half = 0; half < 2; ++half) {
    const int n0 = half * 64;
    f32x4 acc[3][4];
    #pragma unroll
    for (int i = 0; i < 3; ++i) {
      #pragma unroll
      for (int j = 0; j < 4; ++j) acc[i][j] = (f32x4){0.f, 0.f, 0.f, 0.f};
    }
    gemm_half(W2, ht, oBase, n0, r16, g4, acc);

    float bias2[3][4];
    #pragma unroll
    for (int i = 0; i < 3; ++i) {
      int o4 = oBase + i * 16 + g4 * 4;
      #pragma unroll
      for (int r = 0; r < 4; ++r) bias2[i][r] = b2[o4 + r];
    }
    float mx[3][2][4];
    #pragma unroll
    for (int i = 0; i < 3; ++i) {
      #pragma unroll
      for (int gg = 0; gg < 2; ++gg) {
        #pragma unroll
        for (int r = 0; r < 4; ++r) mx[i][gg][r] = 0.f;   // values are relu'd (>=0)
      }
    }
    #pragma unroll
    for (int j = 0; j < 4; ++j) {
      int l = n0 + j * 16 + r16;
      float xv[6];
      #pragma unroll
      for (int c = 0; c < 6; ++c) xv[c] = xtw[l * 8 + c];
      #pragma unroll
      for (int i = 0; i < 3; ++i) {
        int o4 = oBase + i * 16 + g4 * 4;
        #pragma unroll
        for (int r = 0; r < 4; ++r) {
          float h0 = btl[o4 + r];
          #pragma unroll
          for (int c = 0; c < 6; ++c) h0 += wtl[(o4 + r) * 6 + c] * xv[c];
          h0 = fmaxf(h0, 0.f);
          float v = fmaxf(acc[i][j][r] + bias2[i][r] + h0, 0.f);
          mx[i][j >> 1][r] = fmaxf(mx[i][j >> 1][r], v);
        }
      }
    }
    #pragma unroll
    for (int i = 0; i < 3; ++i) {
      #pragma unroll
      for (int gg = 0; gg < 2; ++gg) {
        float m0 = mx[i][gg][0], m1 = mx[i][gg][1], m2 = mx[i][gg][2], m3 = mx[i][gg][3];
        #pragma unroll
        for (int s = 1; s < 16; s <<= 1) {
          m0 = fmaxf(m0, __shfl_xor(m0, s));
          m1 = fmaxf(m1, __shfl_xor(m1, s));
          m2 = fmaxf(m2, __shfl_xor(m2, s));
          m3 = fmaxf(m3, __shfl_xor(m3, s));
        }
        if (r16 == 0) {
          int sIdx = sBase + half * 2 + gg;
          size_t fi = ((size_t)(b * SGRP + sIdx)) * CCH + oBase + i * 16 + g4 * 4;
          *(uint2*)(feat + fi) = make_uint2(pk2(m0, m1), pk2(m2, m3));
        }
      }
    }
  }
}

// ---------------- pos res_block on feat (B,384,512) + final transpose to (B,S,C) fp32 ----------------
__global__ __launch_bounds__(256) void pos_kernel(const unsigned short* __restrict__ feat,
                                                  const unsigned short* __restrict__ Wp1,
                                                  const float* __restrict__ bp1,
                                                  const unsigned short* __restrict__ Wp2,
                                                  const float* __restrict__ bp2,
                                                  float* __restrict__ out) {
  __shared__ unsigned short h1[16 * LDSP];
  const int tid = threadIdx.x;
  const int lane = tid & 63, wid = tid >> 6;
  const int r16 = lane & 15, g4 = lane >> 4;
  const int bid = blockIdx.x;
  const int b = bid >> 5;
  const int s0 = (bid & 31) << 4;
  const size_t rowBase = ((size_t)(b * SGRP + s0 + r16)) * CCH;

  f32x4 acc[6];
  #pragma unroll
  for (int i = 0; i < 6; ++i) acc[i] = (f32x4){0.f, 0.f, 0.f, 0.f};
  for (int ks = 0; ks < 12; ++ks) {
    const int kOff = ks * 32 + g4 * 8;
    bf16x8 bfr = *(const bf16x8*)(feat + rowBase + kOff);
    #pragma unroll
    for (int i = 0; i < 6; ++i) {
      bf16x8 a = *(const bf16x8*)(Wp1 + (size_t)(wid * 96 + i * 16 + r16) * CCH + kOff);
      acc[i] = __builtin_amdgcn_mfma_f32_16x16x32_bf16(a, bfr, acc[i], 0, 0, 0);
    }
  }
  #pragma unroll
  for (int i = 0; i < 6; ++i) {
    int o4 = wid * 96 + i * 16 + g4 * 4;
    unsigned u0 = pk2(fmaxf(acc[i][0] + bp1[o4 + 0], 0.f), fmaxf(acc[i][1] + bp1[o4 + 1], 0.f));
    unsigned u1 = pk2(fmaxf(acc[i][2] + bp1[o4 + 2], 0.f), fmaxf(acc[i][3] + bp1[o4 + 3], 0.f));
    *(uint2*)(h1 + r16 * LDSP + o4) = make_uint2(u0, u1);
  }
  __syncthreads();

  f32x4 acc2[6];
  #pragma unroll
  for (int i = 0; i < 6; ++i) acc2[i] = (f32x4){0.f, 0.f, 0.f, 0.f};
  for (int ks = 0; ks < 12; ++ks) {
    const int kOff = ks * 32 + g4 * 8;
    bf16x8 bfr = *(const bf16x8*)(h1 + r16 * LDSP + kOff);
    #pragma unroll
    for (int i = 0; i < 6; ++i) {
      bf16x8 a = *(const bf16x8*)(Wp2 + (size_t)(wid * 96 + i * 16 + r16) * CCH + kOff);
      acc2[i] = __builtin_amdgcn_mfma_f32_16x16x32_bf16(a, bfr, acc2[i], 0, 0, 0);
    }
  }
  #pragma unroll
  for (int i = 0; i < 6; ++i) {
    int o4 = wid * 96 + i * 16 + g4 * 4;
    uint2 rr = *(const uint2*)(feat + rowBase + o4);
    float4 v;
    v.x = fmaxf(acc2[i][0] + bp2[o4 + 0] + b2f((unsigned short)(rr.x & 0xffff)), 0.f);
    v.y = fmaxf(acc2[i][1] + bp2[o4 + 1] + b2f((unsigned short)(rr.x >> 16)), 0.f);
    v.z = fmaxf(acc2[i][2] + bp2[o4 + 2] + b2f((unsigned short)(rr.y & 0xffff)), 0.f);
    v.w = fmaxf(acc2[i][3] + bp2[o4 + 3] + b2f((unsigned short)(rr.y >> 16)), 0.f);
    *(float4*)(out + rowBase + o4) = v;
  }
}

// ---------------- launch ----------------
extern "C" void kernel_launch(void* const* d_in, const int* in_sizes, int n_in,
                              void* d_out, int out_size, void* d_ws, size_t ws_size,
                              hipStream_t stream) {
  (void)in_sizes; (void)n_in; (void)out_size; (void)ws_size;
  const float* xyz   = (const float*)d_in[0];
  const float* alpha = (const float*)d_in[1];
  const float* beta  = (const float*)d_in[2];
  const float* Wt    = (const float*)d_in[3];
  const float* bt    = (const float*)d_in[4];
  const float* gt    = (const float*)d_in[5];
  const float* bbt   = (const float*)d_in[6];
  const float* Wpre1 = (const float*)d_in[7];
  const float* bpre1 = (const float*)d_in[8];
  const float* gpre1 = (const float*)d_in[9];
  const float* bbpre1= (const float*)d_in[10];
  const float* Wpre2 = (const float*)d_in[11];
  const float* bpre2 = (const float*)d_in[12];
  const float* gpre2 = (const float*)d_in[13];
  const float* bbpre2= (const float*)d_in[14];
  const float* Wpos1 = (const float*)d_in[15];
  const float* bpos1 = (const float*)d_in[16];
  const float* gpos1 = (const float*)d_in[17];
  const float* bbpos1= (const float*)d_in[18];
  const float* Wpos2 = (const float*)d_in[19];
  const float* bpos2 = (const float*)d_in[20];
  const float* gpos2 = (const float*)d_in[21];
  const float* bbpos2= (const float*)d_in[22];

  char* ws = (char*)d_ws;
  size_t off = 0;
  auto alloc = [&](size_t bytes) -> void* {
    void* p = ws + off;
    off += (bytes + 255) & ~(size_t)255;
    return p;
  };
  float* WtF = (float*)alloc(CCH * 6 * 4);
  float* btF = (float*)alloc(CCH * 4);
  unsigned short* W1 = (unsigned short*)alloc(CCH * CCH * 2);
  float* b1 = (float*)alloc(CCH * 4);
  unsigned short* W2 = (unsigned short*)alloc(CCH * CCH * 2);
  float* b2 = (float*)alloc(CCH * 4);
  unsigned short* Wp1 = (unsigned short*)alloc(CCH * CCH * 2);
  float* bp1 = (float*)alloc(CCH * 4);
  unsigned short* Wp2 = (unsigned short*)alloc(CCH * CCH * 2);
  float* bp2 = (float*)alloc(CCH * 4);
  int* cIdx = (int*)alloc(8 * SGRP * 4);
  float* ctrW = (float*)alloc(8 * SGRP * 3 * 4);
  float* nbrD = (float*)alloc((size_t)8 * SGRP * KNBR * 3 * 4);
  float* partials = (float*)alloc(8 * SGRP * 2 * 4);
  float* stdv = (float*)alloc(8 * 4);
  unsigned short* feat = (unsigned short*)alloc((size_t)8 * SGRP * CCH * 2);
  unsigned long long* pub = (unsigned long long*)alloc(2 * 8 * 4 * 3 * 8);

  fold_w_f32<<<CCH, 64, 0, stream>>>(Wt, bt, gt, bbt, WtF, btF, 6);
  FoldArgs fa0{Wpre1, bpre1, gpre1, bbpre1, W1, b1};
  FoldArgs fa1{Wpre2, bpre2, gpre2, bbpre2, W2, b2};
  FoldArgs fa2{Wpos1, bpos1, gpos1, bbpos1, Wp1, bp1};
  FoldArgs fa3{Wpos2, bpos2, gpos2, bbpos2, Wp2, bp2};
  fold4_bf16<<<dim3(CCH, 4), 128, 0, stream>>>(fa0, fa1, fa2, fa3);

  // zero the handshake area every launch (ws is poisoned 0xAA; replays must not
  // see stale seq values)
  hipMemsetAsync(pub, 0, 2 * 8 * 4 * 3 * 8, stream);
  fps_kernel<<<32, 256, 0, stream>>>(xyz, cIdx, pub);
  knn_kernel<<<8 * SGRP, 256, 0, stream>>>(xyz, cIdx, nbrD, ctrW, partials);
  std_kernel<<<8, 256, 0, stream>>>(partials, stdv);
  group_mlp_kernel<<<1024, 512, 0, stream>>>(alpha, beta, WtF, btF, W1, b1, W2, b2,
                                             nbrD, ctrW, stdv, feat);
  pos_kernel<<<256, 256, 0, stream>>>(feat, Wp1, bp1, Wp2, bp2, (float*)d_out);
}

// Round 5
// 1955.104 us; speedup vs baseline: 1.8230x; 1.8230x over previous
//
#include <hip/hip_runtime.h>
#include <hip/hip_bf16.h>
#include <math.h>

typedef __bf16 bf16x8 __attribute__((ext_vector_type(8)));
typedef float f32x4 __attribute__((ext_vector_type(4)));

#define NPTS 8192
#define SGRP 512
#define KNBR 32
#define CCH 384
#define LDSP 392   // padded ushort row stride for [l][c] LDS tiles

static __device__ __forceinline__ unsigned short f2b(float f) {
  union { float f; unsigned u; } v; v.f = f;
  return (unsigned short)((v.u + 0x7fffu + ((v.u >> 16) & 1u)) >> 16);
}
static __device__ __forceinline__ float b2f(unsigned short u) {
  union { unsigned u; float f; } v; v.u = ((unsigned)u) << 16;
  return v.f;
}
static __device__ __forceinline__ unsigned pk2(float a, float b) {
  return (unsigned)f2b(a) | ((unsigned)f2b(b) << 16);
}

// fmax with DPP-shifted self (identity 0 for invalid lanes: distances are >= 0)
#define DPPMAX(v, ctrl) \
  fmaxf((v), __int_as_float(__builtin_amdgcn_update_dpp(0, __float_as_int(v), (ctrl), 0xf, 0xf, false)))

// ---------------- weight folding: bn(conv(x)) = (W*s)x + (b*s+bb) ----------------
struct FoldArgs {
  const float *W, *b, *g, *bb;
  unsigned short* Wd;
  float* bd;
};
__global__ void fold4_bf16(FoldArgs a0, FoldArgs a1, FoldArgs a2, FoldArgs a3) {
  FoldArgs a = (blockIdx.y == 0) ? a0 : (blockIdx.y == 1) ? a1 : (blockIdx.y == 2) ? a2 : a3;
  int o = blockIdx.x;
  float sc = a.g[o] / sqrtf(1.0f + 1e-5f);
  for (int c = threadIdx.x; c < CCH; c += blockDim.x)
    a.Wd[o * CCH + c] = f2b(a.W[o * CCH + c] * sc);
  if (threadIdx.x == 0) a.bd[o] = a.b[o] * sc + a.bb[o];
}
__global__ void fold_w_f32(const float* __restrict__ W, const float* __restrict__ b,
                           const float* __restrict__ g, const float* __restrict__ bb,
                           float* __restrict__ Wd, float* __restrict__ bd, int Cin) {
  int o = blockIdx.x;
  float sc = g[o] / sqrtf(1.0f + 1e-5f);
  for (int c = threadIdx.x; c < Cin; c += blockDim.x)
    Wd[o * Cin + c] = W[o * Cin + c] * sc;
  if (threadIdx.x == 0) bd[o] = b[o] * sc + bb[o];
}

// ---------------- FPS v5: 2 independent batches per block, 1 barrier/step --------
// Thread tid owns points [tid*16, tid*16+16) of BOTH batches (registers only).
// Contiguous ownership => lane order == index order => strict > everywhere
// reproduces numpy first-max tie semantics. Winner coords are carried through
// the reduction (cndmask + readlane + LDS slots) -- no trailing broadcast read.
// The two batches share one barrier per step, halving the serial-tail cost.
static __device__ __forceinline__ void fps_wave_reduce(
    float (&X)[16], float (&Y)[16], float (&Z)[16], float (&D)[16],
    float cx, float cy, float cz, int tid,
    float &kv, unsigned &ki, unsigned &kx, unsigned &ky, unsigned &kz) {
  #pragma clang fp contract(off)
  float bv = -1.0f; int bi = 0; float bx = 0.f, by = 0.f, bz = 0.f;
  #pragma unroll
  for (int j = 0; j < 16; ++j) {
    float dx = X[j] - cx, dy = Y[j] - cy, dz = Z[j] - cz;
    float d = (dx * dx + dy * dy) + dz * dz;   // contract off: numpy ulp-exact
    float nd = fminf(D[j], d);
    D[j] = nd;
    if (nd > bv) { bv = nd; bi = tid * 16 + j; bx = X[j]; by = Y[j]; bz = Z[j]; }
  }
  float m = bv;
  m = DPPMAX(m, 0x111);   // row_shr:1
  m = DPPMAX(m, 0x112);   // row_shr:2
  m = DPPMAX(m, 0x114);   // row_shr:4
  m = DPPMAX(m, 0x118);   // row_shr:8
  m = DPPMAX(m, 0x142);   // row_bcast:15
  m = DPPMAX(m, 0x143);   // row_bcast:31
  float wmax = __uint_as_float(__builtin_amdgcn_readlane(__float_as_uint(m), 63));
  unsigned long long msk = __ballot(bv == wmax);
  int srcLane = (int)__builtin_ctzll(msk);          // lowest lane == lowest index
  kv = wmax;
  ki = (unsigned)__builtin_amdgcn_readlane(bi, srcLane);
  kx = (unsigned)__builtin_amdgcn_readlane(__float_as_int(bx), srcLane);
  ky = (unsigned)__builtin_amdgcn_readlane(__float_as_int(by), srcLane);
  kz = (unsigned)__builtin_amdgcn_readlane(__float_as_int(bz), srcLane);
}

__global__ __launch_bounds__(512, 2) void fps_kernel(const float* __restrict__ xyz,
                                                     int* __restrict__ cIdx) {
  #pragma clang fp contract(off)
  __shared__ uint4 slotA[2][16];     // [parity][batchHalf*8 + wave] = (val, idx, x, y)
  __shared__ unsigned slotZ[2][16];  // z coord
  const int tid = threadIdx.x, lane = tid & 63, wid = tid >> 6;
  const int b0 = blockIdx.x * 2, b1 = b0 + 1;
  const float* xA = xyz + (size_t)b0 * NPTS * 3;
  const float* xB = xyz + (size_t)b1 * NPTS * 3;

  float XA[16], YA[16], ZA[16], DA[16];
  float XB[16], YB[16], ZB[16], DB[16];
  {
    const float4* srcA = (const float4*)xA + tid * 12;
    const float4* srcB = (const float4*)xB + tid * 12;
    float tmp[48];
    #pragma unroll
    for (int q = 0; q < 12; ++q) {
      float4 t = srcA[q];
      tmp[q * 4 + 0] = t.x; tmp[q * 4 + 1] = t.y;
      tmp[q * 4 + 2] = t.z; tmp[q * 4 + 3] = t.w;
    }
    #pragma unroll
    for (int j = 0; j < 16; ++j) {
      XA[j] = tmp[j * 3 + 0]; YA[j] = tmp[j * 3 + 1]; ZA[j] = tmp[j * 3 + 2];
      DA[j] = __builtin_inff();
    }
    #pragma unroll
    for (int q = 0; q < 12; ++q) {
      float4 t = srcB[q];
      tmp[q * 4 + 0] = t.x; tmp[q * 4 + 1] = t.y;
      tmp[q * 4 + 2] = t.z; tmp[q * 4 + 3] = t.w;
    }
    #pragma unroll
    for (int j = 0; j < 16; ++j) {
      XB[j] = tmp[j * 3 + 0]; YB[j] = tmp[j * 3 + 1]; ZB[j] = tmp[j * 3 + 2];
      DB[j] = __builtin_inff();
    }
  }
  if (tid == 0) { cIdx[b0 * SGRP] = 0; cIdx[b1 * SGRP] = 0; }
  float cxA = xA[0], cyA = xA[1], czA = xA[2];
  float cxB = xB[0], cyB = xB[1], czB = xB[2];

  for (int step = 1; step < SGRP; ++step) {
    const int par = step & 1;
    float kv; unsigned ki, kx, ky, kz;
    fps_wave_reduce(XA, YA, ZA, DA, cxA, cyA, czA, tid, kv, ki, kx, ky, kz);
    if (lane == 0) {
      slotA[par][wid] = make_uint4(__float_as_uint(kv), ki, kx, ky);
      slotZ[par][wid] = kz;
    }
    fps_wave_reduce(XB, YB, ZB, DB, cxB, cyB, czB, tid, kv, ki, kx, ky, kz);
    if (lane == 0) {
      slotA[par][8 + wid] = make_uint4(__float_as_uint(kv), ki, kx, ky);
      slotZ[par][8 + wid] = kz;
    }
    __syncthreads();   // the only barrier per step (serves both batches)
    // combine per batch: ascending wave order + strict > => lowest index on ties
    float gvA = -1.0f; unsigned giA = 0;
    #pragma unroll
    for (int w = 0; w < 8; ++w) {
      uint4 s = slotA[par][w];
      float fv = __uint_as_float(s.x);
      if (fv > gvA) {
        gvA = fv; giA = s.y;
        cxA = __uint_as_float(s.z); cyA = __uint_as_float(s.w);
        czA = __uint_as_float(slotZ[par][w]);
      }
    }
    float gvB = -1.0f; unsigned giB = 0;
    #pragma unroll
    for (int w = 0; w < 8; ++w) {
      uint4 s = slotA[par][8 + w];
      float fv = __uint_as_float(s.x);
      if (fv > gvB) {
        gvB = fv; giB = s.y;
        cxB = __uint_as_float(s.z); cyB = __uint_as_float(s.w);
        czB = __uint_as_float(slotZ[par][8 + w]);
      }
    }
    if (tid == 0) {
      cIdx[b0 * SGRP + step] = (int)giA;
      cIdx[b1 * SGRP + step] = (int)giB;
    }
  }
}

// ---------------- kNN v2: cached per-thread min, winner-only rescan, 1 barrier/iter ----
__global__ __launch_bounds__(256) void knn_kernel(const float* __restrict__ xyz,
                                                  const int* __restrict__ cIdx,
                                                  float* __restrict__ nbrDiff,
                                                  float* __restrict__ ctrW,
                                                  float* __restrict__ partials) {
  #pragma clang fp contract(off)
  __shared__ unsigned long long keyBuf[4];
  __shared__ int winners[KNBR];
  const int cid = blockIdx.x;
  const int b = cid >> 9;
  const int tid = threadIdx.x;
  const float* xb = xyz + (size_t)b * NPTS * 3;
  const int cI = cIdx[cid];
  const float cx = xb[cI * 3], cy = xb[cI * 3 + 1], cz = xb[cI * 3 + 2];
  const float cs = (cx * cx + cy * cy) + cz * cz;

  float d2[32];
  float mv = __builtin_inff(); int mi = 0;
  #pragma unroll
  for (int j = 0; j < 32; ++j) {
    int p = tid + (j << 8);
    float x = xb[p * 3], y = xb[p * 3 + 1], z = xb[p * 3 + 2];
    float ps = (x * x + y * y) + z * z;
    float dot = (cx * x + cy * y) + cz * z;
    d2[j] = (cs + ps) - 2.0f * dot;
    if (d2[j] < mv) { mv = d2[j]; mi = p; }   // strict <: lowest p on tie
  }
  if (tid < 4) keyBuf[tid] = 0xFFFFFFFFFFFFFFFFull;
  __syncthreads();

  for (int it = 0; it < KNBR; ++it) {
    if (tid == 0) keyBuf[(it + 2) & 3] = 0xFFFFFFFFFFFFFFFFull;
    float bv = mv; int bi = mi;
    #pragma unroll
    for (int s = 1; s < 64; s <<= 1) {
      float ov = __shfl_xor(bv, s); int oi = __shfl_xor(bi, s);
      if (ov < bv || (ov == bv && oi < bi)) { bv = ov; bi = oi; }
    }
    if ((tid & 63) == 0) {
      unsigned u = __float_as_uint(bv);
      unsigned m = u ^ (unsigned)(((int)u >> 31) | 0x80000000);   // monotone float->uint
      unsigned long long key = (((unsigned long long)m) << 32) | (unsigned long long)bi;
      atomicMin(&keyBuf[it & 3], key);
    }
    __syncthreads();
    unsigned long long k = keyBuf[it & 3];
    int wi = (int)(k & 0x1FFFu);
    if (tid == 0) winners[it] = wi;
    if (tid == (wi & 255)) {     // only the owner rescans its 32 values
      #pragma unroll
      for (int j = 0; j < 32; ++j)
        if (wi == tid + (j << 8)) d2[j] = __builtin_inff();
      mv = __builtin_inff(); mi = 0;
      #pragma unroll
      for (int j = 0; j < 32; ++j)
        if (d2[j] < mv) { mv = d2[j]; mi = tid + (j << 8); }
    }
  }
  __syncthreads();

  // gather diffs + per-center stats partials
  float sum = 0.f, sq = 0.f;
  if (tid < KNBR) {
    int w = winners[tid];
    float dx = xb[w * 3] - cx, dy = xb[w * 3 + 1] - cy, dz = xb[w * 3 + 2] - cz;
    size_t o = ((size_t)cid * KNBR + tid) * 3;
    nbrDiff[o + 0] = dx; nbrDiff[o + 1] = dy; nbrDiff[o + 2] = dz;
    sum = (dx + dy) + dz;
    sq = (dx * dx + dy * dy) + dz * dz;
  }
  if (tid < 64) {
    #pragma unroll
    for (int s = 1; s < 64; s <<= 1) { sum += __shfl_xor(sum, s); sq += __shfl_xor(sq, s); }
    if (tid == 0) { partials[cid * 2] = sum; partials[cid * 2 + 1] = sq; }
  }
  if (tid < 3) ctrW[(size_t)cid * 3 + tid] = xb[cI * 3 + tid];
}

// ---------------- per-batch std (ddof=1), deterministic fp64 tree ----------------
__global__ __launch_bounds__(256) void std_kernel(const float* __restrict__ partials,
                                                  float* __restrict__ stdv) {
  __shared__ double sd[256], sq[256];
  const int b = blockIdx.x, t = threadIdx.x;
  int i0 = (b * 512 + t) * 2;
  sd[t] = (double)partials[i0] + (double)partials[i0 + 512];
  sq[t] = (double)partials[i0 + 1] + (double)partials[i0 + 513];
  for (int st = 128; st > 0; st >>= 1) {
    __syncthreads();
    if (t < st) { sd[t] += sd[t + st]; sq[t] += sq[t + st]; }
  }
  if (t == 0) {
    double n = (double)(SGRP * KNBR * 3);
    double mean = sd[0] / n;
    double var = (sq[0] - sd[0] * mean) / (n - 1.0);
    stdv[b] = (float)sqrt(var);
  }
}

// ---------------- fused group MLP (t-net + pre res_block + maxpool) ----------------
// one block = 4 groups (128 l-columns), 8 waves, MFMA 16x16x32 bf16
static __device__ __forceinline__ void gemm_half(const unsigned short* __restrict__ W,
                                                 const unsigned short* ht,
                                                 int oBase, int n0, int r16, int g4,
                                                 f32x4 acc[3][4]) {
  for (int ks = 0; ks < 12; ++ks) {
    const int kOff = ks * 32 + g4 * 8;
    bf16x8 a[3], bb[4];
    #pragma unroll
    for (int i = 0; i < 3; ++i)
      a[i] = *(const bf16x8*)(W + (size_t)(oBase + i * 16 + r16) * CCH + kOff);
    #pragma unroll
    for (int j = 0; j < 4; ++j)
      bb[j] = *(const bf16x8*)(ht + (n0 + j * 16 + r16) * LDSP + kOff);
    #pragma unroll
    for (int i = 0; i < 3; ++i) {
      #pragma unroll
      for (int j = 0; j < 4; ++j)
        acc[i][j] = __builtin_amdgcn_mfma_f32_16x16x32_bf16(a[i], bb[j], acc[i][j], 0, 0, 0);
    }
  }
}

__global__ __launch_bounds__(512) void group_mlp_kernel(
    const float* __restrict__ alpha, const float* __restrict__ beta,
    const float* __restrict__ WtF, const float* __restrict__ btF,
    const unsigned short* __restrict__ W1, const float* __restrict__ b1,
    const unsigned short* __restrict__ W2, const float* __restrict__ b2,
    const float* __restrict__ nbrDiff, const float* __restrict__ ctrW,
    const float* __restrict__ stdv, unsigned short* __restrict__ feat) {
  __shared__ unsigned short ht[128 * LDSP];
  __shared__ float xtw[128 * 8];
  __shared__ float wtl[CCH * 6];
  __shared__ float btl[CCH];

  const int tid = threadIdx.x;
  const int lane = tid & 63, wid = tid >> 6;
  const int r16 = lane & 15, g4 = lane >> 4;
  const int bid = blockIdx.x;
  const int b = bid >> 7;
  const int sBase = (bid & 127) << 2;

  for (int i = tid; i < CCH * 6; i += 512) wtl[i] = WtF[i];
  for (int i = tid; i < CCH; i += 512) btl[i] = btF[i];

  const float inv = 1.0f / (stdv[b] + 1e-5f);
  if (tid < 128) {
    int g = tid >> 5, kk = tid & 31;
    int cid = b * SGRP + sBase + g;
    const float* nb = nbrDiff + ((size_t)cid * KNBR + kk) * 3;
    const float* cc = ctrW + (size_t)cid * 3;
    #pragma unroll
    for (int c = 0; c < 3; ++c) {
      xtw[tid * 8 + c] = alpha[c] * (nb[c] * inv) + beta[c];
      xtw[tid * 8 + 3 + c] = cc[c];
    }
  }
  __syncthreads();

  // conv1 (t-net, K=6) -> h0 bf16 into ht[l][o]
  {
    int l = tid & 127, oi = tid >> 7;
    float xv[6];
    #pragma unroll
    for (int c = 0; c < 6; ++c) xv[c] = xtw[l * 8 + c];
    for (int j = 0; j < 96; ++j) {
      int o = oi * 96 + j;
      float v = btl[o];
      #pragma unroll
      for (int c = 0; c < 6; ++c) v += wtl[o * 6 + c] * xv[c];
      ht[l * LDSP + o] = f2b(fmaxf(v, 0.0f));
    }
  }
  __syncthreads();

  const int oBase = wid * 48;

  // conv2: h1 = relu(W1 h0 + b1), overwrite ht by l-halves (disjoint rows)
  for (int half = 0; half < 2; ++half) {
    const int n0 = half * 64;
    f32x4 acc[3][4];
    #pragma unroll
    for (int i = 0; i < 3; ++i) {
      #pragma unroll
      for (int j = 0; j < 4; ++j) acc[i][j] = (f32x4){0.f, 0.f, 0.f, 0.f};
    }
    gemm_half(W1, ht, oBase, n0, r16, g4, acc);
    __syncthreads();   // all waves done reading this half's h0 rows
    #pragma unroll
    for (int i = 0; i < 3; ++i) {
      int o4 = oBase + i * 16 + g4 * 4;
      float bs0 = b1[o4], bs1 = b1[o4 + 1], bs2 = b1[o4 + 2], bs3 = b1[o4 + 3];
      #pragma unroll
      for (int j = 0; j < 4; ++j) {
        int row = n0 + j * 16 + r16;
        unsigned u0 = pk2(fmaxf(acc[i][j][0] + bs0, 0.f), fmaxf(acc[i][j][1] + bs1, 0.f));
        unsigned u1 = pk2(fmaxf(acc[i][j][2] + bs2, 0.f), fmaxf(acc[i][j][3] + bs3, 0.f));
        *(uint2*)(ht + row * LDSP + o4) = make_uint2(u0, u1);
      }
    }
    __syncthreads();
  }

  // conv3 + bias + residual(h0 recomputed) + relu + maxpool over K=32
  for (int half = 0; half < 2; ++half) {
    const int n0 = half * 64;
    f32x4 acc[3][4];
    #pragma unroll
    for (int i = 0; i < 3; ++i) {
      #pragma unroll
      for (int j = 0; j < 4; ++j) acc[i][j] = (f32x4){0.f, 0.f, 0.f, 0.f};
    }
    gemm_half(W2, ht, oBase, n0, r16, g4, acc);

    float bias2[3][4];
    #pragma unroll
    for (int i = 0; i < 3; ++i) {
      int o4 = oBase + i * 16 + g4 * 4;
      #pragma unroll
      for (int r = 0; r < 4; ++r) bias2[i][r] = b2[o4 + r];
    }
    float mx[3][2][4];
    #pragma unroll
    for (int i = 0; i < 3; ++i) {
      #pragma unroll
      for (int gg = 0; gg < 2; ++gg) {
        #pragma unroll
        for (int r = 0; r < 4; ++r) mx[i][gg][r] = 0.f;   // values are relu'd (>=0)
      }
    }
    #pragma unroll
    for (int j = 0; j < 4; ++j) {
      int l = n0 + j * 16 + r16;
      float xv[6];
      #pragma unroll
      for (int c = 0; c < 6; ++c) xv[c] = xtw[l * 8 + c];
      #pragma unroll
      for (int i = 0; i < 3; ++i) {
        int o4 = oBase + i * 16 + g4 * 4;
        #pragma unroll
        for (int r = 0; r < 4; ++r) {
          float h0 = btl[o4 + r];
          #pragma unroll
          for (int c = 0; c < 6; ++c) h0 += wtl[(o4 + r) * 6 + c] * xv[c];
          h0 = fmaxf(h0, 0.f);
          float v = fmaxf(acc[i][j][r] + bias2[i][r] + h0, 0.f);
          mx[i][j >> 1][r] = fmaxf(mx[i][j >> 1][r], v);
        }
      }
    }
    #pragma unroll
    for (int i = 0; i < 3; ++i) {
      #pragma unroll
      for (int gg = 0; gg < 2; ++gg) {
        float m0 = mx[i][gg][0], m1 = mx[i][gg][1], m2 = mx[i][gg][2], m3 = mx[i][gg][3];
        #pragma unroll
        for (int s = 1; s < 16; s <<= 1) {
          m0 = fmaxf(m0, __shfl_xor(m0, s));
          m1 = fmaxf(m1, __shfl_xor(m1, s));
          m2 = fmaxf(m2, __shfl_xor(m2, s));
          m3 = fmaxf(m3, __shfl_xor(m3, s));
        }
        if (r16 == 0) {
          int sIdx = sBase + half * 2 + gg;
          size_t fi = ((size_t)(b * SGRP + sIdx)) * CCH + oBase + i * 16 + g4 * 4;
          *(uint2*)(feat + fi) = make_uint2(pk2(m0, m1), pk2(m2, m3));
        }
      }
    }
  }
}

// ---------------- pos res_block on feat (B,384,512) + final transpose to (B,S,C) fp32 ----------------
__global__ __launch_bounds__(256) void pos_kernel(const unsigned short* __restrict__ feat,
                                                  const unsigned short* __restrict__ Wp1,
                                                  const float* __restrict__ bp1,
                                                  const unsigned short* __restrict__ Wp2,
                                                  const float* __restrict__ bp2,
                                                  float* __restrict__ out) {
  __shared__ unsigned short h1[16 * LDSP];
  const int tid = threadIdx.x;
  const int lane = tid & 63, wid = tid >> 6;
  const int r16 = lane & 15, g4 = lane >> 4;
  const int bid = blockIdx.x;
  const int b = bid >> 5;
  const int s0 = (bid & 31) << 4;
  const size_t rowBase = ((size_t)(b * SGRP + s0 + r16)) * CCH;

  f32x4 acc[6];
  #pragma unroll
  for (int i = 0; i < 6; ++i) acc[i] = (f32x4){0.f, 0.f, 0.f, 0.f};
  for (int ks = 0; ks < 12; ++ks) {
    const int kOff = ks * 32 + g4 * 8;
    bf16x8 bfr = *(const bf16x8*)(feat + rowBase + kOff);
    #pragma unroll
    for (int i = 0; i < 6; ++i) {
      bf16x8 a = *(const bf16x8*)(Wp1 + (size_t)(wid * 96 + i * 16 + r16) * CCH + kOff);
      acc[i] = __builtin_amdgcn_mfma_f32_16x16x32_bf16(a, bfr, acc[i], 0, 0, 0);
    }
  }
  #pragma unroll
  for (int i = 0; i < 6; ++i) {
    int o4 = wid * 96 + i * 16 + g4 * 4;
    unsigned u0 = pk2(fmaxf(acc[i][0] + bp1[o4 + 0], 0.f), fmaxf(acc[i][1] + bp1[o4 + 1], 0.f));
    unsigned u1 = pk2(fmaxf(acc[i][2] + bp1[o4 + 2], 0.f), fmaxf(acc[i][3] + bp1[o4 + 3], 0.f));
    *(uint2*)(h1 + r16 * LDSP + o4) = make_uint2(u0, u1);
  }
  __syncthreads();

  f32x4 acc2[6];
  #pragma unroll
  for (int i = 0; i < 6; ++i) acc2[i] = (f32x4){0.f, 0.f, 0.f, 0.f};
  for (int ks = 0; ks < 12; ++ks) {
    const int kOff = ks * 32 + g4 * 8;
    bf16x8 bfr = *(const bf16x8*)(h1 + r16 * LDSP + kOff);
    #pragma unroll
    for (int i = 0; i < 6; ++i) {
      bf16x8 a = *(const bf16x8*)(Wp2 + (size_t)(wid * 96 + i * 16 + r16) * CCH + kOff);
      acc2[i] = __builtin_amdgcn_mfma_f32_16x16x32_bf16(a, bfr, acc2[i], 0, 0, 0);
    }
  }
  #pragma unroll
  for (int i = 0; i < 6; ++i) {
    int o4 = wid * 96 + i * 16 + g4 * 4;
    uint2 rr = *(const uint2*)(feat + rowBase + o4);
    float4 v;
    v.x = fmaxf(acc2[i][0] + bp2[o4 + 0] + b2f((unsigned short)(rr.x & 0xffff)), 0.f);
    v.y = fmaxf(acc2[i][1] + bp2[o4 + 1] + b2f((unsigned short)(rr.x >> 16)), 0.f);
    v.z = fmaxf(acc2[i][2] + bp2[o4 + 2] + b2f((unsigned short)(rr.y & 0xffff)), 0.f);
    v.w = fmaxf(acc2[i][3] + bp2[o4 + 3] + b2f((unsigned short)(rr.y >> 16)), 0.f);
    *(float4*)(out + rowBase + o4) = v;
  }
}

// ---------------- launch ----------------
extern "C" void kernel_launch(void* const* d_in, const int* in_sizes, int n_in,
                              void* d_out, int out_size, void* d_ws, size_t ws_size,
                              hipStream_t stream) {
  (void)in_sizes; (void)n_in; (void)out_size; (void)ws_size;
  const float* xyz   = (const float*)d_in[0];
  const float* alpha = (const float*)d_in[1];
  const float* beta  = (const float*)d_in[2];
  const float* Wt    = (const float*)d_in[3];
  const float* bt    = (const float*)d_in[4];
  const float* gt    = (const float*)d_in[5];
  const float* bbt   = (const float*)d_in[6];
  const float* Wpre1 = (const float*)d_in[7];
  const float* bpre1 = (const float*)d_in[8];
  const float* gpre1 = (const float*)d_in[9];
  const float* bbpre1= (const float*)d_in[10];
  const float* Wpre2 = (const float*)d_in[11];
  const float* bpre2 = (const float*)d_in[12];
  const float* gpre2 = (const float*)d_in[13];
  const float* bbpre2= (const float*)d_in[14];
  const float* Wpos1 = (const float*)d_in[15];
  const float* bpos1 = (const float*)d_in[16];
  const float* gpos1 = (const float*)d_in[17];
  const float* bbpos1= (const float*)d_in[18];
  const float* Wpos2 = (const float*)d_in[19];
  const float* bpos2 = (const float*)d_in[20];
  const float* gpos2 = (const float*)d_in[21];
  const float* bbpos2= (const float*)d_in[22];

  char* ws = (char*)d_ws;
  size_t off = 0;
  auto alloc = [&](size_t bytes) -> void* {
    void* p = ws + off;
    off += (bytes + 255) & ~(size_t)255;
    return p;
  };
  float* WtF = (float*)alloc(CCH * 6 * 4);
  float* btF = (float*)alloc(CCH * 4);
  unsigned short* W1 = (unsigned short*)alloc(CCH * CCH * 2);
  float* b1 = (float*)alloc(CCH * 4);
  unsigned short* W2 = (unsigned short*)alloc(CCH * CCH * 2);
  float* b2 = (float*)alloc(CCH * 4);
  unsigned short* Wp1 = (unsigned short*)alloc(CCH * CCH * 2);
  float* bp1 = (float*)alloc(CCH * 4);
  unsigned short* Wp2 = (unsigned short*)alloc(CCH * CCH * 2);
  float* bp2 = (float*)alloc(CCH * 4);
  int* cIdx = (int*)alloc(8 * SGRP * 4);
  float* ctrW = (float*)alloc(8 * SGRP * 3 * 4);
  float* nbrD = (float*)alloc((size_t)8 * SGRP * KNBR * 3 * 4);
  float* partials = (float*)alloc(8 * SGRP * 2 * 4);
  float* stdv = (float*)alloc(8 * 4);
  unsigned short* feat = (unsigned short*)alloc((size_t)8 * SGRP * CCH * 2);

  fold_w_f32<<<CCH, 64, 0, stream>>>(Wt, bt, gt, bbt, WtF, btF, 6);
  FoldArgs fa0{Wpre1, bpre1, gpre1, bbpre1, W1, b1};
  FoldArgs fa1{Wpre2, bpre2, gpre2, bbpre2, W2, b2};
  FoldArgs fa2{Wpos1, bpos1, gpos1, bbpos1, Wp1, bp1};
  FoldArgs fa3{Wpos2, bpos2, gpos2, bbpos2, Wp2, bp2};
  fold4_bf16<<<dim3(CCH, 4), 128, 0, stream>>>(fa0, fa1, fa2, fa3);

  fps_kernel<<<4, 512, 0, stream>>>(xyz, cIdx);
  knn_kernel<<<8 * SGRP, 256, 0, stream>>>(xyz, cIdx, nbrD, ctrW, partials);
  std_kernel<<<8, 256, 0, stream>>>(partials, stdv);
  group_mlp_kernel<<<1024, 512, 0, stream>>>(alpha, beta, WtF, btF, W1, b1, W2, b2,
                                             nbrD, ctrW, stdv, feat);
  pos_kernel<<<256, 256, 0, stream>>>(feat, Wp1, bp1, Wp2, bp2, (float*)d_out);
}

// Round 6
// 1740.435 us; speedup vs baseline: 2.0478x; 1.1233x over previous
//
#include <hip/hip_runtime.h>
#include <hip/hip_bf16.h>
#include <math.h>

typedef __bf16 bf16x8 __attribute__((ext_vector_type(8)));
typedef float f32x4 __attribute__((ext_vector_type(4)));

#define NPTS 8192
#define SGRP 512
#define KNBR 32
#define CCH 384
#define LDSP 392   // padded ushort row stride for [l][c] LDS tiles

static __device__ __forceinline__ unsigned short f2b(float f) {
  union { float f; unsigned u; } v; v.f = f;
  return (unsigned short)((v.u + 0x7fffu + ((v.u >> 16) & 1u)) >> 16);
}
static __device__ __forceinline__ float b2f(unsigned short u) {
  union { unsigned u; float f; } v; v.u = ((unsigned)u) << 16;
  return v.f;
}
static __device__ __forceinline__ unsigned pk2(float a, float b) {
  return (unsigned)f2b(a) | ((unsigned)f2b(b) << 16);
}

// fmax with DPP-shifted self (identity 0 for invalid lanes: distances are >= 0)
#define DPPMAX(v, ctrl) \
  fmaxf((v), __int_as_float(__builtin_amdgcn_update_dpp(0, __float_as_int(v), (ctrl), 0xf, 0xf, false)))

// ---------------- weight folding: bn(conv(x)) = (W*s)x + (b*s+bb) ----------------
struct FoldArgs {
  const float *W, *b, *g, *bb;
  unsigned short* Wd;
  float* bd;
};
__global__ void fold4_bf16(FoldArgs a0, FoldArgs a1, FoldArgs a2, FoldArgs a3) {
  FoldArgs a = (blockIdx.y == 0) ? a0 : (blockIdx.y == 1) ? a1 : (blockIdx.y == 2) ? a2 : a3;
  int o = blockIdx.x;
  float sc = a.g[o] / sqrtf(1.0f + 1e-5f);
  for (int c = threadIdx.x; c < CCH; c += blockDim.x)
    a.Wd[o * CCH + c] = f2b(a.W[o * CCH + c] * sc);
  if (threadIdx.x == 0) a.bd[o] = a.b[o] * sc + a.bb[o];
}
__global__ void fold_w_f32(const float* __restrict__ W, const float* __restrict__ b,
                           const float* __restrict__ g, const float* __restrict__ bb,
                           float* __restrict__ Wd, float* __restrict__ bd, int Cin) {
  int o = blockIdx.x;
  float sc = g[o] / sqrtf(1.0f + 1e-5f);
  for (int c = threadIdx.x; c < Cin; c += blockDim.x)
    Wd[o * Cin + c] = W[o * Cin + c] * sc;
  if (threadIdx.x == 0) bd[o] = b[o] * sc + bb[o];
}

// ---------------- FPS v6: 2 batches/block, 1024 thr x 8 pts, reg-budget safe ------
// Thread tid owns points [tid*8, tid*8+8) of both batches (64 data VGPRs total;
// __launch_bounds__(1024,4) pins the cap at 128 -> no spill). One barrier per
// step serves both batches. Cross-wave combine is in-register (slot load +
// full-wave DPP max + ballot/ctz + readlane); winner coords come from a uniform
// global load (removes the 192KB LDS need). Contiguous ownership + strict > =>
// numpy first-max tie semantics; distance arithmetic is contract-off, ulp-exact.
__global__ __launch_bounds__(1024, 4) void fps_kernel(const float* __restrict__ xyz,
                                                      int* __restrict__ cIdx) {
  #pragma clang fp contract(off)
  __shared__ float slotV[2][2][16];
  __shared__ unsigned slotI[2][2][16];
  const int tid = threadIdx.x, lane = tid & 63, wid = tid >> 6;   // wid 0..15
  const int b0 = blockIdx.x * 2, b1 = b0 + 1;
  const float* xA = xyz + (size_t)b0 * NPTS * 3;
  const float* xB = xyz + (size_t)b1 * NPTS * 3;

  float XA[8], YA[8], ZA[8], DA[8];
  float XB[8], YB[8], ZB[8], DB[8];
  {
    const float4* s = (const float4*)xA + tid * 6;
    float4 t0 = s[0], t1 = s[1], t2 = s[2], t3 = s[3], t4 = s[4], t5 = s[5];
    XA[0] = t0.x; YA[0] = t0.y; ZA[0] = t0.z;
    XA[1] = t0.w; YA[1] = t1.x; ZA[1] = t1.y;
    XA[2] = t1.z; YA[2] = t1.w; ZA[2] = t2.x;
    XA[3] = t2.y; YA[3] = t2.z; ZA[3] = t2.w;
    XA[4] = t3.x; YA[4] = t3.y; ZA[4] = t3.z;
    XA[5] = t3.w; YA[5] = t4.x; ZA[5] = t4.y;
    XA[6] = t4.z; YA[6] = t4.w; ZA[6] = t5.x;
    XA[7] = t5.y; YA[7] = t5.z; ZA[7] = t5.w;
  }
  {
    const float4* s = (const float4*)xB + tid * 6;
    float4 t0 = s[0], t1 = s[1], t2 = s[2], t3 = s[3], t4 = s[4], t5 = s[5];
    XB[0] = t0.x; YB[0] = t0.y; ZB[0] = t0.z;
    XB[1] = t0.w; YB[1] = t1.x; ZB[1] = t1.y;
    XB[2] = t1.z; YB[2] = t1.w; ZB[2] = t2.x;
    XB[3] = t2.y; YB[3] = t2.z; ZB[3] = t2.w;
    XB[4] = t3.x; YB[4] = t3.y; ZB[4] = t3.z;
    XB[5] = t3.w; YB[5] = t4.x; ZB[5] = t4.y;
    XB[6] = t4.z; YB[6] = t4.w; ZB[6] = t5.x;
    XB[7] = t5.y; YB[7] = t5.z; ZB[7] = t5.w;
  }
  #pragma unroll
  for (int j = 0; j < 8; ++j) { DA[j] = __builtin_inff(); DB[j] = __builtin_inff(); }
  if (tid == 0) { cIdx[b0 * SGRP] = 0; cIdx[b1 * SGRP] = 0; }
  float cxA = xA[0], cyA = xA[1], czA = xA[2];
  float cxB = xB[0], cyB = xB[1], czB = xB[2];
  const int tbase = tid * 8;

  for (int step = 1; step < SGRP; ++step) {
    const int par = step & 1;
    // ---- batch A distance update + in-thread argmax (strict >: first max) ----
    float avA = -1.0f; int aiA = 0;
    #pragma unroll
    for (int j = 0; j < 8; ++j) {
      float dx = XA[j] - cxA, dy = YA[j] - cyA, dz = ZA[j] - czA;
      float d = (dx * dx + dy * dy) + dz * dz;   // contract off: numpy ulp-exact
      float nd = fminf(DA[j], d);
      DA[j] = nd;
      if (nd > avA) { avA = nd; aiA = tbase + j; }
    }
    float mA = avA;
    mA = DPPMAX(mA, 0x111); mA = DPPMAX(mA, 0x112); mA = DPPMAX(mA, 0x114);
    mA = DPPMAX(mA, 0x118); mA = DPPMAX(mA, 0x142); mA = DPPMAX(mA, 0x143);
    float wmaxA = __uint_as_float(__builtin_amdgcn_readlane(__float_as_uint(mA), 63));
    unsigned long long mskA = __ballot(avA == wmaxA);
    int srcA = (int)__builtin_ctzll(mskA);
    unsigned wbiA = (unsigned)__builtin_amdgcn_readlane(aiA, srcA);
    if (lane == 0) { slotV[par][0][wid] = wmaxA; slotI[par][0][wid] = wbiA; }
    // ---- batch B ----
    float avB = -1.0f; int aiB = 0;
    #pragma unroll
    for (int j = 0; j < 8; ++j) {
      float dx = XB[j] - cxB, dy = YB[j] - cyB, dz = ZB[j] - czB;
      float d = (dx * dx + dy * dy) + dz * dz;
      float nd = fminf(DB[j], d);
      DB[j] = nd;
      if (nd > avB) { avB = nd; aiB = tbase + j; }
    }
    float mB = avB;
    mB = DPPMAX(mB, 0x111); mB = DPPMAX(mB, 0x112); mB = DPPMAX(mB, 0x114);
    mB = DPPMAX(mB, 0x118); mB = DPPMAX(mB, 0x142); mB = DPPMAX(mB, 0x143);
    float wmaxB = __uint_as_float(__builtin_amdgcn_readlane(__float_as_uint(mB), 63));
    unsigned long long mskB = __ballot(avB == wmaxB);
    int srcB = (int)__builtin_ctzll(mskB);
    unsigned wbiB = (unsigned)__builtin_amdgcn_readlane(aiB, srcB);
    if (lane == 0) { slotV[par][1][wid] = wmaxB; slotI[par][1][wid] = wbiB; }

    __syncthreads();   // the only barrier per step (serves both batches)

    // ---- cross-wave combine, in-register (lane l holds slot l&15) ----
    float svA = slotV[par][0][lane & 15];
    unsigned siA = slotI[par][0][lane & 15];
    float svB = slotV[par][1][lane & 15];
    unsigned siB = slotI[par][1][lane & 15];
    float gA = svA;
    gA = DPPMAX(gA, 0x111); gA = DPPMAX(gA, 0x112); gA = DPPMAX(gA, 0x114);
    gA = DPPMAX(gA, 0x118); gA = DPPMAX(gA, 0x142); gA = DPPMAX(gA, 0x143);
    float gmA = __uint_as_float(__builtin_amdgcn_readlane(__float_as_uint(gA), 63));
    int sA = (int)__builtin_ctzll(__ballot(svA == gmA));   // lowest slot = lowest idx
    unsigned giA = (unsigned)__builtin_amdgcn_readlane((int)siA, sA);
    float gB = svB;
    gB = DPPMAX(gB, 0x111); gB = DPPMAX(gB, 0x112); gB = DPPMAX(gB, 0x114);
    gB = DPPMAX(gB, 0x118); gB = DPPMAX(gB, 0x142); gB = DPPMAX(gB, 0x143);
    float gmB = __uint_as_float(__builtin_amdgcn_readlane(__float_as_uint(gB), 63));
    int sB = (int)__builtin_ctzll(__ballot(svB == gmB));
    unsigned giB = (unsigned)__builtin_amdgcn_readlane((int)siB, sB);

    // winner coords: uniform global loads (L2-resident; shared by both batches)
    cxA = xA[giA * 3 + 0]; cyA = xA[giA * 3 + 1]; czA = xA[giA * 3 + 2];
    cxB = xB[giB * 3 + 0]; cyB = xB[giB * 3 + 1]; czB = xB[giB * 3 + 2];
    if (tid == 0) {
      cIdx[b0 * SGRP + step] = (int)giA;
      cIdx[b1 * SGRP + step] = (int)giB;
    }
  }
}

// ---------------- kNN v2: cached per-thread min, winner-only rescan, 1 barrier/iter ----
__global__ __launch_bounds__(256) void knn_kernel(const float* __restrict__ xyz,
                                                  const int* __restrict__ cIdx,
                                                  float* __restrict__ nbrDiff,
                                                  float* __restrict__ ctrW,
                                                  float* __restrict__ partials) {
  #pragma clang fp contract(off)
  __shared__ unsigned long long keyBuf[4];
  __shared__ int winners[KNBR];
  const int cid = blockIdx.x;
  const int b = cid >> 9;
  const int tid = threadIdx.x;
  const float* xb = xyz + (size_t)b * NPTS * 3;
  const int cI = cIdx[cid];
  const float cx = xb[cI * 3], cy = xb[cI * 3 + 1], cz = xb[cI * 3 + 2];
  const float cs = (cx * cx + cy * cy) + cz * cz;

  float d2[32];
  float mv = __builtin_inff(); int mi = 0;
  #pragma unroll
  for (int j = 0; j < 32; ++j) {
    int p = tid + (j << 8);
    float x = xb[p * 3], y = xb[p * 3 + 1], z = xb[p * 3 + 2];
    float ps = (x * x + y * y) + z * z;
    float dot = (cx * x + cy * y) + cz * z;
    d2[j] = (cs + ps) - 2.0f * dot;
    if (d2[j] < mv) { mv = d2[j]; mi = p; }   // strict <: lowest p on tie
  }
  if (tid < 4) keyBuf[tid] = 0xFFFFFFFFFFFFFFFFull;
  __syncthreads();

  for (int it = 0; it < KNBR; ++it) {
    if (tid == 0) keyBuf[(it + 2) & 3] = 0xFFFFFFFFFFFFFFFFull;
    float bv = mv; int bi = mi;
    #pragma unroll
    for (int s = 1; s < 64; s <<= 1) {
      float ov = __shfl_xor(bv, s); int oi = __shfl_xor(bi, s);
      if (ov < bv || (ov == bv && oi < bi)) { bv = ov; bi = oi; }
    }
    if ((tid & 63) == 0) {
      unsigned u = __float_as_uint(bv);
      unsigned m = u ^ (unsigned)(((int)u >> 31) | 0x80000000);   // monotone float->uint
      unsigned long long key = (((unsigned long long)m) << 32) | (unsigned long long)bi;
      atomicMin(&keyBuf[it & 3], key);
    }
    __syncthreads();
    unsigned long long k = keyBuf[it & 3];
    int wi = (int)(k & 0x1FFFu);
    if (tid == 0) winners[it] = wi;
    if (tid == (wi & 255)) {     // only the owner rescans its 32 values
      #pragma unroll
      for (int j = 0; j < 32; ++j)
        if (wi == tid + (j << 8)) d2[j] = __builtin_inff();
      mv = __builtin_inff(); mi = 0;
      #pragma unroll
      for (int j = 0; j < 32; ++j)
        if (d2[j] < mv) { mv = d2[j]; mi = tid + (j << 8); }
    }
  }
  __syncthreads();

  // gather diffs + per-center stats partials
  float sum = 0.f, sq = 0.f;
  if (tid < KNBR) {
    int w = winners[tid];
    float dx = xb[w * 3] - cx, dy = xb[w * 3 + 1] - cy, dz = xb[w * 3 + 2] - cz;
    size_t o = ((size_t)cid * KNBR + tid) * 3;
    nbrDiff[o + 0] = dx; nbrDiff[o + 1] = dy; nbrDiff[o + 2] = dz;
    sum = (dx + dy) + dz;
    sq = (dx * dx + dy * dy) + dz * dz;
  }
  if (tid < 64) {
    #pragma unroll
    for (int s = 1; s < 64; s <<= 1) { sum += __shfl_xor(sum, s); sq += __shfl_xor(sq, s); }
    if (tid == 0) { partials[cid * 2] = sum; partials[cid * 2 + 1] = sq; }
  }
  if (tid < 3) ctrW[(size_t)cid * 3 + tid] = xb[cI * 3 + tid];
}

// ---------------- per-batch std (ddof=1), deterministic fp64 tree ----------------
__global__ __launch_bounds__(256) void std_kernel(const float* __restrict__ partials,
                                                  float* __restrict__ stdv) {
  __shared__ double sd[256], sq[256];
  const int b = blockIdx.x, t = threadIdx.x;
  int i0 = (b * 512 + t) * 2;
  sd[t] = (double)partials[i0] + (double)partials[i0 + 512];
  sq[t] = (double)partials[i0 + 1] + (double)partials[i0 + 513];
  for (int st = 128; st > 0; st >>= 1) {
    __syncthreads();
    if (t < st) { sd[t] += sd[t + st]; sq[t] += sq[t + st]; }
  }
  if (t == 0) {
    double n = (double)(SGRP * KNBR * 3);
    double mean = sd[0] / n;
    double var = (sq[0] - sd[0] * mean) / (n - 1.0);
    stdv[b] = (float)sqrt(var);
  }
}

// ---------------- fused group MLP (t-net + pre res_block + maxpool) ----------------
// one block = 4 groups (128 l-columns), 8 waves, MFMA 16x16x32 bf16
static __device__ __forceinline__ void gemm_half(const unsigned short* __restrict__ W,
                                                 const unsigned short* ht,
                                                 int oBase, int n0, int r16, int g4,
                                                 f32x4 acc[3][4]) {
  for (int ks = 0; ks < 12; ++ks) {
    const int kOff = ks * 32 + g4 * 8;
    bf16x8 a[3], bb[4];
    #pragma unroll
    for (int i = 0; i < 3; ++i)
      a[i] = *(const bf16x8*)(W + (size_t)(oBase + i * 16 + r16) * CCH + kOff);
    #pragma unroll
    for (int j = 0; j < 4; ++j)
      bb[j] = *(const bf16x8*)(ht + (n0 + j * 16 + r16) * LDSP + kOff);
    #pragma unroll
    for (int i = 0; i < 3; ++i) {
      #pragma unroll
      for (int j = 0; j < 4; ++j)
        acc[i][j] = __builtin_amdgcn_mfma_f32_16x16x32_bf16(a[i], bb[j], acc[i][j], 0, 0, 0);
    }
  }
}

__global__ __launch_bounds__(512) void group_mlp_kernel(
    const float* __restrict__ alpha, const float* __restrict__ beta,
    const float* __restrict__ WtF, const float* __restrict__ btF,
    const unsigned short* __restrict__ W1, const float* __restrict__ b1,
    const unsigned short* __restrict__ W2, const float* __restrict__ b2,
    const float* __restrict__ nbrDiff, const float* __restrict__ ctrW,
    const float* __restrict__ stdv, unsigned short* __restrict__ feat) {
  __shared__ unsigned short ht[128 * LDSP];
  __shared__ float xtw[128 * 8];
  __shared__ float wtl[CCH * 6];
  __shared__ float btl[CCH];

  const int tid = threadIdx.x;
  const int lane = tid & 63, wid = tid >> 6;
  const int r16 = lane & 15, g4 = lane >> 4;
  const int bid = blockIdx.x;
  const int b = bid >> 7;
  const int sBase = (bid & 127) << 2;

  for (int i = tid; i < CCH * 6; i += 512) wtl[i] = WtF[i];
  for (int i = tid; i < CCH; i += 512) btl[i] = btF[i];

  const float inv = 1.0f / (stdv[b] + 1e-5f);
  if (tid < 128) {
    int g = tid >> 5, kk = tid & 31;
    int cid = b * SGRP + sBase + g;
    const float* nb = nbrDiff + ((size_t)cid * KNBR + kk) * 3;
    const float* cc = ctrW + (size_t)cid * 3;
    #pragma unroll
    for (int c = 0; c < 3; ++c) {
      xtw[tid * 8 + c] = alpha[c] * (nb[c] * inv) + beta[c];
      xtw[tid * 8 + 3 + c] = cc[c];
    }
  }
  __syncthreads();

  // conv1 (t-net, K=6) -> h0 bf16 into ht[l][o]
  {
    int l = tid & 127, oi = tid >> 7;
    float xv[6];
    #pragma unroll
    for (int c = 0; c < 6; ++c) xv[c] = xtw[l * 8 + c];
    for (int j = 0; j < 96; ++j) {
      int o = oi * 96 + j;
      float v = btl[o];
      #pragma unroll
      for (int c = 0; c < 6; ++c) v += wtl[o * 6 + c] * xv[c];
      ht[l * LDSP + o] = f2b(fmaxf(v, 0.0f));
    }
  }
  __syncthreads();

  const int oBase = wid * 48;

  // conv2: h1 = relu(W1 h0 + b1), overwrite ht by l-halves (disjoint rows)
  for (int half = 0; half < 2; ++half) {
    const int n0 = half * 64;
    f32x4 acc[3][4];
    #pragma unroll
    for (int i = 0; i < 3; ++i) {
      #pragma unroll
      for (int j = 0; j < 4; ++j) acc[i][j] = (f32x4){0.f, 0.f, 0.f, 0.f};
    }
    gemm_half(W1, ht, oBase, n0, r16, g4, acc);
    __syncthreads();   // all waves done reading this half's h0 rows
    #pragma unroll
    for (int i = 0; i < 3; ++i) {
      int o4 = oBase + i * 16 + g4 * 4;
      float bs0 = b1[o4], bs1 = b1[o4 + 1], bs2 = b1[o4 + 2], bs3 = b1[o4 + 3];
      #pragma unroll
      for (int j = 0; j < 4; ++j) {
        int row = n0 + j * 16 + r16;
        unsigned u0 = pk2(fmaxf(acc[i][j][0] + bs0, 0.f), fmaxf(acc[i][j][1] + bs1, 0.f));
        unsigned u1 = pk2(fmaxf(acc[i][j][2] + bs2, 0.f), fmaxf(acc[i][j][3] + bs3, 0.f));
        *(uint2*)(ht + row * LDSP + o4) = make_uint2(u0, u1);
      }
    }
    __syncthreads();
  }

  // conv3 + bias + residual(h0 recomputed) + relu + maxpool over K=32
  for (int half = 0; half < 2; ++half) {
    const int n0 = half * 64;
    f32x4 acc[3][4];
    #pragma unroll
    for (int i = 0; i < 3; ++i) {
      #pragma unroll
      for (int j = 0; j < 4; ++j) acc[i][j] = (f32x4){0.f, 0.f, 0.f, 0.f};
    }
    gemm_half(W2, ht, oBase, n0, r16, g4, acc);

    float bias2[3][4];
    #pragma unroll
    for (int i = 0; i < 3; ++i) {
      int o4 = oBase + i * 16 + g4 * 4;
      #pragma unroll
      for (int r = 0; r < 4; ++r) bias2[i][r] = b2[o4 + r];
    }
    float mx[3][2][4];
    #pragma unroll
    for (int i = 0; i < 3; ++i) {
      #pragma unroll
      for (int gg = 0; gg < 2; ++gg) {
        #pragma unroll
        for (int r = 0; r < 4; ++r) mx[i][gg][r] = 0.f;   // values are relu'd (>=0)
      }
    }
    #pragma unroll
    for (int j = 0; j < 4; ++j) {
      int l = n0 + j * 16 + r16;
      float xv[6];
      #pragma unroll
      for (int c = 0; c < 6; ++c) xv[c] = xtw[l * 8 + c];
      #pragma unroll
      for (int i = 0; i < 3; ++i) {
        int o4 = oBase + i * 16 + g4 * 4;
        #pragma unroll
        for (int r = 0; r < 4; ++r) {
          float h0 = btl[o4 + r];
          #pragma unroll
          for (int c = 0; c < 6; ++c) h0 += wtl[(o4 + r) * 6 + c] * xv[c];
          h0 = fmaxf(h0, 0.f);
          float v = fmaxf(acc[i][j][r] + bias2[i][r] + h0, 0.f);
          mx[i][j >> 1][r] = fmaxf(mx[i][j >> 1][r], v);
        }
      }
    }
    #pragma unroll
    for (int i = 0; i < 3; ++i) {
      #pragma unroll
      for (int gg = 0; gg < 2; ++gg) {
        float m0 = mx[i][gg][0], m1 = mx[i][gg][1], m2 = mx[i][gg][2], m3 = mx[i][gg][3];
        #pragma unroll
        for (int s = 1; s < 16; s <<= 1) {
          m0 = fmaxf(m0, __shfl_xor(m0, s));
          m1 = fmaxf(m1, __shfl_xor(m1, s));
          m2 = fmaxf(m2, __shfl_xor(m2, s));
          m3 = fmaxf(m3, __shfl_xor(m3, s));
        }
        if (r16 == 0) {
          int sIdx = sBase + half * 2 + gg;
          size_t fi = ((size_t)(b * SGRP + sIdx)) * CCH + oBase + i * 16 + g4 * 4;
          *(uint2*)(feat + fi) = make_uint2(pk2(m0, m1), pk2(m2, m3));
        }
      }
    }
  }
}

// ---------------- pos res_block on feat (B,384,512) + final transpose to (B,S,C) fp32 ----------------
__global__ __launch_bounds__(256) void pos_kernel(const unsigned short* __restrict__ feat,
                                                  const unsigned short* __restrict__ Wp1,
                                                  const float* __restrict__ bp1,
                                                  const unsigned short* __restrict__ Wp2,
                                                  const float* __restrict__ bp2,
                                                  float* __restrict__ out) {
  __shared__ unsigned short h1[16 * LDSP];
  const int tid = threadIdx.x;
  const int lane = tid & 63, wid = tid >> 6;
  const int r16 = lane & 15, g4 = lane >> 4;
  const int bid = blockIdx.x;
  const int b = bid >> 5;
  const int s0 = (bid & 31) << 4;
  const size_t rowBase = ((size_t)(b * SGRP + s0 + r16)) * CCH;

  f32x4 acc[6];
  #pragma unroll
  for (int i = 0; i < 6; ++i) acc[i] = (f32x4){0.f, 0.f, 0.f, 0.f};
  for (int ks = 0; ks < 12; ++ks) {
    const int kOff = ks * 32 + g4 * 8;
    bf16x8 bfr = *(const bf16x8*)(feat + rowBase + kOff);
    #pragma unroll
    for (int i = 0; i < 6; ++i) {
      bf16x8 a = *(const bf16x8*)(Wp1 + (size_t)(wid * 96 + i * 16 + r16) * CCH + kOff);
      acc[i] = __builtin_amdgcn_mfma_f32_16x16x32_bf16(a, bfr, acc[i], 0, 0, 0);
    }
  }
  #pragma unroll
  for (int i = 0; i < 6; ++i) {
    int o4 = wid * 96 + i * 16 + g4 * 4;
    unsigned u0 = pk2(fmaxf(acc[i][0] + bp1[o4 + 0], 0.f), fmaxf(acc[i][1] + bp1[o4 + 1], 0.f));
    unsigned u1 = pk2(fmaxf(acc[i][2] + bp1[o4 + 2], 0.f), fmaxf(acc[i][3] + bp1[o4 + 3], 0.f));
    *(uint2*)(h1 + r16 * LDSP + o4) = make_uint2(u0, u1);
  }
  __syncthreads();

  f32x4 acc2[6];
  #pragma unroll
  for (int i = 0; i < 6; ++i) acc2[i] = (f32x4){0.f, 0.f, 0.f, 0.f};
  for (int ks = 0; ks < 12; ++ks) {
    const int kOff = ks * 32 + g4 * 8;
    bf16x8 bfr = *(const bf16x8*)(h1 + r16 * LDSP + kOff);
    #pragma unroll
    for (int i = 0; i < 6; ++i) {
      bf16x8 a = *(const bf16x8*)(Wp2 + (size_t)(wid * 96 + i * 16 + r16) * CCH + kOff);
      acc2[i] = __builtin_amdgcn_mfma_f32_16x16x32_bf16(a, bfr, acc2[i], 0, 0, 0);
    }
  }
  #pragma unroll
  for (int i = 0; i < 6; ++i) {
    int o4 = wid * 96 + i * 16 + g4 * 4;
    uint2 rr = *(const uint2*)(feat + rowBase + o4);
    float4 v;
    v.x = fmaxf(acc2[i][0] + bp2[o4 + 0] + b2f((unsigned short)(rr.x & 0xffff)), 0.f);
    v.y = fmaxf(acc2[i][1] + bp2[o4 + 1] + b2f((unsigned short)(rr.x >> 16)), 0.f);
    v.z = fmaxf(acc2[i][2] + bp2[o4 + 2] + b2f((unsigned short)(rr.y & 0xffff)), 0.f);
    v.w = fmaxf(acc2[i][3] + bp2[o4 + 3] + b2f((unsigned short)(rr.y >> 16)), 0.f);
    *(float4*)(out + rowBase + o4) = v;
  }
}

// ---------------- launch ----------------
extern "C" void kernel_launch(void* const* d_in, const int* in_sizes, int n_in,
                              void* d_out, int out_size, void* d_ws, size_t ws_size,
                              hipStream_t stream) {
  (void)in_sizes; (void)n_in; (void)out_size; (void)ws_size;
  const float* xyz   = (const float*)d_in[0];
  const float* alpha = (const float*)d_in[1];
  const float* beta  = (const float*)d_in[2];
  const float* Wt    = (const float*)d_in[3];
  const float* bt    = (const float*)d_in[4];
  const float* gt    = (const float*)d_in[5];
  const float* bbt   = (const float*)d_in[6];
  const float* Wpre1 = (const float*)d_in[7];
  const float* bpre1 = (const float*)d_in[8];
  const float* gpre1 = (const float*)d_in[9];
  const float* bbpre1= (const float*)d_in[10];
  const float* Wpre2 = (const float*)d_in[11];
  const float* bpre2 = (const float*)d_in[12];
  const float* gpre2 = (const float*)d_in[13];
  const float* bbpre2= (const float*)d_in[14];
  const float* Wpos1 = (const float*)d_in[15];
  const float* bpos1 = (const float*)d_in[16];
  const float* gpos1 = (const float*)d_in[17];
  const float* bbpos1= (const float*)d_in[18];
  const float* Wpos2 = (const float*)d_in[19];
  const float* bpos2 = (const float*)d_in[20];
  const float* gpos2 = (const float*)d_in[21];
  const float* bbpos2= (const float*)d_in[22];

  char* ws = (char*)d_ws;
  size_t off = 0;
  auto alloc = [&](size_t bytes) -> void* {
    void* p = ws + off;
    off += (bytes + 255) & ~(size_t)255;
    return p;
  };
  float* WtF = (float*)alloc(CCH * 6 * 4);
  float* btF = (float*)alloc(CCH * 4);
  unsigned short* W1 = (unsigned short*)alloc(CCH * CCH * 2);
  float* b1 = (float*)alloc(CCH * 4);
  unsigned short* W2 = (unsigned short*)alloc(CCH * CCH * 2);
  float* b2 = (float*)alloc(CCH * 4);
  unsigned short* Wp1 = (unsigned short*)alloc(CCH * CCH * 2);
  float* bp1 = (float*)alloc(CCH * 4);
  unsigned short* Wp2 = (unsigned short*)alloc(CCH * CCH * 2);
  float* bp2 = (float*)alloc(CCH * 4);
  int* cIdx = (int*)alloc(8 * SGRP * 4);
  float* ctrW = (float*)alloc(8 * SGRP * 3 * 4);
  float* nbrD = (float*)alloc((size_t)8 * SGRP * KNBR * 3 * 4);
  float* partials = (float*)alloc(8 * SGRP * 2 * 4);
  float* stdv = (float*)alloc(8 * 4);
  unsigned short* feat = (unsigned short*)alloc((size_t)8 * SGRP * CCH * 2);

  fold_w_f32<<<CCH, 64, 0, stream>>>(Wt, bt, gt, bbt, WtF, btF, 6);
  FoldArgs fa0{Wpre1, bpre1, gpre1, bbpre1, W1, b1};
  FoldArgs fa1{Wpre2, bpre2, gpre2, bbpre2, W2, b2};
  FoldArgs fa2{Wpos1, bpos1, gpos1, bbpos1, Wp1, bp1};
  FoldArgs fa3{Wpos2, bpos2, gpos2, bbpos2, Wp2, bp2};
  fold4_bf16<<<dim3(CCH, 4), 128, 0, stream>>>(fa0, fa1, fa2, fa3);

  fps_kernel<<<4, 1024, 0, stream>>>(xyz, cIdx);
  knn_kernel<<<8 * SGRP, 256, 0, stream>>>(xyz, cIdx, nbrD, ctrW, partials);
  std_kernel<<<8, 256, 0, stream>>>(partials, stdv);
  group_mlp_kernel<<<1024, 512, 0, stream>>>(alpha, beta, WtF, btF, W1, b1, W2, b2,
                                             nbrD, ctrW, stdv, feat);
  pos_kernel<<<256, 256, 0, stream>>>(feat, Wp1, bp1, Wp2, bp2, (float*)d_out);
}

// Round 7
// 1179.662 us; speedup vs baseline: 3.0213x; 1.4754x over previous
//
#include <hip/hip_runtime.h>
#include <hip/hip_bf16.h>
#include <math.h>

typedef __bf16 bf16x8 __attribute__((ext_vector_type(8)));
typedef float f32x4 __attribute__((ext_vector_type(4)));

#define NPTS 8192
#define SGRP 512
#define KNBR 32
#define CCH 384
#define LDSP 392   // padded ushort row stride for [l][c] LDS tiles

static __device__ __forceinline__ unsigned short f2b(float f) {
  union { float f; unsigned u; } v; v.f = f;
  return (unsigned short)((v.u + 0x7fffu + ((v.u >> 16) & 1u)) >> 16);
}
static __device__ __forceinline__ float b2f(unsigned short u) {
  union { unsigned u; float f; } v; v.u = ((unsigned)u) << 16;
  return v.f;
}
static __device__ __forceinline__ unsigned pk2(float a, float b) {
  return (unsigned)f2b(a) | ((unsigned)f2b(b) << 16);
}

// fmax with DPP-shifted self (identity 0 for invalid lanes: distances are >= 0)
#define DPPMAX(v, ctrl) \
  fmaxf((v), __int_as_float(__builtin_amdgcn_update_dpp(0, __float_as_int(v), (ctrl), 0xf, 0xf, false)))

// ---------------- weight folding: bn(conv(x)) = (W*s)x + (b*s+bb) ----------------
struct FoldArgs {
  const float *W, *b, *g, *bb;
  unsigned short* Wd;
  float* bd;
};
__global__ void fold4_bf16(FoldArgs a0, FoldArgs a1, FoldArgs a2, FoldArgs a3) {
  FoldArgs a = (blockIdx.y == 0) ? a0 : (blockIdx.y == 1) ? a1 : (blockIdx.y == 2) ? a2 : a3;
  int o = blockIdx.x;
  float sc = a.g[o] / sqrtf(1.0f + 1e-5f);
  for (int c = threadIdx.x; c < CCH; c += blockDim.x)
    a.Wd[o * CCH + c] = f2b(a.W[o * CCH + c] * sc);
  if (threadIdx.x == 0) a.bd[o] = a.b[o] * sc + a.bb[o];
}
__global__ void fold_w_f32(const float* __restrict__ W, const float* __restrict__ b,
                           const float* __restrict__ g, const float* __restrict__ bb,
                           float* __restrict__ Wd, float* __restrict__ bd, int Cin) {
  int o = blockIdx.x;
  float sc = g[o] / sqrtf(1.0f + 1e-5f);
  for (int c = threadIdx.x; c < Cin; c += blockDim.x)
    Wd[o * Cin + c] = W[o * Cin + c] * sc;
  if (threadIdx.x == 0) bd[o] = b[o] * sc + bb[o];
}

// ---------------- FPS v7: v3 base + coord-carry + in-register slot combine -------
// 8 blocks x 512 threads; thread tid owns points [tid*16, tid*16+16) in registers
// (64 data VGPRs; plain __launch_bounds__(512) -- the only config the allocator
// has never spilled). Contiguous ownership + strict > => numpy first-max ties.
// Winner coords are cndmask-carried through the dist loop and travel via
// readlane -> 5 scalar LDS slots; cross-wave combine is in-register (lane l
// reads slot l&7, full-wave DPP max, ballot/ctz, readlane). One barrier/step,
// parity-double-buffered slots; no trailing dependent coordinate reads.
__global__ __launch_bounds__(512) void fps_kernel(const float* __restrict__ xyz,
                                                  int* __restrict__ cIdx) {
  #pragma clang fp contract(off)
  __shared__ float slotV[2][8], slotX[2][8], slotY[2][8], slotZ[2][8];
  __shared__ unsigned slotI[2][8];
  const int b = blockIdx.x, tid = threadIdx.x;
  const int lane = tid & 63, wid = tid >> 6;
  const float* xb = xyz + (size_t)b * NPTS * 3;

  float X[16], Y[16], Z[16], D[16];
  {
    const float4* src = (const float4*)xb + tid * 12;
    float tmp[48];
    #pragma unroll
    for (int q = 0; q < 12; ++q) {
      float4 t = src[q];
      tmp[q * 4 + 0] = t.x; tmp[q * 4 + 1] = t.y;
      tmp[q * 4 + 2] = t.z; tmp[q * 4 + 3] = t.w;
    }
    #pragma unroll
    for (int j = 0; j < 16; ++j) {
      X[j] = tmp[j * 3 + 0]; Y[j] = tmp[j * 3 + 1]; Z[j] = tmp[j * 3 + 2];
      D[j] = __builtin_inff();
    }
  }
  if (tid == 0) cIdx[b * SGRP] = 0;
  float cx = xb[0], cy = xb[1], cz = xb[2];
  const int tbase = tid * 16;

  for (int step = 1; step < SGRP; ++step) {
    const int par = step & 1;
    // dist update + in-thread argmax with coord carry (strict >: first max)
    float bv = -1.0f; int bi = 0; float bx = 0.f, by = 0.f, bz = 0.f;
    #pragma unroll
    for (int j = 0; j < 16; ++j) {
      float dx = X[j] - cx, dy = Y[j] - cy, dz = Z[j] - cz;
      float d = (dx * dx + dy * dy) + dz * dz;   // contract off: numpy ulp-exact
      float nd = fminf(D[j], d);
      D[j] = nd;
      if (nd > bv) { bv = nd; bi = tbase + j; bx = X[j]; by = Y[j]; bz = Z[j]; }
    }
    // wave prefix-max (value only), pure VALU
    float m = bv;
    m = DPPMAX(m, 0x111); m = DPPMAX(m, 0x112); m = DPPMAX(m, 0x114);
    m = DPPMAX(m, 0x118); m = DPPMAX(m, 0x142); m = DPPMAX(m, 0x143);
    float wmax = __uint_as_float(__builtin_amdgcn_readlane(__float_as_uint(m), 63));
    unsigned long long msk = __ballot(bv == wmax);
    int srcLane = (int)__builtin_ctzll(msk);          // lowest lane == lowest index
    unsigned wbi = (unsigned)__builtin_amdgcn_readlane(bi, srcLane);
    unsigned wx = (unsigned)__builtin_amdgcn_readlane(__float_as_int(bx), srcLane);
    unsigned wy = (unsigned)__builtin_amdgcn_readlane(__float_as_int(by), srcLane);
    unsigned wz = (unsigned)__builtin_amdgcn_readlane(__float_as_int(bz), srcLane);
    if (lane == 0) {
      slotV[par][wid] = wmax;      slotI[par][wid] = wbi;
      slotX[par][wid] = __uint_as_float(wx);
      slotY[par][wid] = __uint_as_float(wy);
      slotZ[par][wid] = __uint_as_float(wz);
    }
    __syncthreads();   // the only barrier per step
    // in-register cross-wave combine: lane l holds slot l&7 (broadcast reads)
    const int sl = lane & 7;
    float sv = slotV[par][sl];
    unsigned si = slotI[par][sl];
    float sx = slotX[par][sl], sy = slotY[par][sl], sz = slotZ[par][sl];
    float g = sv;
    g = DPPMAX(g, 0x111); g = DPPMAX(g, 0x112); g = DPPMAX(g, 0x114);
    g = DPPMAX(g, 0x118); g = DPPMAX(g, 0x142); g = DPPMAX(g, 0x143);
    float gm = __uint_as_float(__builtin_amdgcn_readlane(__float_as_uint(g), 63));
    int l0 = (int)__builtin_ctzll(__ballot(sv == gm));  // lowest lane = lowest slot
    cx = __uint_as_float((unsigned)__builtin_amdgcn_readlane(__float_as_int(sx), l0));
    cy = __uint_as_float((unsigned)__builtin_amdgcn_readlane(__float_as_int(sy), l0));
    cz = __uint_as_float((unsigned)__builtin_amdgcn_readlane(__float_as_int(sz), l0));
    unsigned gi = (unsigned)__builtin_amdgcn_readlane((int)si, l0);
    if (tid == 0) cIdx[b * SGRP + step] = (int)gi;
  }
}

// ---------------- kNN v2: cached per-thread min, winner-only rescan, 1 barrier/iter ----
__global__ __launch_bounds__(256) void knn_kernel(const float* __restrict__ xyz,
                                                  const int* __restrict__ cIdx,
                                                  float* __restrict__ nbrDiff,
                                                  float* __restrict__ ctrW,
                                                  float* __restrict__ partials) {
  #pragma clang fp contract(off)
  __shared__ unsigned long long keyBuf[4];
  __shared__ int winners[KNBR];
  const int cid = blockIdx.x;
  const int b = cid >> 9;
  const int tid = threadIdx.x;
  const float* xb = xyz + (size_t)b * NPTS * 3;
  const int cI = cIdx[cid];
  const float cx = xb[cI * 3], cy = xb[cI * 3 + 1], cz = xb[cI * 3 + 2];
  const float cs = (cx * cx + cy * cy) + cz * cz;

  float d2[32];
  float mv = __builtin_inff(); int mi = 0;
  #pragma unroll
  for (int j = 0; j < 32; ++j) {
    int p = tid + (j << 8);
    float x = xb[p * 3], y = xb[p * 3 + 1], z = xb[p * 3 + 2];
    float ps = (x * x + y * y) + z * z;
    float dot = (cx * x + cy * y) + cz * z;
    d2[j] = (cs + ps) - 2.0f * dot;
    if (d2[j] < mv) { mv = d2[j]; mi = p; }   // strict <: lowest p on tie
  }
  if (tid < 4) keyBuf[tid] = 0xFFFFFFFFFFFFFFFFull;
  __syncthreads();

  for (int it = 0; it < KNBR; ++it) {
    if (tid == 0) keyBuf[(it + 2) & 3] = 0xFFFFFFFFFFFFFFFFull;
    float bv = mv; int bi = mi;
    #pragma unroll
    for (int s = 1; s < 64; s <<= 1) {
      float ov = __shfl_xor(bv, s); int oi = __shfl_xor(bi, s);
      if (ov < bv || (ov == bv && oi < bi)) { bv = ov; bi = oi; }
    }
    if ((tid & 63) == 0) {
      unsigned u = __float_as_uint(bv);
      unsigned m = u ^ (unsigned)(((int)u >> 31) | 0x80000000);   // monotone float->uint
      unsigned long long key = (((unsigned long long)m) << 32) | (unsigned long long)bi;
      atomicMin(&keyBuf[it & 3], key);
    }
    __syncthreads();
    unsigned long long k = keyBuf[it & 3];
    int wi = (int)(k & 0x1FFFu);
    if (tid == 0) winners[it] = wi;
    if (tid == (wi & 255)) {     // only the owner rescans its 32 values
      #pragma unroll
      for (int j = 0; j < 32; ++j)
        if (wi == tid + (j << 8)) d2[j] = __builtin_inff();
      mv = __builtin_inff(); mi = 0;
      #pragma unroll
      for (int j = 0; j < 32; ++j)
        if (d2[j] < mv) { mv = d2[j]; mi = tid + (j << 8); }
    }
  }
  __syncthreads();

  // gather diffs + per-center stats partials
  float sum = 0.f, sq = 0.f;
  if (tid < KNBR) {
    int w = winners[tid];
    float dx = xb[w * 3] - cx, dy = xb[w * 3 + 1] - cy, dz = xb[w * 3 + 2] - cz;
    size_t o = ((size_t)cid * KNBR + tid) * 3;
    nbrDiff[o + 0] = dx; nbrDiff[o + 1] = dy; nbrDiff[o + 2] = dz;
    sum = (dx + dy) + dz;
    sq = (dx * dx + dy * dy) + dz * dz;
  }
  if (tid < 64) {
    #pragma unroll
    for (int s = 1; s < 64; s <<= 1) { sum += __shfl_xor(sum, s); sq += __shfl_xor(sq, s); }
    if (tid == 0) { partials[cid * 2] = sum; partials[cid * 2 + 1] = sq; }
  }
  if (tid < 3) ctrW[(size_t)cid * 3 + tid] = xb[cI * 3 + tid];
}

// ---------------- per-batch std (ddof=1), deterministic fp64 tree ----------------
__global__ __launch_bounds__(256) void std_kernel(const float* __restrict__ partials,
                                                  float* __restrict__ stdv) {
  __shared__ double sd[256], sq[256];
  const int b = blockIdx.x, t = threadIdx.x;
  int i0 = (b * 512 + t) * 2;
  sd[t] = (double)partials[i0] + (double)partials[i0 + 512];
  sq[t] = (double)partials[i0 + 1] + (double)partials[i0 + 513];
  for (int st = 128; st > 0; st >>= 1) {
    __syncthreads();
    if (t < st) { sd[t] += sd[t + st]; sq[t] += sq[t + st]; }
  }
  if (t == 0) {
    double n = (double)(SGRP * KNBR * 3);
    double mean = sd[0] / n;
    double var = (sq[0] - sd[0] * mean) / (n - 1.0);
    stdv[b] = (float)sqrt(var);
  }
}

// ---------------- fused group MLP (t-net + pre res_block + maxpool) ----------------
// one block = 4 groups (128 l-columns), 8 waves, MFMA 16x16x32 bf16
static __device__ __forceinline__ void gemm_half(const unsigned short* __restrict__ W,
                                                 const unsigned short* ht,
                                                 int oBase, int n0, int r16, int g4,
                                                 f32x4 acc[3][4]) {
  for (int ks = 0; ks < 12; ++ks) {
    const int kOff = ks * 32 + g4 * 8;
    bf16x8 a[3], bb[4];
    #pragma unroll
    for (int i = 0; i < 3; ++i)
      a[i] = *(const bf16x8*)(W + (size_t)(oBase + i * 16 + r16) * CCH + kOff);
    #pragma unroll
    for (int j = 0; j < 4; ++j)
      bb[j] = *(const bf16x8*)(ht + (n0 + j * 16 + r16) * LDSP + kOff);
    #pragma unroll
    for (int i = 0; i < 3; ++i) {
      #pragma unroll
      for (int j = 0; j < 4; ++j)
        acc[i][j] = __builtin_amdgcn_mfma_f32_16x16x32_bf16(a[i], bb[j], acc[i][j], 0, 0, 0);
    }
  }
}

__global__ __launch_bounds__(512) void group_mlp_kernel(
    const float* __restrict__ alpha, const float* __restrict__ beta,
    const float* __restrict__ WtF, const float* __restrict__ btF,
    const unsigned short* __restrict__ W1, const float* __restrict__ b1,
    const unsigned short* __restrict__ W2, const float* __restrict__ b2,
    const float* __restrict__ nbrDiff, const float* __restrict__ ctrW,
    const float* __restrict__ stdv, unsigned short* __restrict__ feat) {
  __shared__ unsigned short ht[128 * LDSP];
  __shared__ float xtw[128 * 8];
  __shared__ float wtl[CCH * 6];
  __shared__ float btl[CCH];

  const int tid = threadIdx.x;
  const int lane = tid & 63, wid = tid >> 6;
  const int r16 = lane & 15, g4 = lane >> 4;
  const int bid = blockIdx.x;
  const int b = bid >> 7;
  const int sBase = (bid & 127) << 2;

  for (int i = tid; i < CCH * 6; i += 512) wtl[i] = WtF[i];
  for (int i = tid; i < CCH; i += 512) btl[i] = btF[i];

  const float inv = 1.0f / (stdv[b] + 1e-5f);
  if (tid < 128) {
    int g = tid >> 5, kk = tid & 31;
    int cid = b * SGRP + sBase + g;
    const float* nb = nbrDiff + ((size_t)cid * KNBR + kk) * 3;
    const float* cc = ctrW + (size_t)cid * 3;
    #pragma unroll
    for (int c = 0; c < 3; ++c) {
      xtw[tid * 8 + c] = alpha[c] * (nb[c] * inv) + beta[c];
      xtw[tid * 8 + 3 + c] = cc[c];
    }
  }
  __syncthreads();

  // conv1 (t-net, K=6) -> h0 bf16 into ht[l][o]
  {
    int l = tid & 127, oi = tid >> 7;
    float xv[6];
    #pragma unroll
    for (int c = 0; c < 6; ++c) xv[c] = xtw[l * 8 + c];
    for (int j = 0; j < 96; ++j) {
      int o = oi * 96 + j;
      float v = btl[o];
      #pragma unroll
      for (int c = 0; c < 6; ++c) v += wtl[o * 6 + c] * xv[c];
      ht[l * LDSP + o] = f2b(fmaxf(v, 0.0f));
    }
  }
  __syncthreads();

  const int oBase = wid * 48;

  // conv2: h1 = relu(W1 h0 + b1), overwrite ht by l-halves (disjoint rows)
  for (int half = 0; half < 2; ++half) {
    const int n0 = half * 64;
    f32x4 acc[3][4];
    #pragma unroll
    for (int i = 0; i < 3; ++i) {
      #pragma unroll
      for (int j = 0; j < 4; ++j) acc[i][j] = (f32x4){0.f, 0.f, 0.f, 0.f};
    }
    gemm_half(W1, ht, oBase, n0, r16, g4, acc);
    __syncthreads();   // all waves done reading this half's h0 rows
    #pragma unroll
    for (int i = 0; i < 3; ++i) {
      int o4 = oBase + i * 16 + g4 * 4;
      float bs0 = b1[o4], bs1 = b1[o4 + 1], bs2 = b1[o4 + 2], bs3 = b1[o4 + 3];
      #pragma unroll
      for (int j = 0; j < 4; ++j) {
        int row = n0 + j * 16 + r16;
        unsigned u0 = pk2(fmaxf(acc[i][j][0] + bs0, 0.f), fmaxf(acc[i][j][1] + bs1, 0.f));
        unsigned u1 = pk2(fmaxf(acc[i][j][2] + bs2, 0.f), fmaxf(acc[i][j][3] + bs3, 0.f));
        *(uint2*)(ht + row * LDSP + o4) = make_uint2(u0, u1);
      }
    }
    __syncthreads();
  }

  // conv3 + bias + residual(h0 recomputed) + relu + maxpool over K=32
  for (int half = 0; half < 2; ++half) {
    const int n0 = half * 64;
    f32x4 acc[3][4];
    #pragma unroll
    for (int i = 0; i < 3; ++i) {
      #pragma unroll
      for (int j = 0; j < 4; ++j) acc[i][j] = (f32x4){0.f, 0.f, 0.f, 0.f};
    }
    gemm_half(W2, ht, oBase, n0, r16, g4, acc);

    float bias2[3][4];
    #pragma unroll
    for (int i = 0; i < 3; ++i) {
      int o4 = oBase + i * 16 + g4 * 4;
      #pragma unroll
      for (int r = 0; r < 4; ++r) bias2[i][r] = b2[o4 + r];
    }
    float mx[3][2][4];
    #pragma unroll
    for (int i = 0; i < 3; ++i) {
      #pragma unroll
      for (int gg = 0; gg < 2; ++gg) {
        #pragma unroll
        for (int r = 0; r < 4; ++r) mx[i][gg][r] = 0.f;   // values are relu'd (>=0)
      }
    }
    #pragma unroll
    for (int j = 0; j < 4; ++j) {
      int l = n0 + j * 16 + r16;
      float xv[6];
      #pragma unroll
      for (int c = 0; c < 6; ++c) xv[c] = xtw[l * 8 + c];
      #pragma unroll
      for (int i = 0; i < 3; ++i) {
        int o4 = oBase + i * 16 + g4 * 4;
        #pragma unroll
        for (int r = 0; r < 4; ++r) {
          float h0 = btl[o4 + r];
          #pragma unroll
          for (int c = 0; c < 6; ++c) h0 += wtl[(o4 + r) * 6 + c] * xv[c];
          h0 = fmaxf(h0, 0.f);
          float v = fmaxf(acc[i][j][r] + bias2[i][r] + h0, 0.f);
          mx[i][j >> 1][r] = fmaxf(mx[i][j >> 1][r], v);
        }
      }
    }
    #pragma unroll
    for (int i = 0; i < 3; ++i) {
      #pragma unroll
      for (int gg = 0; gg < 2; ++gg) {
        float m0 = mx[i][gg][0], m1 = mx[i][gg][1], m2 = mx[i][gg][2], m3 = mx[i][gg][3];
        #pragma unroll
        for (int s = 1; s < 16; s <<= 1) {
          m0 = fmaxf(m0, __shfl_xor(m0, s));
          m1 = fmaxf(m1, __shfl_xor(m1, s));
          m2 = fmaxf(m2, __shfl_xor(m2, s));
          m3 = fmaxf(m3, __shfl_xor(m3, s));
        }
        if (r16 == 0) {
          int sIdx = sBase + half * 2 + gg;
          size_t fi = ((size_t)(b * SGRP + sIdx)) * CCH + oBase + i * 16 + g4 * 4;
          *(uint2*)(feat + fi) = make_uint2(pk2(m0, m1), pk2(m2, m3));
        }
      }
    }
  }
}

// ---------------- pos res_block on feat (B,384,512) + final transpose to (B,S,C) fp32 ----------------
__global__ __launch_bounds__(256) void pos_kernel(const unsigned short* __restrict__ feat,
                                                  const unsigned short* __restrict__ Wp1,
                                                  const float* __restrict__ bp1,
                                                  const unsigned short* __restrict__ Wp2,
                                                  const float* __restrict__ bp2,
                                                  float* __restrict__ out) {
  __shared__ unsigned short h1[16 * LDSP];
  const int tid = threadIdx.x;
  const int lane = tid & 63, wid = tid >> 6;
  const int r16 = lane & 15, g4 = lane >> 4;
  const int bid = blockIdx.x;
  const int b = bid >> 5;
  const int s0 = (bid & 31) << 4;
  const size_t rowBase = ((size_t)(b * SGRP + s0 + r16)) * CCH;

  f32x4 acc[6];
  #pragma unroll
  for (int i = 0; i < 6; ++i) acc[i] = (f32x4){0.f, 0.f, 0.f, 0.f};
  for (int ks = 0; ks < 12; ++ks) {
    const int kOff = ks * 32 + g4 * 8;
    bf16x8 bfr = *(const bf16x8*)(feat + rowBase + kOff);
    #pragma unroll
    for (int i = 0; i < 6; ++i) {
      bf16x8 a = *(const bf16x8*)(Wp1 + (size_t)(wid * 96 + i * 16 + r16) * CCH + kOff);
      acc[i] = __builtin_amdgcn_mfma_f32_16x16x32_bf16(a, bfr, acc[i], 0, 0, 0);
    }
  }
  #pragma unroll
  for (int i = 0; i < 6; ++i) {
    int o4 = wid * 96 + i * 16 + g4 * 4;
    unsigned u0 = pk2(fmaxf(acc[i][0] + bp1[o4 + 0], 0.f), fmaxf(acc[i][1] + bp1[o4 + 1], 0.f));
    unsigned u1 = pk2(fmaxf(acc[i][2] + bp1[o4 + 2], 0.f), fmaxf(acc[i][3] + bp1[o4 + 3], 0.f));
    *(uint2*)(h1 + r16 * LDSP + o4) = make_uint2(u0, u1);
  }
  __syncthreads();

  f32x4 acc2[6];
  #pragma unroll
  for (int i = 0; i < 6; ++i) acc2[i] = (f32x4){0.f, 0.f, 0.f, 0.f};
  for (int ks = 0; ks < 12; ++ks) {
    const int kOff = ks * 32 + g4 * 8;
    bf16x8 bfr = *(const bf16x8*)(h1 + r16 * LDSP + kOff);
    #pragma unroll
    for (int i = 0; i < 6; ++i) {
      bf16x8 a = *(const bf16x8*)(Wp2 + (size_t)(wid * 96 + i * 16 + r16) * CCH + kOff);
      acc2[i] = __builtin_amdgcn_mfma_f32_16x16x32_bf16(a, bfr, acc2[i], 0, 0, 0);
    }
  }
  #pragma unroll
  for (int i = 0; i < 6; ++i) {
    int o4 = wid * 96 + i * 16 + g4 * 4;
    uint2 rr = *(const uint2*)(feat + rowBase + o4);
    float4 v;
    v.x = fmaxf(acc2[i][0] + bp2[o4 + 0] + b2f((unsigned short)(rr.x & 0xffff)), 0.f);
    v.y = fmaxf(acc2[i][1] + bp2[o4 + 1] + b2f((unsigned short)(rr.x >> 16)), 0.f);
    v.z = fmaxf(acc2[i][2] + bp2[o4 + 2] + b2f((unsigned short)(rr.y & 0xffff)), 0.f);
    v.w = fmaxf(acc2[i][3] + bp2[o4 + 3] + b2f((unsigned short)(rr.y >> 16)), 0.f);
    *(float4*)(out + rowBase + o4) = v;
  }
}

// ---------------- launch ----------------
extern "C" void kernel_launch(void* const* d_in, const int* in_sizes, int n_in,
                              void* d_out, int out_size, void* d_ws, size_t ws_size,
                              hipStream_t stream) {
  (void)in_sizes; (void)n_in; (void)out_size; (void)ws_size;
  const float* xyz   = (const float*)d_in[0];
  const float* alpha = (const float*)d_in[1];
  const float* beta  = (const float*)d_in[2];
  const float* Wt    = (const float*)d_in[3];
  const float* bt    = (const float*)d_in[4];
  const float* gt    = (const float*)d_in[5];
  const float* bbt   = (const float*)d_in[6];
  const float* Wpre1 = (const float*)d_in[7];
  const float* bpre1 = (const float*)d_in[8];
  const float* gpre1 = (const float*)d_in[9];
  const float* bbpre1= (const float*)d_in[10];
  const float* Wpre2 = (const float*)d_in[11];
  const float* bpre2 = (const float*)d_in[12];
  const float* gpre2 = (const float*)d_in[13];
  const float* bbpre2= (const float*)d_in[14];
  const float* Wpos1 = (const float*)d_in[15];
  const float* bpos1 = (const float*)d_in[16];
  const float* gpos1 = (const float*)d_in[17];
  const float* bbpos1= (const float*)d_in[18];
  const float* Wpos2 = (const float*)d_in[19];
  const float* bpos2 = (const float*)d_in[20];
  const float* gpos2 = (const float*)d_in[21];
  const float* bbpos2= (const float*)d_in[22];

  char* ws = (char*)d_ws;
  size_t off = 0;
  auto alloc = [&](size_t bytes) -> void* {
    void* p = ws + off;
    off += (bytes + 255) & ~(size_t)255;
    return p;
  };
  float* WtF = (float*)alloc(CCH * 6 * 4);
  float* btF = (float*)alloc(CCH * 4);
  unsigned short* W1 = (unsigned short*)alloc(CCH * CCH * 2);
  float* b1 = (float*)alloc(CCH * 4);
  unsigned short* W2 = (unsigned short*)alloc(CCH * CCH * 2);
  float* b2 = (float*)alloc(CCH * 4);
  unsigned short* Wp1 = (unsigned short*)alloc(CCH * CCH * 2);
  float* bp1 = (float*)alloc(CCH * 4);
  unsigned short* Wp2 = (unsigned short*)alloc(CCH * CCH * 2);
  float* bp2 = (float*)alloc(CCH * 4);
  int* cIdx = (int*)alloc(8 * SGRP * 4);
  float* ctrW = (float*)alloc(8 * SGRP * 3 * 4);
  float* nbrD = (float*)alloc((size_t)8 * SGRP * KNBR * 3 * 4);
  float* partials = (float*)alloc(8 * SGRP * 2 * 4);
  float* stdv = (float*)alloc(8 * 4);
  unsigned short* feat = (unsigned short*)alloc((size_t)8 * SGRP * CCH * 2);

  fold_w_f32<<<CCH, 64, 0, stream>>>(Wt, bt, gt, bbt, WtF, btF, 6);
  FoldArgs fa0{Wpre1, bpre1, gpre1, bbpre1, W1, b1};
  FoldArgs fa1{Wpre2, bpre2, gpre2, bbpre2, W2, b2};
  FoldArgs fa2{Wpos1, bpos1, gpos1, bbpos1, Wp1, bp1};
  FoldArgs fa3{Wpos2, bpos2, gpos2, bbpos2, Wp2, bp2};
  fold4_bf16<<<dim3(CCH, 4), 128, 0, stream>>>(fa0, fa1, fa2, fa3);

  fps_kernel<<<8, 512, 0, stream>>>(xyz, cIdx);
  knn_kernel<<<8 * SGRP, 256, 0, stream>>>(xyz, cIdx, nbrD, ctrW, partials);
  std_kernel<<<8, 256, 0, stream>>>(partials, stdv);
  group_mlp_kernel<<<1024, 512, 0, stream>>>(alpha, beta, WtF, btF, W1, b1, W2, b2,
                                             nbrD, ctrW, stdv, feat);
  pos_kernel<<<256, 256, 0, stream>>>(feat, Wp1, bp1, Wp2, bp2, (float*)d_out);
}

// Round 8
// 1176.734 us; speedup vs baseline: 3.0288x; 1.0025x over previous
//
#include <hip/hip_runtime.h>
#include <hip/hip_bf16.h>
#include <math.h>

typedef __bf16 bf16x8 __attribute__((ext_vector_type(8)));
typedef float f32x4 __attribute__((ext_vector_type(4)));

#define NPTS 8192
#define SGRP 512
#define KNBR 32
#define CCH 384
#define LDSP 392   // padded ushort row stride for [l][c] LDS tiles

static __device__ __forceinline__ unsigned short f2b(float f) {
  union { float f; unsigned u; } v; v.f = f;
  return (unsigned short)((v.u + 0x7fffu + ((v.u >> 16) & 1u)) >> 16);
}
static __device__ __forceinline__ float b2f(unsigned short u) {
  union { unsigned u; float f; } v; v.u = ((unsigned)u) << 16;
  return v.f;
}
static __device__ __forceinline__ unsigned pk2(float a, float b) {
  return (unsigned)f2b(a) | ((unsigned)f2b(b) << 16);
}

// fmax with DPP-shifted self (identity 0 for invalid lanes: distances are >= 0)
#define DPPMAX(v, ctrl) \
  fmaxf((v), __int_as_float(__builtin_amdgcn_update_dpp(0, __float_as_int(v), (ctrl), 0xf, 0xf, false)))

// ---------------- weight folding: bn(conv(x)) = (W*s)x + (b*s+bb) ----------------
struct FoldArgs {
  const float *W, *b, *g, *bb;
  unsigned short* Wd;
  float* bd;
};
__global__ void fold4_bf16(FoldArgs a0, FoldArgs a1, FoldArgs a2, FoldArgs a3) {
  FoldArgs a = (blockIdx.y == 0) ? a0 : (blockIdx.y == 1) ? a1 : (blockIdx.y == 2) ? a2 : a3;
  int o = blockIdx.x;
  float sc = a.g[o] / sqrtf(1.0f + 1e-5f);
  for (int c = threadIdx.x; c < CCH; c += blockDim.x)
    a.Wd[o * CCH + c] = f2b(a.W[o * CCH + c] * sc);
  if (threadIdx.x == 0) a.bd[o] = a.b[o] * sc + a.bb[o];
}
__global__ void fold_w_f32(const float* __restrict__ W, const float* __restrict__ b,
                           const float* __restrict__ g, const float* __restrict__ bb,
                           float* __restrict__ Wd, float* __restrict__ bd, int Cin) {
  int o = blockIdx.x;
  float sc = g[o] / sqrtf(1.0f + 1e-5f);
  for (int c = threadIdx.x; c < Cin; c += blockDim.x)
    Wd[o * Cin + c] = W[o * Cin + c] * sc;
  if (threadIdx.x == 0) bd[o] = b[o] * sc + bb[o];
}

// ---------------- FPS v8: v7 + waves_per_eu(1,2) to stop the spill heuristic ----
// Diagnosis across r3-r7: the AMDGPU allocator targets the max occupancy the
// LDS footprint permits. Tiny LDS => it targets 8 waves/SIMD => 64 VGPRs =>
// spills the 64-VGPR point arrays. amdgpu_waves_per_eu(1,2) pins the target to
// <=2 waves/EU (register budget 256) -- what v3 got implicitly from 96KB LDS.
// 8 blocks x 512 threads; thread tid owns points [tid*16, tid*16+16) in regs.
// Contiguous ownership + strict > => numpy first-max ties. Winner coords are
// cndmask-carried through the dist loop; cross-wave combine is in-register
// (lane l reads slot l&7, DPP max, ballot/ctz, readlane). One barrier/step.
__global__ __launch_bounds__(512)
__attribute__((amdgpu_waves_per_eu(1, 2)))
void fps_kernel(const float* __restrict__ xyz, int* __restrict__ cIdx) {
  #pragma clang fp contract(off)
  __shared__ float slotV[2][8], slotX[2][8], slotY[2][8], slotZ[2][8];
  __shared__ unsigned slotI[2][8];
  const int b = blockIdx.x, tid = threadIdx.x;
  const int lane = tid & 63, wid = tid >> 6;
  const float* xb = xyz + (size_t)b * NPTS * 3;

  float X[16], Y[16], Z[16], D[16];
  {
    const float4* src = (const float4*)xb + tid * 12;
    float tmp[48];
    #pragma unroll
    for (int q = 0; q < 12; ++q) {
      float4 t = src[q];
      tmp[q * 4 + 0] = t.x; tmp[q * 4 + 1] = t.y;
      tmp[q * 4 + 2] = t.z; tmp[q * 4 + 3] = t.w;
    }
    #pragma unroll
    for (int j = 0; j < 16; ++j) {
      X[j] = tmp[j * 3 + 0]; Y[j] = tmp[j * 3 + 1]; Z[j] = tmp[j * 3 + 2];
      D[j] = __builtin_inff();
    }
  }
  if (tid == 0) cIdx[b * SGRP] = 0;
  float cx = xb[0], cy = xb[1], cz = xb[2];
  const int tbase = tid * 16;

  for (int step = 1; step < SGRP; ++step) {
    const int par = step & 1;
    // dist update + in-thread argmax with coord carry (strict >: first max)
    float bv = -1.0f; int bi = 0; float bx = 0.f, by = 0.f, bz = 0.f;
    #pragma unroll
    for (int j = 0; j < 16; ++j) {
      float dx = X[j] - cx, dy = Y[j] - cy, dz = Z[j] - cz;
      float d = (dx * dx + dy * dy) + dz * dz;   // contract off: numpy ulp-exact
      float nd = fminf(D[j], d);
      D[j] = nd;
      if (nd > bv) { bv = nd; bi = tbase + j; bx = X[j]; by = Y[j]; bz = Z[j]; }
    }
    // wave prefix-max (value only), pure VALU
    float m = bv;
    m = DPPMAX(m, 0x111); m = DPPMAX(m, 0x112); m = DPPMAX(m, 0x114);
    m = DPPMAX(m, 0x118); m = DPPMAX(m, 0x142); m = DPPMAX(m, 0x143);
    float wmax = __uint_as_float(__builtin_amdgcn_readlane(__float_as_uint(m), 63));
    unsigned long long msk = __ballot(bv == wmax);
    int srcLane = (int)__builtin_ctzll(msk);          // lowest lane == lowest index
    unsigned wbi = (unsigned)__builtin_amdgcn_readlane(bi, srcLane);
    unsigned wx = (unsigned)__builtin_amdgcn_readlane(__float_as_int(bx), srcLane);
    unsigned wy = (unsigned)__builtin_amdgcn_readlane(__float_as_int(by), srcLane);
    unsigned wz = (unsigned)__builtin_amdgcn_readlane(__float_as_int(bz), srcLane);
    if (lane == 0) {
      slotV[par][wid] = wmax;      slotI[par][wid] = wbi;
      slotX[par][wid] = __uint_as_float(wx);
      slotY[par][wid] = __uint_as_float(wy);
      slotZ[par][wid] = __uint_as_float(wz);
    }
    __syncthreads();   // the only barrier per step
    // in-register cross-wave combine: lane l holds slot l&7 (broadcast reads)
    const int sl = lane & 7;
    float sv = slotV[par][sl];
    unsigned si = slotI[par][sl];
    float sx = slotX[par][sl], sy = slotY[par][sl], sz = slotZ[par][sl];
    float g = sv;
    g = DPPMAX(g, 0x111); g = DPPMAX(g, 0x112); g = DPPMAX(g, 0x114);
    g = DPPMAX(g, 0x118); g = DPPMAX(g, 0x142); g = DPPMAX(g, 0x143);
    float gm = __uint_as_float(__builtin_amdgcn_readlane(__float_as_uint(g), 63));
    int l0 = (int)__builtin_ctzll(__ballot(sv == gm));  // lowest lane = lowest slot
    cx = __uint_as_float((unsigned)__builtin_amdgcn_readlane(__float_as_int(sx), l0));
    cy = __uint_as_float((unsigned)__builtin_amdgcn_readlane(__float_as_int(sy), l0));
    cz = __uint_as_float((unsigned)__builtin_amdgcn_readlane(__float_as_int(sz), l0));
    unsigned gi = (unsigned)__builtin_amdgcn_readlane((int)si, l0);
    if (tid == 0) cIdx[b * SGRP + step] = (int)gi;
  }
}

// ---------------- kNN v2: cached per-thread min, winner-only rescan, 1 barrier/iter ----
__global__ __launch_bounds__(256) void knn_kernel(const float* __restrict__ xyz,
                                                  const int* __restrict__ cIdx,
                                                  float* __restrict__ nbrDiff,
                                                  float* __restrict__ ctrW,
                                                  float* __restrict__ partials) {
  #pragma clang fp contract(off)
  __shared__ unsigned long long keyBuf[4];
  __shared__ int winners[KNBR];
  const int cid = blockIdx.x;
  const int b = cid >> 9;
  const int tid = threadIdx.x;
  const float* xb = xyz + (size_t)b * NPTS * 3;
  const int cI = cIdx[cid];
  const float cx = xb[cI * 3], cy = xb[cI * 3 + 1], cz = xb[cI * 3 + 2];
  const float cs = (cx * cx + cy * cy) + cz * cz;

  float d2[32];
  float mv = __builtin_inff(); int mi = 0;
  #pragma unroll
  for (int j = 0; j < 32; ++j) {
    int p = tid + (j << 8);
    float x = xb[p * 3], y = xb[p * 3 + 1], z = xb[p * 3 + 2];
    float ps = (x * x + y * y) + z * z;
    float dot = (cx * x + cy * y) + cz * z;
    d2[j] = (cs + ps) - 2.0f * dot;
    if (d2[j] < mv) { mv = d2[j]; mi = p; }   // strict <: lowest p on tie
  }
  if (tid < 4) keyBuf[tid] = 0xFFFFFFFFFFFFFFFFull;
  __syncthreads();

  for (int it = 0; it < KNBR; ++it) {
    if (tid == 0) keyBuf[(it + 2) & 3] = 0xFFFFFFFFFFFFFFFFull;
    float bv = mv; int bi = mi;
    #pragma unroll
    for (int s = 1; s < 64; s <<= 1) {
      float ov = __shfl_xor(bv, s); int oi = __shfl_xor(bi, s);
      if (ov < bv || (ov == bv && oi < bi)) { bv = ov; bi = oi; }
    }
    if ((tid & 63) == 0) {
      unsigned u = __float_as_uint(bv);
      unsigned m = u ^ (unsigned)(((int)u >> 31) | 0x80000000);   // monotone float->uint
      unsigned long long key = (((unsigned long long)m) << 32) | (unsigned long long)bi;
      atomicMin(&keyBuf[it & 3], key);
    }
    __syncthreads();
    unsigned long long k = keyBuf[it & 3];
    int wi = (int)(k & 0x1FFFu);
    if (tid == 0) winners[it] = wi;
    if (tid == (wi & 255)) {     // only the owner rescans its 32 values
      #pragma unroll
      for (int j = 0; j < 32; ++j)
        if (wi == tid + (j << 8)) d2[j] = __builtin_inff();
      mv = __builtin_inff(); mi = 0;
      #pragma unroll
      for (int j = 0; j < 32; ++j)
        if (d2[j] < mv) { mv = d2[j]; mi = tid + (j << 8); }
    }
  }
  __syncthreads();

  // gather diffs + per-center stats partials
  float sum = 0.f, sq = 0.f;
  if (tid < KNBR) {
    int w = winners[tid];
    float dx = xb[w * 3] - cx, dy = xb[w * 3 + 1] - cy, dz = xb[w * 3 + 2] - cz;
    size_t o = ((size_t)cid * KNBR + tid) * 3;
    nbrDiff[o + 0] = dx; nbrDiff[o + 1] = dy; nbrDiff[o + 2] = dz;
    sum = (dx + dy) + dz;
    sq = (dx * dx + dy * dy) + dz * dz;
  }
  if (tid < 64) {
    #pragma unroll
    for (int s = 1; s < 64; s <<= 1) { sum += __shfl_xor(sum, s); sq += __shfl_xor(sq, s); }
    if (tid == 0) { partials[cid * 2] = sum; partials[cid * 2 + 1] = sq; }
  }
  if (tid < 3) ctrW[(size_t)cid * 3 + tid] = xb[cI * 3 + tid];
}

// ---------------- per-batch std (ddof=1), deterministic fp64 tree ----------------
__global__ __launch_bounds__(256) void std_kernel(const float* __restrict__ partials,
                                                  float* __restrict__ stdv) {
  __shared__ double sd[256], sq[256];
  const int b = blockIdx.x, t = threadIdx.x;
  int i0 = (b * 512 + t) * 2;
  sd[t] = (double)partials[i0] + (double)partials[i0 + 512];
  sq[t] = (double)partials[i0 + 1] + (double)partials[i0 + 513];
  for (int st = 128; st > 0; st >>= 1) {
    __syncthreads();
    if (t < st) { sd[t] += sd[t + st]; sq[t] += sq[t + st]; }
  }
  if (t == 0) {
    double n = (double)(SGRP * KNBR * 3);
    double mean = sd[0] / n;
    double var = (sq[0] - sd[0] * mean) / (n - 1.0);
    stdv[b] = (float)sqrt(var);
  }
}

// ---------------- fused group MLP (t-net + pre res_block + maxpool) ----------------
// one block = 4 groups (128 l-columns), 8 waves, MFMA 16x16x32 bf16
static __device__ __forceinline__ void gemm_half(const unsigned short* __restrict__ W,
                                                 const unsigned short* ht,
                                                 int oBase, int n0, int r16, int g4,
                                                 f32x4 acc[3][4]) {
  for (int ks = 0; ks < 12; ++ks) {
    const int kOff = ks * 32 + g4 * 8;
    bf16x8 a[3], bb[4];
    #pragma unroll
    for (int i = 0; i < 3; ++i)
      a[i] = *(const bf16x8*)(W + (size_t)(oBase + i * 16 + r16) * CCH + kOff);
    #pragma unroll
    for (int j = 0; j < 4; ++j)
      bb[j] = *(const bf16x8*)(ht + (n0 + j * 16 + r16) * LDSP + kOff);
    #pragma unroll
    for (int i = 0; i < 3; ++i) {
      #pragma unroll
      for (int j = 0; j < 4; ++j)
        acc[i][j] = __builtin_amdgcn_mfma_f32_16x16x32_bf16(a[i], bb[j], acc[i][j], 0, 0, 0);
    }
  }
}

__global__ __launch_bounds__(512) void group_mlp_kernel(
    const float* __restrict__ alpha, const float* __restrict__ beta,
    const float* __restrict__ WtF, const float* __restrict__ btF,
    const unsigned short* __restrict__ W1, const float* __restrict__ b1,
    const unsigned short* __restrict__ W2, const float* __restrict__ b2,
    const float* __restrict__ nbrDiff, const float* __restrict__ ctrW,
    const float* __restrict__ stdv, unsigned short* __restrict__ feat) {
  __shared__ unsigned short ht[128 * LDSP];
  __shared__ float xtw[128 * 8];
  __shared__ float wtl[CCH * 6];
  __shared__ float btl[CCH];

  const int tid = threadIdx.x;
  const int lane = tid & 63, wid = tid >> 6;
  const int r16 = lane & 15, g4 = lane >> 4;
  const int bid = blockIdx.x;
  const int b = bid >> 7;
  const int sBase = (bid & 127) << 2;

  for (int i = tid; i < CCH * 6; i += 512) wtl[i] = WtF[i];
  for (int i = tid; i < CCH; i += 512) btl[i] = btF[i];

  const float inv = 1.0f / (stdv[b] + 1e-5f);
  if (tid < 128) {
    int g = tid >> 5, kk = tid & 31;
    int cid = b * SGRP + sBase + g;
    const float* nb = nbrDiff + ((size_t)cid * KNBR + kk) * 3;
    const float* cc = ctrW + (size_t)cid * 3;
    #pragma unroll
    for (int c = 0; c < 3; ++c) {
      xtw[tid * 8 + c] = alpha[c] * (nb[c] * inv) + beta[c];
      xtw[tid * 8 + 3 + c] = cc[c];
    }
  }
  __syncthreads();

  // conv1 (t-net, K=6) -> h0 bf16 into ht[l][o]
  {
    int l = tid & 127, oi = tid >> 7;
    float xv[6];
    #pragma unroll
    for (int c = 0; c < 6; ++c) xv[c] = xtw[l * 8 + c];
    for (int j = 0; j < 96; ++j) {
      int o = oi * 96 + j;
      float v = btl[o];
      #pragma unroll
      for (int c = 0; c < 6; ++c) v += wtl[o * 6 + c] * xv[c];
      ht[l * LDSP + o] = f2b(fmaxf(v, 0.0f));
    }
  }
  __syncthreads();

  const int oBase = wid * 48;

  // conv2: h1 = relu(W1 h0 + b1), overwrite ht by l-halves (disjoint rows)
  for (int half = 0; half < 2; ++half) {
    const int n0 = half * 64;
    f32x4 acc[3][4];
    #pragma unroll
    for (int i = 0; i < 3; ++i) {
      #pragma unroll
      for (int j = 0; j < 4; ++j) acc[i][j] = (f32x4){0.f, 0.f, 0.f, 0.f};
    }
    gemm_half(W1, ht, oBase, n0, r16, g4, acc);
    __syncthreads();   // all waves done reading this half's h0 rows
    #pragma unroll
    for (int i = 0; i < 3; ++i) {
      int o4 = oBase + i * 16 + g4 * 4;
      float bs0 = b1[o4], bs1 = b1[o4 + 1], bs2 = b1[o4 + 2], bs3 = b1[o4 + 3];
      #pragma unroll
      for (int j = 0; j < 4; ++j) {
        int row = n0 + j * 16 + r16;
        unsigned u0 = pk2(fmaxf(acc[i][j][0] + bs0, 0.f), fmaxf(acc[i][j][1] + bs1, 0.f));
        unsigned u1 = pk2(fmaxf(acc[i][j][2] + bs2, 0.f), fmaxf(acc[i][j][3] + bs3, 0.f));
        *(uint2*)(ht + row * LDSP + o4) = make_uint2(u0, u1);
      }
    }
    __syncthreads();
  }

  // conv3 + bias + residual(h0 recomputed) + relu + maxpool over K=32
  for (int half = 0; half < 2; ++half) {
    const int n0 = half * 64;
    f32x4 acc[3][4];
    #pragma unroll
    for (int i = 0; i < 3; ++i) {
      #pragma unroll
      for (int j = 0; j < 4; ++j) acc[i][j] = (f32x4){0.f, 0.f, 0.f, 0.f};
    }
    gemm_half(W2, ht, oBase, n0, r16, g4, acc);

    float bias2[3][4];
    #pragma unroll
    for (int i = 0; i < 3; ++i) {
      int o4 = oBase + i * 16 + g4 * 4;
      #pragma unroll
      for (int r = 0; r < 4; ++r) bias2[i][r] = b2[o4 + r];
    }
    float mx[3][2][4];
    #pragma unroll
    for (int i = 0; i < 3; ++i) {
      #pragma unroll
      for (int gg = 0; gg < 2; ++gg) {
        #pragma unroll
        for (int r = 0; r < 4; ++r) mx[i][gg][r] = 0.f;   // values are relu'd (>=0)
      }
    }
    #pragma unroll
    for (int j = 0; j < 4; ++j) {
      int l = n0 + j * 16 + r16;
      float xv[6];
      #pragma unroll
      for (int c = 0; c < 6; ++c) xv[c] = xtw[l * 8 + c];
      #pragma unroll
      for (int i = 0; i < 3; ++i) {
        int o4 = oBase + i * 16 + g4 * 4;
        #pragma unroll
        for (int r = 0; r < 4; ++r) {
          float h0 = btl[o4 + r];
          #pragma unroll
          for (int c = 0; c < 6; ++c) h0 += wtl[(o4 + r) * 6 + c] * xv[c];
          h0 = fmaxf(h0, 0.f);
          float v = fmaxf(acc[i][j][r] + bias2[i][r] + h0, 0.f);
          mx[i][j >> 1][r] = fmaxf(mx[i][j >> 1][r], v);
        }
      }
    }
    #pragma unroll
    for (int i = 0; i < 3; ++i) {
      #pragma unroll
      for (int gg = 0; gg < 2; ++gg) {
        float m0 = mx[i][gg][0], m1 = mx[i][gg][1], m2 = mx[i][gg][2], m3 = mx[i][gg][3];
        #pragma unroll
        for (int s = 1; s < 16; s <<= 1) {
          m0 = fmaxf(m0, __shfl_xor(m0, s));
          m1 = fmaxf(m1, __shfl_xor(m1, s));
          m2 = fmaxf(m2, __shfl_xor(m2, s));
          m3 = fmaxf(m3, __shfl_xor(m3, s));
        }
        if (r16 == 0) {
          int sIdx = sBase + half * 2 + gg;
          size_t fi = ((size_t)(b * SGRP + sIdx)) * CCH + oBase + i * 16 + g4 * 4;
          *(uint2*)(feat + fi) = make_uint2(pk2(m0, m1), pk2(m2, m3));
        }
      }
    }
  }
}

// ---------------- pos res_block on feat (B,384,512) + final transpose to (B,S,C) fp32 ----------------
__global__ __launch_bounds__(256) void pos_kernel(const unsigned short* __restrict__ feat,
                                                  const unsigned short* __restrict__ Wp1,
                                                  const float* __restrict__ bp1,
                                                  const unsigned short* __restrict__ Wp2,
                                                  const float* __restrict__ bp2,
                                                  float* __restrict__ out) {
  __shared__ unsigned short h1[16 * LDSP];
  const int tid = threadIdx.x;
  const int lane = tid & 63, wid = tid >> 6;
  const int r16 = lane & 15, g4 = lane >> 4;
  const int bid = blockIdx.x;
  const int b = bid >> 5;
  const int s0 = (bid & 31) << 4;
  const size_t rowBase = ((size_t)(b * SGRP + s0 + r16)) * CCH;

  f32x4 acc[6];
  #pragma unroll
  for (int i = 0; i < 6; ++i) acc[i] = (f32x4){0.f, 0.f, 0.f, 0.f};
  for (int ks = 0; ks < 12; ++ks) {
    const int kOff = ks * 32 + g4 * 8;
    bf16x8 bfr = *(const bf16x8*)(feat + rowBase + kOff);
    #pragma unroll
    for (int i = 0; i < 6; ++i) {
      bf16x8 a = *(const bf16x8*)(Wp1 + (size_t)(wid * 96 + i * 16 + r16) * CCH + kOff);
      acc[i] = __builtin_amdgcn_mfma_f32_16x16x32_bf16(a, bfr, acc[i], 0, 0, 0);
    }
  }
  #pragma unroll
  for (int i = 0; i < 6; ++i) {
    int o4 = wid * 96 + i * 16 + g4 * 4;
    unsigned u0 = pk2(fmaxf(acc[i][0] + bp1[o4 + 0], 0.f), fmaxf(acc[i][1] + bp1[o4 + 1], 0.f));
    unsigned u1 = pk2(fmaxf(acc[i][2] + bp1[o4 + 2], 0.f), fmaxf(acc[i][3] + bp1[o4 + 3], 0.f));
    *(uint2*)(h1 + r16 * LDSP + o4) = make_uint2(u0, u1);
  }
  __syncthreads();

  f32x4 acc2[6];
  #pragma unroll
  for (int i = 0; i < 6; ++i) acc2[i] = (f32x4){0.f, 0.f, 0.f, 0.f};
  for (int ks = 0; ks < 12; ++ks) {
    const int kOff = ks * 32 + g4 * 8;
    bf16x8 bfr = *(const bf16x8*)(h1 + r16 * LDSP + kOff);
    #pragma unroll
    for (int i = 0; i < 6; ++i) {
      bf16x8 a = *(const bf16x8*)(Wp2 + (size_t)(wid * 96 + i * 16 + r16) * CCH + kOff);
      acc2[i] = __builtin_amdgcn_mfma_f32_16x16x32_bf16(a, bfr, acc2[i], 0, 0, 0);
    }
  }
  #pragma unroll
  for (int i = 0; i < 6; ++i) {
    int o4 = wid * 96 + i * 16 + g4 * 4;
    uint2 rr = *(const uint2*)(feat + rowBase + o4);
    float4 v;
    v.x = fmaxf(acc2[i][0] + bp2[o4 + 0] + b2f((unsigned short)(rr.x & 0xffff)), 0.f);
    v.y = fmaxf(acc2[i][1] + bp2[o4 + 1] + b2f((unsigned short)(rr.x >> 16)), 0.f);
    v.z = fmaxf(acc2[i][2] + bp2[o4 + 2] + b2f((unsigned short)(rr.y & 0xffff)), 0.f);
    v.w = fmaxf(acc2[i][3] + bp2[o4 + 3] + b2f((unsigned short)(rr.y >> 16)), 0.f);
    *(float4*)(out + rowBase + o4) = v;
  }
}

// ---------------- launch ----------------
extern "C" void kernel_launch(void* const* d_in, const int* in_sizes, int n_in,
                              void* d_out, int out_size, void* d_ws, size_t ws_size,
                              hipStream_t stream) {
  (void)in_sizes; (void)n_in; (void)out_size; (void)ws_size;
  const float* xyz   = (const float*)d_in[0];
  const float* alpha = (const float*)d_in[1];
  const float* beta  = (const float*)d_in[2];
  const float* Wt    = (const float*)d_in[3];
  const float* bt    = (const float*)d_in[4];
  const float* gt    = (const float*)d_in[5];
  const float* bbt   = (const float*)d_in[6];
  const float* Wpre1 = (const float*)d_in[7];
  const float* bpre1 = (const float*)d_in[8];
  const float* gpre1 = (const float*)d_in[9];
  const float* bbpre1= (const float*)d_in[10];
  const float* Wpre2 = (const float*)d_in[11];
  const float* bpre2 = (const float*)d_in[12];
  const float* gpre2 = (const float*)d_in[13];
  const float* bbpre2= (const float*)d_in[14];
  const float* Wpos1 = (const float*)d_in[15];
  const float* bpos1 = (const float*)d_in[16];
  const float* gpos1 = (const float*)d_in[17];
  const float* bbpos1= (const float*)d_in[18];
  const float* Wpos2 = (const float*)d_in[19];
  const float* bpos2 = (const float*)d_in[20];
  const float* gpos2 = (const float*)d_in[21];
  const float* bbpos2= (const float*)d_in[22];

  char* ws = (char*)d_ws;
  size_t off = 0;
  auto alloc = [&](size_t bytes) -> void* {
    void* p = ws + off;
    off += (bytes + 255) & ~(size_t)255;
    return p;
  };
  float* WtF = (float*)alloc(CCH * 6 * 4);
  float* btF = (float*)alloc(CCH * 4);
  unsigned short* W1 = (unsigned short*)alloc(CCH * CCH * 2);
  float* b1 = (float*)alloc(CCH * 4);
  unsigned short* W2 = (unsigned short*)alloc(CCH * CCH * 2);
  float* b2 = (float*)alloc(CCH * 4);
  unsigned short* Wp1 = (unsigned short*)alloc(CCH * CCH * 2);
  float* bp1 = (float*)alloc(CCH * 4);
  unsigned short* Wp2 = (unsigned short*)alloc(CCH * CCH * 2);
  float* bp2 = (float*)alloc(CCH * 4);
  int* cIdx = (int*)alloc(8 * SGRP * 4);
  float* ctrW = (float*)alloc(8 * SGRP * 3 * 4);
  float* nbrD = (float*)alloc((size_t)8 * SGRP * KNBR * 3 * 4);
  float* partials = (float*)alloc(8 * SGRP * 2 * 4);
  float* stdv = (float*)alloc(8 * 4);
  unsigned short* feat = (unsigned short*)alloc((size_t)8 * SGRP * CCH * 2);

  fold_w_f32<<<CCH, 64, 0, stream>>>(Wt, bt, gt, bbt, WtF, btF, 6);
  FoldArgs fa0{Wpre1, bpre1, gpre1, bbpre1, W1, b1};
  FoldArgs fa1{Wpre2, bpre2, gpre2, bbpre2, W2, b2};
  FoldArgs fa2{Wpos1, bpos1, gpos1, bbpos1, Wp1, bp1};
  FoldArgs fa3{Wpos2, bpos2, gpos2, bbpos2, Wp2, bp2};
  fold4_bf16<<<dim3(CCH, 4), 128, 0, stream>>>(fa0, fa1, fa2, fa3);

  fps_kernel<<<8, 512, 0, stream>>>(xyz, cIdx);
  knn_kernel<<<8 * SGRP, 256, 0, stream>>>(xyz, cIdx, nbrD, ctrW, partials);
  std_kernel<<<8, 256, 0, stream>>>(partials, stdv);
  group_mlp_kernel<<<1024, 512, 0, stream>>>(alpha, beta, WtF, btF, W1, b1, W2, b2,
                                             nbrD, ctrW, stdv, feat);
  pos_kernel<<<256, 256, 0, stream>>>(feat, Wp1, bp1, Wp2, bp2, (float*)d_out);
}

// Round 9
// 1157.234 us; speedup vs baseline: 3.0799x; 1.0169x over previous
//
#include <hip/hip_runtime.h>
#include <hip/hip_bf16.h>
#include <math.h>

typedef __bf16 bf16x8 __attribute__((ext_vector_type(8)));
typedef float f32x4 __attribute__((ext_vector_type(4)));

#define NPTS 8192
#define SGRP 512
#define KNBR 32
#define CCH 384
#define LDSP 392   // padded ushort row stride for [l][c] LDS tiles

static __device__ __forceinline__ unsigned short f2b(float f) {
  union { float f; unsigned u; } v; v.f = f;
  return (unsigned short)((v.u + 0x7fffu + ((v.u >> 16) & 1u)) >> 16);
}
static __device__ __forceinline__ float b2f(unsigned short u) {
  union { unsigned u; float f; } v; v.u = ((unsigned)u) << 16;
  return v.f;
}
static __device__ __forceinline__ unsigned pk2(float a, float b) {
  return (unsigned)f2b(a) | ((unsigned)f2b(b) << 16);
}

// fmax with DPP-shifted self (identity 0 for invalid lanes: distances are >= 0)
#define DPPMAX(v, ctrl) \
  fmaxf((v), __int_as_float(__builtin_amdgcn_update_dpp(0, __float_as_int(v), (ctrl), 0xf, 0xf, false)))

// ---------------- weight folding: bn(conv(x)) = (W*s)x + (b*s+bb) ----------------
struct FoldArgs {
  const float *W, *b, *g, *bb;
  unsigned short* Wd;
  float* bd;
};
__global__ void fold4_bf16(FoldArgs a0, FoldArgs a1, FoldArgs a2, FoldArgs a3) {
  FoldArgs a = (blockIdx.y == 0) ? a0 : (blockIdx.y == 1) ? a1 : (blockIdx.y == 2) ? a2 : a3;
  int o = blockIdx.x;
  float sc = a.g[o] / sqrtf(1.0f + 1e-5f);
  for (int c = threadIdx.x; c < CCH; c += blockDim.x)
    a.Wd[o * CCH + c] = f2b(a.W[o * CCH + c] * sc);
  if (threadIdx.x == 0) a.bd[o] = a.b[o] * sc + a.bb[o];
}
__global__ void fold_w_f32(const float* __restrict__ W, const float* __restrict__ b,
                           const float* __restrict__ g, const float* __restrict__ bb,
                           float* __restrict__ Wd, float* __restrict__ bd, int Cin) {
  int o = blockIdx.x;
  float sc = g[o] / sqrtf(1.0f + 1e-5f);
  for (int c = threadIdx.x; c < Cin; c += blockDim.x)
    Wd[o * Cin + c] = W[o * Cin + c] * sc;
  if (threadIdx.x == 0) bd[o] = b[o] * sc + bb[o];
}

// ---------------- FPS v9: v7 structure + 96KB LDS footprint (allocator pin) -----
// r3-r8 diagnosis: the AMDGPU register allocator targets the max occupancy the
// STATIC LDS footprint permits. Tiny LDS -> 8 waves/EU target -> 64-VGPR budget
// -> the 64-VGPR point arrays spill to scratch (r7: VGPR=64, 597us; r5/r6 same).
// amdgpu_waves_per_eu was ignored (r8). The only working knob is LDS size: 96KB
// -> 1 block/CU -> 2 waves/SIMD -> ~256-VGPR budget (r3: 88 VGPR, no spill).
// bigLds below is genuinely used (slots at its head), so the full object is
// allocated. DO NOT SHRINK IT.
// 8 blocks x 512 threads; thread tid owns points [tid*16, tid*16+16) in regs.
// Contiguous ownership + strict > => numpy first-max ties. Winner coords are
// cndmask-carried through the dist loop; cross-wave combine is in-register
// (lane l reads slot l&7, DPP max, ballot/ctz, readlane). One barrier/step.
__global__ __launch_bounds__(512)
void fps_kernel(const float* __restrict__ xyz, int* __restrict__ cIdx) {
  #pragma clang fp contract(off)
  __shared__ float bigLds[24576];           // 96 KB; first 80 floats = slots
  float* slotV = bigLds;                    // [2][8]
  float* slotX = bigLds + 16;               // [2][8]
  float* slotY = bigLds + 32;               // [2][8]
  float* slotZ = bigLds + 48;               // [2][8]
  unsigned* slotI = (unsigned*)(bigLds + 64);  // [2][8]
  const int b = blockIdx.x, tid = threadIdx.x;
  const int lane = tid & 63, wid = tid >> 6;
  const float* xb = xyz + (size_t)b * NPTS * 3;

  float X[16], Y[16], Z[16], D[16];
  {
    const float4* src = (const float4*)xb + tid * 12;
    float tmp[48];
    #pragma unroll
    for (int q = 0; q < 12; ++q) {
      float4 t = src[q];
      tmp[q * 4 + 0] = t.x; tmp[q * 4 + 1] = t.y;
      tmp[q * 4 + 2] = t.z; tmp[q * 4 + 3] = t.w;
    }
    #pragma unroll
    for (int j = 0; j < 16; ++j) {
      X[j] = tmp[j * 3 + 0]; Y[j] = tmp[j * 3 + 1]; Z[j] = tmp[j * 3 + 2];
      D[j] = __builtin_inff();
    }
  }
  if (tid == 0) cIdx[b * SGRP] = 0;
  float cx = xb[0], cy = xb[1], cz = xb[2];
  const int tbase = tid * 16;

  for (int step = 1; step < SGRP; ++step) {
    const int par = step & 1;
    // dist update + in-thread argmax with coord carry (strict >: first max)
    float bv = -1.0f; int bi = 0; float bx = 0.f, by = 0.f, bz = 0.f;
    #pragma unroll
    for (int j = 0; j < 16; ++j) {
      float dx = X[j] - cx, dy = Y[j] - cy, dz = Z[j] - cz;
      float d = (dx * dx + dy * dy) + dz * dz;   // contract off: numpy ulp-exact
      float nd = fminf(D[j], d);
      D[j] = nd;
      if (nd > bv) { bv = nd; bi = tbase + j; bx = X[j]; by = Y[j]; bz = Z[j]; }
    }
    // wave prefix-max (value only), pure VALU
    float m = bv;
    m = DPPMAX(m, 0x111); m = DPPMAX(m, 0x112); m = DPPMAX(m, 0x114);
    m = DPPMAX(m, 0x118); m = DPPMAX(m, 0x142); m = DPPMAX(m, 0x143);
    float wmax = __uint_as_float(__builtin_amdgcn_readlane(__float_as_uint(m), 63));
    unsigned long long msk = __ballot(bv == wmax);
    int srcLane = (int)__builtin_ctzll(msk);          // lowest lane == lowest index
    unsigned wbi = (unsigned)__builtin_amdgcn_readlane(bi, srcLane);
    unsigned wx = (unsigned)__builtin_amdgcn_readlane(__float_as_int(bx), srcLane);
    unsigned wy = (unsigned)__builtin_amdgcn_readlane(__float_as_int(by), srcLane);
    unsigned wz = (unsigned)__builtin_amdgcn_readlane(__float_as_int(bz), srcLane);
    if (lane == 0) {
      slotV[par * 8 + wid] = wmax;      slotI[par * 8 + wid] = wbi;
      slotX[par * 8 + wid] = __uint_as_float(wx);
      slotY[par * 8 + wid] = __uint_as_float(wy);
      slotZ[par * 8 + wid] = __uint_as_float(wz);
    }
    __syncthreads();   // the only barrier per step
    // in-register cross-wave combine: lane l holds slot l&7 (broadcast reads)
    const int sl = par * 8 + (lane & 7);
    float sv = slotV[sl];
    unsigned si = slotI[sl];
    float sx = slotX[sl], sy = slotY[sl], sz = slotZ[sl];
    float g = sv;
    g = DPPMAX(g, 0x111); g = DPPMAX(g, 0x112); g = DPPMAX(g, 0x114);
    g = DPPMAX(g, 0x118); g = DPPMAX(g, 0x142); g = DPPMAX(g, 0x143);
    float gm = __uint_as_float(__builtin_amdgcn_readlane(__float_as_uint(g), 63));
    int l0 = (int)__builtin_ctzll(__ballot(sv == gm));  // lowest lane = lowest slot
    cx = __uint_as_float((unsigned)__builtin_amdgcn_readlane(__float_as_int(sx), l0));
    cy = __uint_as_float((unsigned)__builtin_amdgcn_readlane(__float_as_int(sy), l0));
    cz = __uint_as_float((unsigned)__builtin_amdgcn_readlane(__float_as_int(sz), l0));
    unsigned gi = (unsigned)__builtin_amdgcn_readlane((int)si, l0);
    if (tid == 0) cIdx[b * SGRP + step] = (int)gi;
  }
}

// ---------------- kNN v2: cached per-thread min, winner-only rescan, 1 barrier/iter ----
__global__ __launch_bounds__(256) void knn_kernel(const float* __restrict__ xyz,
                                                  const int* __restrict__ cIdx,
                                                  float* __restrict__ nbrDiff,
                                                  float* __restrict__ ctrW,
                                                  float* __restrict__ partials) {
  #pragma clang fp contract(off)
  __shared__ unsigned long long keyBuf[4];
  __shared__ int winners[KNBR];
  const int cid = blockIdx.x;
  const int b = cid >> 9;
  const int tid = threadIdx.x;
  const float* xb = xyz + (size_t)b * NPTS * 3;
  const int cI = cIdx[cid];
  const float cx = xb[cI * 3], cy = xb[cI * 3 + 1], cz = xb[cI * 3 + 2];
  const float cs = (cx * cx + cy * cy) + cz * cz;

  float d2[32];
  float mv = __builtin_inff(); int mi = 0;
  #pragma unroll
  for (int j = 0; j < 32; ++j) {
    int p = tid + (j << 8);
    float x = xb[p * 3], y = xb[p * 3 + 1], z = xb[p * 3 + 2];
    float ps = (x * x + y * y) + z * z;
    float dot = (cx * x + cy * y) + cz * z;
    d2[j] = (cs + ps) - 2.0f * dot;
    if (d2[j] < mv) { mv = d2[j]; mi = p; }   // strict <: lowest p on tie
  }
  if (tid < 4) keyBuf[tid] = 0xFFFFFFFFFFFFFFFFull;
  __syncthreads();

  for (int it = 0; it < KNBR; ++it) {
    if (tid == 0) keyBuf[(it + 2) & 3] = 0xFFFFFFFFFFFFFFFFull;
    float bv = mv; int bi = mi;
    #pragma unroll
    for (int s = 1; s < 64; s <<= 1) {
      float ov = __shfl_xor(bv, s); int oi = __shfl_xor(bi, s);
      if (ov < bv || (ov == bv && oi < bi)) { bv = ov; bi = oi; }
    }
    if ((tid & 63) == 0) {
      unsigned u = __float_as_uint(bv);
      unsigned m = u ^ (unsigned)(((int)u >> 31) | 0x80000000);   // monotone float->uint
      unsigned long long key = (((unsigned long long)m) << 32) | (unsigned long long)bi;
      atomicMin(&keyBuf[it & 3], key);
    }
    __syncthreads();
    unsigned long long k = keyBuf[it & 3];
    int wi = (int)(k & 0x1FFFu);
    if (tid == 0) winners[it] = wi;
    if (tid == (wi & 255)) {     // only the owner rescans its 32 values
      #pragma unroll
      for (int j = 0; j < 32; ++j)
        if (wi == tid + (j << 8)) d2[j] = __builtin_inff();
      mv = __builtin_inff(); mi = 0;
      #pragma unroll
      for (int j = 0; j < 32; ++j)
        if (d2[j] < mv) { mv = d2[j]; mi = tid + (j << 8); }
    }
  }
  __syncthreads();

  // gather diffs + per-center stats partials
  float sum = 0.f, sq = 0.f;
  if (tid < KNBR) {
    int w = winners[tid];
    float dx = xb[w * 3] - cx, dy = xb[w * 3 + 1] - cy, dz = xb[w * 3 + 2] - cz;
    size_t o = ((size_t)cid * KNBR + tid) * 3;
    nbrDiff[o + 0] = dx; nbrDiff[o + 1] = dy; nbrDiff[o + 2] = dz;
    sum = (dx + dy) + dz;
    sq = (dx * dx + dy * dy) + dz * dz;
  }
  if (tid < 64) {
    #pragma unroll
    for (int s = 1; s < 64; s <<= 1) { sum += __shfl_xor(sum, s); sq += __shfl_xor(sq, s); }
    if (tid == 0) { partials[cid * 2] = sum; partials[cid * 2 + 1] = sq; }
  }
  if (tid < 3) ctrW[(size_t)cid * 3 + tid] = xb[cI * 3 + tid];
}

// ---------------- per-batch std (ddof=1), deterministic fp64 tree ----------------
__global__ __launch_bounds__(256) void std_kernel(const float* __restrict__ partials,
                                                  float* __restrict__ stdv) {
  __shared__ double sd[256], sq[256];
  const int b = blockIdx.x, t = threadIdx.x;
  int i0 = (b * 512 + t) * 2;
  sd[t] = (double)partials[i0] + (double)partials[i0 + 512];
  sq[t] = (double)partials[i0 + 1] + (double)partials[i0 + 513];
  for (int st = 128; st > 0; st >>= 1) {
    __syncthreads();
    if (t < st) { sd[t] += sd[t + st]; sq[t] += sq[t + st]; }
  }
  if (t == 0) {
    double n = (double)(SGRP * KNBR * 3);
    double mean = sd[0] / n;
    double var = (sq[0] - sd[0] * mean) / (n - 1.0);
    stdv[b] = (float)sqrt(var);
  }
}

// ---------------- fused group MLP (t-net + pre res_block + maxpool) ----------------
// one block = 4 groups (128 l-columns), 8 waves, MFMA 16x16x32 bf16
static __device__ __forceinline__ void gemm_half(const unsigned short* __restrict__ W,
                                                 const unsigned short* ht,
                                                 int oBase, int n0, int r16, int g4,
                                                 f32x4 acc[3][4]) {
  for (int ks = 0; ks < 12; ++ks) {
    const int kOff = ks * 32 + g4 * 8;
    bf16x8 a[3], bb[4];
    #pragma unroll
    for (int i = 0; i < 3; ++i)
      a[i] = *(const bf16x8*)(W + (size_t)(oBase + i * 16 + r16) * CCH + kOff);
    #pragma unroll
    for (int j = 0; j < 4; ++j)
      bb[j] = *(const bf16x8*)(ht + (n0 + j * 16 + r16) * LDSP + kOff);
    #pragma unroll
    for (int i = 0; i < 3; ++i) {
      #pragma unroll
      for (int j = 0; j < 4; ++j)
        acc[i][j] = __builtin_amdgcn_mfma_f32_16x16x32_bf16(a[i], bb[j], acc[i][j], 0, 0, 0);
    }
  }
}

__global__ __launch_bounds__(512) void group_mlp_kernel(
    const float* __restrict__ alpha, const float* __restrict__ beta,
    const float* __restrict__ WtF, const float* __restrict__ btF,
    const unsigned short* __restrict__ W1, const float* __restrict__ b1,
    const unsigned short* __restrict__ W2, const float* __restrict__ b2,
    const float* __restrict__ nbrDiff, const float* __restrict__ ctrW,
    const float* __restrict__ stdv, unsigned short* __restrict__ feat) {
  __shared__ unsigned short ht[128 * LDSP];
  __shared__ float xtw[128 * 8];
  __shared__ float wtl[CCH * 6];
  __shared__ float btl[CCH];

  const int tid = threadIdx.x;
  const int lane = tid & 63, wid = tid >> 6;
  const int r16 = lane & 15, g4 = lane >> 4;
  const int bid = blockIdx.x;
  const int b = bid >> 7;
  const int sBase = (bid & 127) << 2;

  for (int i = tid; i < CCH * 6; i += 512) wtl[i] = WtF[i];
  for (int i = tid; i < CCH; i += 512) btl[i] = btF[i];

  const float inv = 1.0f / (stdv[b] + 1e-5f);
  if (tid < 128) {
    int g = tid >> 5, kk = tid & 31;
    int cid = b * SGRP + sBase + g;
    const float* nb = nbrDiff + ((size_t)cid * KNBR + kk) * 3;
    const float* cc = ctrW + (size_t)cid * 3;
    #pragma unroll
    for (int c = 0; c < 3; ++c) {
      xtw[tid * 8 + c] = alpha[c] * (nb[c] * inv) + beta[c];
      xtw[tid * 8 + 3 + c] = cc[c];
    }
  }
  __syncthreads();

  // conv1 (t-net, K=6) -> h0 bf16 into ht[l][o]
  {
    int l = tid & 127, oi = tid >> 7;
    float xv[6];
    #pragma unroll
    for (int c = 0; c < 6; ++c) xv[c] = xtw[l * 8 + c];
    for (int j = 0; j < 96; ++j) {
      int o = oi * 96 + j;
      float v = btl[o];
      #pragma unroll
      for (int c = 0; c < 6; ++c) v += wtl[o * 6 + c] * xv[c];
      ht[l * LDSP + o] = f2b(fmaxf(v, 0.0f));
    }
  }
  __syncthreads();

  const int oBase = wid * 48;

  // conv2: h1 = relu(W1 h0 + b1), overwrite ht by l-halves (disjoint rows)
  for (int half = 0; half < 2; ++half) {
    const int n0 = half * 64;
    f32x4 acc[3][4];
    #pragma unroll
    for (int i = 0; i < 3; ++i) {
      #pragma unroll
      for (int j = 0; j < 4; ++j) acc[i][j] = (f32x4){0.f, 0.f, 0.f, 0.f};
    }
    gemm_half(W1, ht, oBase, n0, r16, g4, acc);
    __syncthreads();   // all waves done reading this half's h0 rows
    #pragma unroll
    for (int i = 0; i < 3; ++i) {
      int o4 = oBase + i * 16 + g4 * 4;
      float bs0 = b1[o4], bs1 = b1[o4 + 1], bs2 = b1[o4 + 2], bs3 = b1[o4 + 3];
      #pragma unroll
      for (int j = 0; j < 4; ++j) {
        int row = n0 + j * 16 + r16;
        unsigned u0 = pk2(fmaxf(acc[i][j][0] + bs0, 0.f), fmaxf(acc[i][j][1] + bs1, 0.f));
        unsigned u1 = pk2(fmaxf(acc[i][j][2] + bs2, 0.f), fmaxf(acc[i][j][3] + bs3, 0.f));
        *(uint2*)(ht + row * LDSP + o4) = make_uint2(u0, u1);
      }
    }
    __syncthreads();
  }

  // conv3 + bias + residual(h0 recomputed) + relu + maxpool over K=32
  for (int half = 0; half < 2; ++half) {
    const int n0 = half * 64;
    f32x4 acc[3][4];
    #pragma unroll
    for (int i = 0; i < 3; ++i) {
      #pragma unroll
      for (int j = 0; j < 4; ++j) acc[i][j] = (f32x4){0.f, 0.f, 0.f, 0.f};
    }
    gemm_half(W2, ht, oBase, n0, r16, g4, acc);

    float bias2[3][4];
    #pragma unroll
    for (int i = 0; i < 3; ++i) {
      int o4 = oBase + i * 16 + g4 * 4;
      #pragma unroll
      for (int r = 0; r < 4; ++r) bias2[i][r] = b2[o4 + r];
    }
    float mx[3][2][4];
    #pragma unroll
    for (int i = 0; i < 3; ++i) {
      #pragma unroll
      for (int gg = 0; gg < 2; ++gg) {
        #pragma unroll
        for (int r = 0; r < 4; ++r) mx[i][gg][r] = 0.f;   // values are relu'd (>=0)
      }
    }
    #pragma unroll
    for (int j = 0; j < 4; ++j) {
      int l = n0 + j * 16 + r16;
      float xv[6];
      #pragma unroll
      for (int c = 0; c < 6; ++c) xv[c] = xtw[l * 8 + c];
      #pragma unroll
      for (int i = 0; i < 3; ++i) {
        int o4 = oBase + i * 16 + g4 * 4;
        #pragma unroll
        for (int r = 0; r < 4; ++r) {
          float h0 = btl[o4 + r];
          #pragma unroll
          for (int c = 0; c < 6; ++c) h0 += wtl[(o4 + r) * 6 + c] * xv[c];
          h0 = fmaxf(h0, 0.f);
          float v = fmaxf(acc[i][j][r] + bias2[i][r] + h0, 0.f);
          mx[i][j >> 1][r] = fmaxf(mx[i][j >> 1][r], v);
        }
      }
    }
    #pragma unroll
    for (int i = 0; i < 3; ++i) {
      #pragma unroll
      for (int gg = 0; gg < 2; ++gg) {
        float m0 = mx[i][gg][0], m1 = mx[i][gg][1], m2 = mx[i][gg][2], m3 = mx[i][gg][3];
        #pragma unroll
        for (int s = 1; s < 16; s <<= 1) {
          m0 = fmaxf(m0, __shfl_xor(m0, s));
          m1 = fmaxf(m1, __shfl_xor(m1, s));
          m2 = fmaxf(m2, __shfl_xor(m2, s));
          m3 = fmaxf(m3, __shfl_xor(m3, s));
        }
        if (r16 == 0) {
          int sIdx = sBase + half * 2 + gg;
          size_t fi = ((size_t)(b * SGRP + sIdx)) * CCH + oBase + i * 16 + g4 * 4;
          *(uint2*)(feat + fi) = make_uint2(pk2(m0, m1), pk2(m2, m3));
        }
      }
    }
  }
}

// ---------------- pos res_block on feat (B,384,512) + final transpose to (B,S,C) fp32 ----------------
__global__ __launch_bounds__(256) void pos_kernel(const unsigned short* __restrict__ feat,
                                                  const unsigned short* __restrict__ Wp1,
                                                  const float* __restrict__ bp1,
                                                  const unsigned short* __restrict__ Wp2,
                                                  const float* __restrict__ bp2,
                                                  float* __restrict__ out) {
  __shared__ unsigned short h1[16 * LDSP];
  const int tid = threadIdx.x;
  const int lane = tid & 63, wid = tid >> 6;
  const int r16 = lane & 15, g4 = lane >> 4;
  const int bid = blockIdx.x;
  const int b = bid >> 5;
  const int s0 = (bid & 31) << 4;
  const size_t rowBase = ((size_t)(b * SGRP + s0 + r16)) * CCH;

  f32x4 acc[6];
  #pragma unroll
  for (int i = 0; i < 6; ++i) acc[i] = (f32x4){0.f, 0.f, 0.f, 0.f};
  for (int ks = 0; ks < 12; ++ks) {
    const int kOff = ks * 32 + g4 * 8;
    bf16x8 bfr = *(const bf16x8*)(feat + rowBase + kOff);
    #pragma unroll
    for (int i = 0; i < 6; ++i) {
      bf16x8 a = *(const bf16x8*)(Wp1 + (size_t)(wid * 96 + i * 16 + r16) * CCH + kOff);
      acc[i] = __builtin_amdgcn_mfma_f32_16x16x32_bf16(a, bfr, acc[i], 0, 0, 0);
    }
  }
  #pragma unroll
  for (int i = 0; i < 6; ++i) {
    int o4 = wid * 96 + i * 16 + g4 * 4;
    unsigned u0 = pk2(fmaxf(acc[i][0] + bp1[o4 + 0], 0.f), fmaxf(acc[i][1] + bp1[o4 + 1], 0.f));
    unsigned u1 = pk2(fmaxf(acc[i][2] + bp1[o4 + 2], 0.f), fmaxf(acc[i][3] + bp1[o4 + 3], 0.f));
    *(uint2*)(h1 + r16 * LDSP + o4) = make_uint2(u0, u1);
  }
  __syncthreads();

  f32x4 acc2[6];
  #pragma unroll
  for (int i = 0; i < 6; ++i) acc2[i] = (f32x4){0.f, 0.f, 0.f, 0.f};
  for (int ks = 0; ks < 12; ++ks) {
    const int kOff = ks * 32 + g4 * 8;
    bf16x8 bfr = *(const bf16x8*)(h1 + r16 * LDSP + kOff);
    #pragma unroll
    for (int i = 0; i < 6; ++i) {
      bf16x8 a = *(const bf16x8*)(Wp2 + (size_t)(wid * 96 + i * 16 + r16) * CCH + kOff);
      acc2[i] = __builtin_amdgcn_mfma_f32_16x16x32_bf16(a, bfr, acc2[i], 0, 0, 0);
    }
  }
  #pragma unroll
  for (int i = 0; i < 6; ++i) {
    int o4 = wid * 96 + i * 16 + g4 * 4;
    uint2 rr = *(const uint2*)(feat + rowBase + o4);
    float4 v;
    v.x = fmaxf(acc2[i][0] + bp2[o4 + 0] + b2f((unsigned short)(rr.x & 0xffff)), 0.f);
    v.y = fmaxf(acc2[i][1] + bp2[o4 + 1] + b2f((unsigned short)(rr.x >> 16)), 0.f);
    v.z = fmaxf(acc2[i][2] + bp2[o4 + 2] + b2f((unsigned short)(rr.y & 0xffff)), 0.f);
    v.w = fmaxf(acc2[i][3] + bp2[o4 + 3] + b2f((unsigned short)(rr.y >> 16)), 0.f);
    *(float4*)(out + rowBase + o4) = v;
  }
}

// ---------------- launch ----------------
extern "C" void kernel_launch(void* const* d_in, const int* in_sizes, int n_in,
                              void* d_out, int out_size, void* d_ws, size_t ws_size,
                              hipStream_t stream) {
  (void)in_sizes; (void)n_in; (void)out_size; (void)ws_size;
  const float* xyz   = (const float*)d_in[0];
  const float* alpha = (const float*)d_in[1];
  const float* beta  = (const float*)d_in[2];
  const float* Wt    = (const float*)d_in[3];
  const float* bt    = (const float*)d_in[4];
  const float* gt    = (const float*)d_in[5];
  const float* bbt   = (const float*)d_in[6];
  const float* Wpre1 = (const float*)d_in[7];
  const float* bpre1 = (const float*)d_in[8];
  const float* gpre1 = (const float*)d_in[9];
  const float* bbpre1= (const float*)d_in[10];
  const float* Wpre2 = (const float*)d_in[11];
  const float* bpre2 = (const float*)d_in[12];
  const float* gpre2 = (const float*)d_in[13];
  const float* bbpre2= (const float*)d_in[14];
  const float* Wpos1 = (const float*)d_in[15];
  const float* bpos1 = (const float*)d_in[16];
  const float* gpos1 = (const float*)d_in[17];
  const float* bbpos1= (const float*)d_in[18];
  const float* Wpos2 = (const float*)d_in[19];
  const float* bpos2 = (const float*)d_in[20];
  const float* gpos2 = (const float*)d_in[21];
  const float* bbpos2= (const float*)d_in[22];

  char* ws = (char*)d_ws;
  size_t off = 0;
  auto alloc = [&](size_t bytes) -> void* {
    void* p = ws + off;
    off += (bytes + 255) & ~(size_t)255;
    return p;
  };
  float* WtF = (float*)alloc(CCH * 6 * 4);
  float* btF = (float*)alloc(CCH * 4);
  unsigned short* W1 = (unsigned short*)alloc(CCH * CCH * 2);
  float* b1 = (float*)alloc(CCH * 4);
  unsigned short* W2 = (unsigned short*)alloc(CCH * CCH * 2);
  float* b2 = (float*)alloc(CCH * 4);
  unsigned short* Wp1 = (unsigned short*)alloc(CCH * CCH * 2);
  float* bp1 = (float*)alloc(CCH * 4);
  unsigned short* Wp2 = (unsigned short*)alloc(CCH * CCH * 2);
  float* bp2 = (float*)alloc(CCH * 4);
  int* cIdx = (int*)alloc(8 * SGRP * 4);
  float* ctrW = (float*)alloc(8 * SGRP * 3 * 4);
  float* nbrD = (float*)alloc((size_t)8 * SGRP * KNBR * 3 * 4);
  float* partials = (float*)alloc(8 * SGRP * 2 * 4);
  float* stdv = (float*)alloc(8 * 4);
  unsigned short* feat = (unsigned short*)alloc((size_t)8 * SGRP * CCH * 2);

  fold_w_f32<<<CCH, 64, 0, stream>>>(Wt, bt, gt, bbt, WtF, btF, 6);
  FoldArgs fa0{Wpre1, bpre1, gpre1, bbpre1, W1, b1};
  FoldArgs fa1{Wpre2, bpre2, gpre2, bbpre2, W2, b2};
  FoldArgs fa2{Wpos1, bpos1, gpos1, bbpos1, Wp1, bp1};
  FoldArgs fa3{Wpos2, bpos2, gpos2, bbpos2, Wp2, bp2};
  fold4_bf16<<<dim3(CCH, 4), 128, 0, stream>>>(fa0, fa1, fa2, fa3);

  fps_kernel<<<8, 512, 0, stream>>>(xyz, cIdx);
  knn_kernel<<<8 * SGRP, 256, 0, stream>>>(xyz, cIdx, nbrD, ctrW, partials);
  std_kernel<<<8, 256, 0, stream>>>(partials, stdv);
  group_mlp_kernel<<<1024, 512, 0, stream>>>(alpha, beta, WtF, btF, W1, b1, W2, b2,
                                             nbrD, ctrW, stdv, feat);
  pos_kernel<<<256, 256, 0, stream>>>(feat, Wp1, bp1, Wp2, bp2, (float*)d_out);
}

// Round 10
// 1131.862 us; speedup vs baseline: 3.1489x; 1.0224x over previous
//
#include <hip/hip_runtime.h>
#include <hip/hip_bf16.h>
#include <math.h>

typedef __bf16 bf16x8 __attribute__((ext_vector_type(8)));
typedef float f32x4 __attribute__((ext_vector_type(4)));

#define NPTS 8192
#define SGRP 512
#define KNBR 32
#define CCH 384
#define LDSP 392   // padded ushort row stride for [l][c] LDS tiles

static __device__ __forceinline__ unsigned short f2b(float f) {
  union { float f; unsigned u; } v; v.f = f;
  return (unsigned short)((v.u + 0x7fffu + ((v.u >> 16) & 1u)) >> 16);
}
static __device__ __forceinline__ float b2f(unsigned short u) {
  union { unsigned u; float f; } v; v.u = ((unsigned)u) << 16;
  return v.f;
}
static __device__ __forceinline__ unsigned pk2(float a, float b) {
  return (unsigned)f2b(a) | ((unsigned)f2b(b) << 16);
}

// fmax with DPP-shifted self (identity 0 for invalid lanes: distances are >= 0)
#define DPPMAX(v, ctrl) \
  fmaxf((v), __int_as_float(__builtin_amdgcn_update_dpp(0, __float_as_int(v), (ctrl), 0xf, 0xf, false)))

// ---------------- weight folding: bn(conv(x)) = (W*s)x + (b*s+bb) ----------------
struct FoldArgs {
  const float *W, *b, *g, *bb;
  unsigned short* Wd;
  float* bd;
};
__global__ void fold4_bf16(FoldArgs a0, FoldArgs a1, FoldArgs a2, FoldArgs a3) {
  FoldArgs a = (blockIdx.y == 0) ? a0 : (blockIdx.y == 1) ? a1 : (blockIdx.y == 2) ? a2 : a3;
  int o = blockIdx.x;
  float sc = a.g[o] / sqrtf(1.0f + 1e-5f);
  for (int c = threadIdx.x; c < CCH; c += blockDim.x)
    a.Wd[o * CCH + c] = f2b(a.W[o * CCH + c] * sc);
  if (threadIdx.x == 0) a.bd[o] = a.b[o] * sc + a.bb[o];
}
__global__ void fold_w_f32(const float* __restrict__ W, const float* __restrict__ b,
                           const float* __restrict__ g, const float* __restrict__ bb,
                           float* __restrict__ Wd, float* __restrict__ bd, int Cin) {
  int o = blockIdx.x;
  float sc = g[o] / sqrtf(1.0f + 1e-5f);
  for (int c = threadIdx.x; c < Cin; c += blockDim.x)
    Wd[o * Cin + c] = W[o * Cin + c] * sc;
  if (threadIdx.x == 0) bd[o] = b[o] * sc + bb[o];
}

// ---------------- FPS v10: 1024 thr x 8 pts, 4 waves/SIMD latency hiding --------
// r9 lesson: fps is VALU-latency-bound (87% VALUBusy at 2 waves/SIMD); the fix
// is more waves + shorter in-thread chains, not tail surgery. 1024 threads ->
// 4 waves/SIMD, 8-deep chain, 32 data VGPRs (live set ~50: spill-safe even at
// a 64-VGPR budget; the 96KB xs/ys/zs LDS additionally caps occupancy at
// 1 block/CU -> allocator budget 128). No coord-carry (r9: it cost more than
// it saved). Contiguous ownership (thread tid owns [tid*8, tid*8+8)) + strict
// > => numpy first-max ties. Tail: 16 slots, 1 barrier, in-register combine
// (lane reads slot lane&15, 4-stage DPP prefix-max, ballot/ctz, readlane),
// then xs[gi] LDS broadcast. Slots parity-double-buffered (barrier-ordered).
__global__ __launch_bounds__(1024)
void fps_kernel(const float* __restrict__ xyz, int* __restrict__ cIdx) {
  #pragma clang fp contract(off)
  __shared__ float xs[NPTS], ys[NPTS], zs[NPTS];   // 96KB: coord lookup + allocator pin
  __shared__ float slotV[2][16];
  __shared__ unsigned slotI[2][16];
  const int tid = threadIdx.x, lane = tid & 63, wid = tid >> 6;   // wid 0..15
  const int b = blockIdx.x;
  const float* xb = xyz + (size_t)b * NPTS * 3;

  float X[8], Y[8], Z[8], D[8];
  {
    const float4* s = (const float4*)xb + tid * 6;
    float4 t0 = s[0], t1 = s[1], t2 = s[2], t3 = s[3], t4 = s[4], t5 = s[5];
    X[0] = t0.x; Y[0] = t0.y; Z[0] = t0.z;
    X[1] = t0.w; Y[1] = t1.x; Z[1] = t1.y;
    X[2] = t1.z; Y[2] = t1.w; Z[2] = t2.x;
    X[3] = t2.y; Y[3] = t2.z; Z[3] = t2.w;
    X[4] = t3.x; Y[4] = t3.y; Z[4] = t3.z;
    X[5] = t3.w; Y[5] = t4.x; Z[5] = t4.y;
    X[6] = t4.z; Y[6] = t4.w; Z[6] = t5.x;
    X[7] = t5.y; Y[7] = t5.z; Z[7] = t5.w;
  }
  #pragma unroll
  for (int j = 0; j < 8; ++j) {
    int p = tid * 8 + j;
    xs[p] = X[j]; ys[p] = Y[j]; zs[p] = Z[j];
    D[j] = __builtin_inff();
  }
  if (tid == 0) cIdx[b * SGRP] = 0;
  __syncthreads();
  float cx = xs[0], cy = ys[0], cz = zs[0];
  const int tbase = tid * 8;

  for (int step = 1; step < SGRP; ++step) {
    const int par = step & 1;
    // dist update + in-thread argmax (strict >: first max; 8-deep chain)
    float bv = -1.0f; int bi = 0;
    #pragma unroll
    for (int j = 0; j < 8; ++j) {
      float dx = X[j] - cx, dy = Y[j] - cy, dz = Z[j] - cz;
      float d = (dx * dx + dy * dy) + dz * dz;   // contract off: numpy ulp-exact
      float nd = fminf(D[j], d);
      D[j] = nd;
      if (nd > bv) { bv = nd; bi = tbase + j; }
    }
    // wave max (value only), pure VALU
    float m = bv;
    m = DPPMAX(m, 0x111); m = DPPMAX(m, 0x112); m = DPPMAX(m, 0x114);
    m = DPPMAX(m, 0x118); m = DPPMAX(m, 0x142); m = DPPMAX(m, 0x143);
    float wmax = __uint_as_float(__builtin_amdgcn_readlane(__float_as_uint(m), 63));
    unsigned long long msk = __ballot(bv == wmax);
    int srcLane = (int)__builtin_ctzll(msk);          // lowest lane == lowest index
    unsigned wbi = (unsigned)__builtin_amdgcn_readlane(bi, srcLane);
    if (lane == 0) { slotV[par][wid] = wmax; slotI[par][wid] = wbi; }
    __syncthreads();   // the only barrier per step
    // in-register 16-slot combine: lane l holds slot l&15 (broadcast reads);
    // 4-stage DPP prefix-max within the 16-lane row -> lane 15 has the max.
    float sv = slotV[par][lane & 15];
    unsigned si = slotI[par][lane & 15];
    float g = sv;
    g = DPPMAX(g, 0x111); g = DPPMAX(g, 0x112); g = DPPMAX(g, 0x114);
    g = DPPMAX(g, 0x118);
    float gm = __uint_as_float(__builtin_amdgcn_readlane(__float_as_uint(g), 15));
    int l0 = (int)__builtin_ctzll(__ballot(sv == gm));  // lowest lane = lowest slot
    unsigned gi = (unsigned)__builtin_amdgcn_readlane((int)si, l0);
    if (tid == 0) cIdx[b * SGRP + step] = (int)gi;
    cx = xs[gi]; cy = ys[gi]; cz = zs[gi];   // LDS broadcast
  }
}

// ---------------- kNN v2: cached per-thread min, winner-only rescan, 1 barrier/iter ----
__global__ __launch_bounds__(256) void knn_kernel(const float* __restrict__ xyz,
                                                  const int* __restrict__ cIdx,
                                                  float* __restrict__ nbrDiff,
                                                  float* __restrict__ ctrW,
                                                  float* __restrict__ partials) {
  #pragma clang fp contract(off)
  __shared__ unsigned long long keyBuf[4];
  __shared__ int winners[KNBR];
  const int cid = blockIdx.x;
  const int b = cid >> 9;
  const int tid = threadIdx.x;
  const float* xb = xyz + (size_t)b * NPTS * 3;
  const int cI = cIdx[cid];
  const float cx = xb[cI * 3], cy = xb[cI * 3 + 1], cz = xb[cI * 3 + 2];
  const float cs = (cx * cx + cy * cy) + cz * cz;

  float d2[32];
  float mv = __builtin_inff(); int mi = 0;
  #pragma unroll
  for (int j = 0; j < 32; ++j) {
    int p = tid + (j << 8);
    float x = xb[p * 3], y = xb[p * 3 + 1], z = xb[p * 3 + 2];
    float ps = (x * x + y * y) + z * z;
    float dot = (cx * x + cy * y) + cz * z;
    d2[j] = (cs + ps) - 2.0f * dot;
    if (d2[j] < mv) { mv = d2[j]; mi = p; }   // strict <: lowest p on tie
  }
  if (tid < 4) keyBuf[tid] = 0xFFFFFFFFFFFFFFFFull;
  __syncthreads();

  for (int it = 0; it < KNBR; ++it) {
    if (tid == 0) keyBuf[(it + 2) & 3] = 0xFFFFFFFFFFFFFFFFull;
    float bv = mv; int bi = mi;
    #pragma unroll
    for (int s = 1; s < 64; s <<= 1) {
      float ov = __shfl_xor(bv, s); int oi = __shfl_xor(bi, s);
      if (ov < bv || (ov == bv && oi < bi)) { bv = ov; bi = oi; }
    }
    if ((tid & 63) == 0) {
      unsigned u = __float_as_uint(bv);
      unsigned m = u ^ (unsigned)(((int)u >> 31) | 0x80000000);   // monotone float->uint
      unsigned long long key = (((unsigned long long)m) << 32) | (unsigned long long)bi;
      atomicMin(&keyBuf[it & 3], key);
    }
    __syncthreads();
    unsigned long long k = keyBuf[it & 3];
    int wi = (int)(k & 0x1FFFu);
    if (tid == 0) winners[it] = wi;
    if (tid == (wi & 255)) {     // only the owner rescans its 32 values
      #pragma unroll
      for (int j = 0; j < 32; ++j)
        if (wi == tid + (j << 8)) d2[j] = __builtin_inff();
      mv = __builtin_inff(); mi = 0;
      #pragma unroll
      for (int j = 0; j < 32; ++j)
        if (d2[j] < mv) { mv = d2[j]; mi = tid + (j << 8); }
    }
  }
  __syncthreads();

  // gather diffs + per-center stats partials
  float sum = 0.f, sq = 0.f;
  if (tid < KNBR) {
    int w = winners[tid];
    float dx = xb[w * 3] - cx, dy = xb[w * 3 + 1] - cy, dz = xb[w * 3 + 2] - cz;
    size_t o = ((size_t)cid * KNBR + tid) * 3;
    nbrDiff[o + 0] = dx; nbrDiff[o + 1] = dy; nbrDiff[o + 2] = dz;
    sum = (dx + dy) + dz;
    sq = (dx * dx + dy * dy) + dz * dz;
  }
  if (tid < 64) {
    #pragma unroll
    for (int s = 1; s < 64; s <<= 1) { sum += __shfl_xor(sum, s); sq += __shfl_xor(sq, s); }
    if (tid == 0) { partials[cid * 2] = sum; partials[cid * 2 + 1] = sq; }
  }
  if (tid < 3) ctrW[(size_t)cid * 3 + tid] = xb[cI * 3 + tid];
}

// ---------------- per-batch std (ddof=1), deterministic fp64 tree ----------------
__global__ __launch_bounds__(256) void std_kernel(const float* __restrict__ partials,
                                                  float* __restrict__ stdv) {
  __shared__ double sd[256], sq[256];
  const int b = blockIdx.x, t = threadIdx.x;
  int i0 = (b * 512 + t) * 2;
  sd[t] = (double)partials[i0] + (double)partials[i0 + 512];
  sq[t] = (double)partials[i0 + 1] + (double)partials[i0 + 513];
  for (int st = 128; st > 0; st >>= 1) {
    __syncthreads();
    if (t < st) { sd[t] += sd[t + st]; sq[t] += sq[t + st]; }
  }
  if (t == 0) {
    double n = (double)(SGRP * KNBR * 3);
    double mean = sd[0] / n;
    double var = (sq[0] - sd[0] * mean) / (n - 1.0);
    stdv[b] = (float)sqrt(var);
  }
}

// ---------------- fused group MLP (t-net + pre res_block + maxpool) ----------------
// one block = 4 groups (128 l-columns), 8 waves, MFMA 16x16x32 bf16
static __device__ __forceinline__ void gemm_half(const unsigned short* __restrict__ W,
                                                 const unsigned short* ht,
                                                 int oBase, int n0, int r16, int g4,
                                                 f32x4 acc[3][4]) {
  for (int ks = 0; ks < 12; ++ks) {
    const int kOff = ks * 32 + g4 * 8;
    bf16x8 a[3], bb[4];
    #pragma unroll
    for (int i = 0; i < 3; ++i)
      a[i] = *(const bf16x8*)(W + (size_t)(oBase + i * 16 + r16) * CCH + kOff);
    #pragma unroll
    for (int j = 0; j < 4; ++j)
      bb[j] = *(const bf16x8*)(ht + (n0 + j * 16 + r16) * LDSP + kOff);
    #pragma unroll
    for (int i = 0; i < 3; ++i) {
      #pragma unroll
      for (int j = 0; j < 4; ++j)
        acc[i][j] = __builtin_amdgcn_mfma_f32_16x16x32_bf16(a[i], bb[j], acc[i][j], 0, 0, 0);
    }
  }
}

__global__ __launch_bounds__(512) void group_mlp_kernel(
    const float* __restrict__ alpha, const float* __restrict__ beta,
    const float* __restrict__ WtF, const float* __restrict__ btF,
    const unsigned short* __restrict__ W1, const float* __restrict__ b1,
    const unsigned short* __restrict__ W2, const float* __restrict__ b2,
    const float* __restrict__ nbrDiff, const float* __restrict__ ctrW,
    const float* __restrict__ stdv, unsigned short* __restrict__ feat) {
  __shared__ unsigned short ht[128 * LDSP];
  __shared__ float xtw[128 * 8];
  __shared__ float wtl[CCH * 6];
  __shared__ float btl[CCH];

  const int tid = threadIdx.x;
  const int lane = tid & 63, wid = tid >> 6;
  const int r16 = lane & 15, g4 = lane >> 4;
  const int bid = blockIdx.x;
  const int b = bid >> 7;
  const int sBase = (bid & 127) << 2;

  for (int i = tid; i < CCH * 6; i += 512) wtl[i] = WtF[i];
  for (int i = tid; i < CCH; i += 512) btl[i] = btF[i];

  const float inv = 1.0f / (stdv[b] + 1e-5f);
  if (tid < 128) {
    int g = tid >> 5, kk = tid & 31;
    int cid = b * SGRP + sBase + g;
    const float* nb = nbrDiff + ((size_t)cid * KNBR + kk) * 3;
    const float* cc = ctrW + (size_t)cid * 3;
    #pragma unroll
    for (int c = 0; c < 3; ++c) {
      xtw[tid * 8 + c] = alpha[c] * (nb[c] * inv) + beta[c];
      xtw[tid * 8 + 3 + c] = cc[c];
    }
  }
  __syncthreads();

  // conv1 (t-net, K=6) -> h0 bf16 into ht[l][o]
  {
    int l = tid & 127, oi = tid >> 7;
    float xv[6];
    #pragma unroll
    for (int c = 0; c < 6; ++c) xv[c] = xtw[l * 8 + c];
    for (int j = 0; j < 96; ++j) {
      int o = oi * 96 + j;
      float v = btl[o];
      #pragma unroll
      for (int c = 0; c < 6; ++c) v += wtl[o * 6 + c] * xv[c];
      ht[l * LDSP + o] = f2b(fmaxf(v, 0.0f));
    }
  }
  __syncthreads();

  const int oBase = wid * 48;

  // conv2: h1 = relu(W1 h0 + b1), overwrite ht by l-halves (disjoint rows)
  for (int half = 0; half < 2; ++half) {
    const int n0 = half * 64;
    f32x4 acc[3][4];
    #pragma unroll
    for (int i = 0; i < 3; ++i) {
      #pragma unroll
      for (int j = 0; j < 4; ++j) acc[i][j] = (f32x4){0.f, 0.f, 0.f, 0.f};
    }
    gemm_half(W1, ht, oBase, n0, r16, g4, acc);
    __syncthreads();   // all waves done reading this half's h0 rows
    #pragma unroll
    for (int i = 0; i < 3; ++i) {
      int o4 = oBase + i * 16 + g4 * 4;
      float bs0 = b1[o4], bs1 = b1[o4 + 1], bs2 = b1[o4 + 2], bs3 = b1[o4 + 3];
      #pragma unroll
      for (int j = 0; j < 4; ++j) {
        int row = n0 + j * 16 + r16;
        unsigned u0 = pk2(fmaxf(acc[i][j][0] + bs0, 0.f), fmaxf(acc[i][j][1] + bs1, 0.f));
        unsigned u1 = pk2(fmaxf(acc[i][j][2] + bs2, 0.f), fmaxf(acc[i][j][3] + bs3, 0.f));
        *(uint2*)(ht + row * LDSP + o4) = make_uint2(u0, u1);
      }
    }
    __syncthreads();
  }

  // conv3 + bias + residual(h0 recomputed) + relu + maxpool over K=32
  for (int half = 0; half < 2; ++half) {
    const int n0 = half * 64;
    f32x4 acc[3][4];
    #pragma unroll
    for (int i = 0; i < 3; ++i) {
      #pragma unroll
      for (int j = 0; j < 4; ++j) acc[i][j] = (f32x4){0.f, 0.f, 0.f, 0.f};
    }
    gemm_half(W2, ht, oBase, n0, r16, g4, acc);

    float bias2[3][4];
    #pragma unroll
    for (int i = 0; i < 3; ++i) {
      int o4 = oBase + i * 16 + g4 * 4;
      #pragma unroll
      for (int r = 0; r < 4; ++r) bias2[i][r] = b2[o4 + r];
    }
    float mx[3][2][4];
    #pragma unroll
    for (int i = 0; i < 3; ++i) {
      #pragma unroll
      for (int gg = 0; gg < 2; ++gg) {
        #pragma unroll
        for (int r = 0; r < 4; ++r) mx[i][gg][r] = 0.f;   // values are relu'd (>=0)
      }
    }
    #pragma unroll
    for (int j = 0; j < 4; ++j) {
      int l = n0 + j * 16 + r16;
      float xv[6];
      #pragma unroll
      for (int c = 0; c < 6; ++c) xv[c] = xtw[l * 8 + c];
      #pragma unroll
      for (int i = 0; i < 3; ++i) {
        int o4 = oBase + i * 16 + g4 * 4;
        #pragma unroll
        for (int r = 0; r < 4; ++r) {
          float h0 = btl[o4 + r];
          #pragma unroll
          for (int c = 0; c < 6; ++c) h0 += wtl[(o4 + r) * 6 + c] * xv[c];
          h0 = fmaxf(h0, 0.f);
          float v = fmaxf(acc[i][j][r] + bias2[i][r] + h0, 0.f);
          mx[i][j >> 1][r] = fmaxf(mx[i][j >> 1][r], v);
        }
      }
    }
    #pragma unroll
    for (int i = 0; i < 3; ++i) {
      #pragma unroll
      for (int gg = 0; gg < 2; ++gg) {
        float m0 = mx[i][gg][0], m1 = mx[i][gg][1], m2 = mx[i][gg][2], m3 = mx[i][gg][3];
        #pragma unroll
        for (int s = 1; s < 16; s <<= 1) {
          m0 = fmaxf(m0, __shfl_xor(m0, s));
          m1 = fmaxf(m1, __shfl_xor(m1, s));
          m2 = fmaxf(m2, __shfl_xor(m2, s));
          m3 = fmaxf(m3, __shfl_xor(m3, s));
        }
        if (r16 == 0) {
          int sIdx = sBase + half * 2 + gg;
          size_t fi = ((size_t)(b * SGRP + sIdx)) * CCH + oBase + i * 16 + g4 * 4;
          *(uint2*)(feat + fi) = make_uint2(pk2(m0, m1), pk2(m2, m3));
        }
      }
    }
  }
}

// ---------------- pos res_block on feat (B,384,512) + final transpose to (B,S,C) fp32 ----------------
__global__ __launch_bounds__(256) void pos_kernel(const unsigned short* __restrict__ feat,
                                                  const unsigned short* __restrict__ Wp1,
                                                  const float* __restrict__ bp1,
                                                  const unsigned short* __restrict__ Wp2,
                                                  const float* __restrict__ bp2,
                                                  float* __restrict__ out) {
  __shared__ unsigned short h1[16 * LDSP];
  const int tid = threadIdx.x;
  const int lane = tid & 63, wid = tid >> 6;
  const int r16 = lane & 15, g4 = lane >> 4;
  const int bid = blockIdx.x;
  const int b = bid >> 5;
  const int s0 = (bid & 31) << 4;
  const size_t rowBase = ((size_t)(b * SGRP + s0 + r16)) * CCH;

  f32x4 acc[6];
  #pragma unroll
  for (int i = 0; i < 6; ++i) acc[i] = (f32x4){0.f, 0.f, 0.f, 0.f};
  for (int ks = 0; ks < 12; ++ks) {
    const int kOff = ks * 32 + g4 * 8;
    bf16x8 bfr = *(const bf16x8*)(feat + rowBase + kOff);
    #pragma unroll
    for (int i = 0; i < 6; ++i) {
      bf16x8 a = *(const bf16x8*)(Wp1 + (size_t)(wid * 96 + i * 16 + r16) * CCH + kOff);
      acc[i] = __builtin_amdgcn_mfma_f32_16x16x32_bf16(a, bfr, acc[i], 0, 0, 0);
    }
  }
  #pragma unroll
  for (int i = 0; i < 6; ++i) {
    int o4 = wid * 96 + i * 16 + g4 * 4;
    unsigned u0 = pk2(fmaxf(acc[i][0] + bp1[o4 + 0], 0.f), fmaxf(acc[i][1] + bp1[o4 + 1], 0.f));
    unsigned u1 = pk2(fmaxf(acc[i][2] + bp1[o4 + 2], 0.f), fmaxf(acc[i][3] + bp1[o4 + 3], 0.f));
    *(uint2*)(h1 + r16 * LDSP + o4) = make_uint2(u0, u1);
  }
  __syncthreads();

  f32x4 acc2[6];
  #pragma unroll
  for (int i = 0; i < 6; ++i) acc2[i] = (f32x4){0.f, 0.f, 0.f, 0.f};
  for (int ks = 0; ks < 12; ++ks) {
    const int kOff = ks * 32 + g4 * 8;
    bf16x8 bfr = *(const bf16x8*)(h1 + r16 * LDSP + kOff);
    #pragma unroll
    for (int i = 0; i < 6; ++i) {
      bf16x8 a = *(const bf16x8*)(Wp2 + (size_t)(wid * 96 + i * 16 + r16) * CCH + kOff);
      acc2[i] = __builtin_amdgcn_mfma_f32_16x16x32_bf16(a, bfr, acc2[i], 0, 0, 0);
    }
  }
  #pragma unroll
  for (int i = 0; i < 6; ++i) {
    int o4 = wid * 96 + i * 16 + g4 * 4;
    uint2 rr = *(const uint2*)(feat + rowBase + o4);
    float4 v;
    v.x = fmaxf(acc2[i][0] + bp2[o4 + 0] + b2f((unsigned short)(rr.x & 0xffff)), 0.f);
    v.y = fmaxf(acc2[i][1] + bp2[o4 + 1] + b2f((unsigned short)(rr.x >> 16)), 0.f);
    v.z = fmaxf(acc2[i][2] + bp2[o4 + 2] + b2f((unsigned short)(rr.y & 0xffff)), 0.f);
    v.w = fmaxf(acc2[i][3] + bp2[o4 + 3] + b2f((unsigned short)(rr.y >> 16)), 0.f);
    *(float4*)(out + rowBase + o4) = v;
  }
}

// ---------------- launch ----------------
extern "C" void kernel_launch(void* const* d_in, const int* in_sizes, int n_in,
                              void* d_out, int out_size, void* d_ws, size_t ws_size,
                              hipStream_t stream) {
  (void)in_sizes; (void)n_in; (void)out_size; (void)ws_size;
  const float* xyz   = (const float*)d_in[0];
  const float* alpha = (const float*)d_in[1];
  const float* beta  = (const float*)d_in[2];
  const float* Wt    = (const float*)d_in[3];
  const float* bt    = (const float*)d_in[4];
  const float* gt    = (const float*)d_in[5];
  const float* bbt   = (const float*)d_in[6];
  const float* Wpre1 = (const float*)d_in[7];
  const float* bpre1 = (const float*)d_in[8];
  const float* gpre1 = (const float*)d_in[9];
  const float* bbpre1= (const float*)d_in[10];
  const float* Wpre2 = (const float*)d_in[11];
  const float* bpre2 = (const float*)d_in[12];
  const float* gpre2 = (const float*)d_in[13];
  const float* bbpre2= (const float*)d_in[14];
  const float* Wpos1 = (const float*)d_in[15];
  const float* bpos1 = (const float*)d_in[16];
  const float* gpos1 = (const float*)d_in[17];
  const float* bbpos1= (const float*)d_in[18];
  const float* Wpos2 = (const float*)d_in[19];
  const float* bpos2 = (const float*)d_in[20];
  const float* gpos2 = (const float*)d_in[21];
  const float* bbpos2= (const float*)d_in[22];

  char* ws = (char*)d_ws;
  size_t off = 0;
  auto alloc = [&](size_t bytes) -> void* {
    void* p = ws + off;
    off += (bytes + 255) & ~(size_t)255;
    return p;
  };
  float* WtF = (float*)alloc(CCH * 6 * 4);
  float* btF = (float*)alloc(CCH * 4);
  unsigned short* W1 = (unsigned short*)alloc(CCH * CCH * 2);
  float* b1 = (float*)alloc(CCH * 4);
  unsigned short* W2 = (unsigned short*)alloc(CCH * CCH * 2);
  float* b2 = (float*)alloc(CCH * 4);
  unsigned short* Wp1 = (unsigned short*)alloc(CCH * CCH * 2);
  float* bp1 = (float*)alloc(CCH * 4);
  unsigned short* Wp2 = (unsigned short*)alloc(CCH * CCH * 2);
  float* bp2 = (float*)alloc(CCH * 4);
  int* cIdx = (int*)alloc(8 * SGRP * 4);
  float* ctrW = (float*)alloc(8 * SGRP * 3 * 4);
  float* nbrD = (float*)alloc((size_t)8 * SGRP * KNBR * 3 * 4);
  float* partials = (float*)alloc(8 * SGRP * 2 * 4);
  float* stdv = (float*)alloc(8 * 4);
  unsigned short* feat = (unsigned short*)alloc((size_t)8 * SGRP * CCH * 2);

  fold_w_f32<<<CCH, 64, 0, stream>>>(Wt, bt, gt, bbt, WtF, btF, 6);
  FoldArgs fa0{Wpre1, bpre1, gpre1, bbpre1, W1, b1};
  FoldArgs fa1{Wpre2, bpre2, gpre2, bbpre2, W2, b2};
  FoldArgs fa2{Wpos1, bpos1, gpos1, bbpos1, Wp1, bp1};
  FoldArgs fa3{Wpos2, bpos2, gpos2, bbpos2, Wp2, bp2};
  fold4_bf16<<<dim3(CCH, 4), 128, 0, stream>>>(fa0, fa1, fa2, fa3);

  fps_kernel<<<8, 1024, 0, stream>>>(xyz, cIdx);
  knn_kernel<<<8 * SGRP, 256, 0, stream>>>(xyz, cIdx, nbrD, ctrW, partials);
  std_kernel<<<8, 256, 0, stream>>>(partials, stdv);
  group_mlp_kernel<<<1024, 512, 0, stream>>>(alpha, beta, WtF, btF, W1, b1, W2, b2,
                                             nbrD, ctrW, stdv, feat);
  pos_kernel<<<256, 256, 0, stream>>>(feat, Wp1, bp1, Wp2, bp2, (float*)d_out);
}

// Round 11
// 999.999 us; speedup vs baseline: 3.5641x; 1.1319x over previous
//
#include <hip/hip_runtime.h>
#include <hip/hip_bf16.h>
#include <math.h>

typedef __bf16 bf16x8 __attribute__((ext_vector_type(8)));
typedef float f32x4 __attribute__((ext_vector_type(4)));
typedef float f32x2 __attribute__((ext_vector_type(2)));

#define NPTS 8192
#define SGRP 512
#define KNBR 32
#define CCH 384
#define LDSP 392   // padded ushort row stride for [l][c] LDS tiles

static __device__ __forceinline__ unsigned short f2b(float f) {
  union { float f; unsigned u; } v; v.f = f;
  return (unsigned short)((v.u + 0x7fffu + ((v.u >> 16) & 1u)) >> 16);
}
static __device__ __forceinline__ float b2f(unsigned short u) {
  union { unsigned u; float f; } v; v.u = ((unsigned)u) << 16;
  return v.f;
}
static __device__ __forceinline__ unsigned pk2(float a, float b) {
  return (unsigned)f2b(a) | ((unsigned)f2b(b) << 16);
}

// fmax/fmin with DPP-shifted self. Identity for shifted-in lanes:
// max: 0 (distances >= 0); min: +inf.
#define DPPMAX(v, ctrl) \
  fmaxf((v), __int_as_float(__builtin_amdgcn_update_dpp(0, __float_as_int(v), (ctrl), 0xf, 0xf, false)))
#define DPPMIN(v, ctrl) \
  fminf((v), __int_as_float(__builtin_amdgcn_update_dpp(0x7f800000, __float_as_int(v), (ctrl), 0xf, 0xf, false)))

// ---------------- weight folding: bn(conv(x)) = (W*s)x + (b*s+bb) ----------------
struct FoldArgs {
  const float *W, *b, *g, *bb;
  unsigned short* Wd;
  float* bd;
};
__global__ void fold4_bf16(FoldArgs a0, FoldArgs a1, FoldArgs a2, FoldArgs a3) {
  FoldArgs a = (blockIdx.y == 0) ? a0 : (blockIdx.y == 1) ? a1 : (blockIdx.y == 2) ? a2 : a3;
  int o = blockIdx.x;
  float sc = a.g[o] / sqrtf(1.0f + 1e-5f);
  for (int c = threadIdx.x; c < CCH; c += blockDim.x)
    a.Wd[o * CCH + c] = f2b(a.W[o * CCH + c] * sc);
  if (threadIdx.x == 0) a.bd[o] = a.b[o] * sc + a.bb[o];
}
__global__ void fold_w_f32(const float* __restrict__ W, const float* __restrict__ b,
                           const float* __restrict__ g, const float* __restrict__ bb,
                           float* __restrict__ Wd, float* __restrict__ bd, int Cin) {
  int o = blockIdx.x;
  float sc = g[o] / sqrtf(1.0f + 1e-5f);
  for (int c = threadIdx.x; c < Cin; c += blockDim.x)
    Wd[o * Cin + c] = W[o * Cin + c] * sc;
  if (threadIdx.x == 0) bd[o] = b[o] * sc + bb[o];
}

// ---------------- FPS v11: v10 + packed-fp32 (v_pk_*) distance loop -------------
// r10: fps is VALU-issue-bound (90% busy on its 8 CUs). CDNA4 has full-rate
// packed 2xfp32 VALU (v_pk_add/mul/min_f32); writing the dist loop on f32x2
// halves its instruction count. pk ops are elementwise IEEE fp32 => results
// bit-identical; .x checked before .y in ascending index order => numpy
// first-max ties preserved. 96KB LDS retained: coord lookup + allocator pin
// (prevents the 64-VGPR-budget spill seen in r5-r8 -- DO NOT SHRINK).
__global__ __launch_bounds__(1024)
void fps_kernel(const float* __restrict__ xyz, int* __restrict__ cIdx) {
  #pragma clang fp contract(off)
  __shared__ float xs[NPTS], ys[NPTS], zs[NPTS];   // 96KB
  __shared__ float slotV[2][16];
  __shared__ unsigned slotI[2][16];
  const int tid = threadIdx.x, lane = tid & 63, wid = tid >> 6;   // wid 0..15
  const int b = blockIdx.x;
  const float* xb = xyz + (size_t)b * NPTS * 3;

  f32x2 X2[4], Y2[4], Z2[4], D2[4];
  {
    const float4* s = (const float4*)xb + tid * 6;
    float4 t0 = s[0], t1 = s[1], t2 = s[2], t3 = s[3], t4 = s[4], t5 = s[5];
    X2[0] = (f32x2){t0.x, t0.w}; Y2[0] = (f32x2){t0.y, t1.x}; Z2[0] = (f32x2){t0.z, t1.y};
    X2[1] = (f32x2){t1.z, t2.y}; Y2[1] = (f32x2){t1.w, t2.z}; Z2[1] = (f32x2){t2.x, t2.w};
    X2[2] = (f32x2){t3.x, t3.w}; Y2[2] = (f32x2){t3.y, t4.x}; Z2[2] = (f32x2){t3.z, t4.y};
    X2[3] = (f32x2){t4.z, t5.y}; Y2[3] = (f32x2){t4.w, t5.z}; Z2[3] = (f32x2){t5.x, t5.w};
  }
  #pragma unroll
  for (int j = 0; j < 4; ++j) {
    int p = tid * 8 + j * 2;
    xs[p] = X2[j].x; ys[p] = Y2[j].x; zs[p] = Z2[j].x;
    xs[p + 1] = X2[j].y; ys[p + 1] = Y2[j].y; zs[p + 1] = Z2[j].y;
    D2[j] = (f32x2){__builtin_inff(), __builtin_inff()};
  }
  if (tid == 0) cIdx[b * SGRP] = 0;
  __syncthreads();
  float cx = xs[0], cy = ys[0], cz = zs[0];
  const int tbase = tid * 8;

  for (int step = 1; step < SGRP; ++step) {
    const int par = step & 1;
    const f32x2 cxv = (f32x2){cx, cx}, cyv = (f32x2){cy, cy}, czv = (f32x2){cz, cz};
    // packed dist update + in-thread argmax (strict >, ascending index order)
    float bv = -1.0f; int bi = 0;
    #pragma unroll
    for (int j = 0; j < 4; ++j) {
      f32x2 dx = X2[j] - cxv, dy = Y2[j] - cyv, dz = Z2[j] - czv;
      f32x2 d = (dx * dx + dy * dy) + dz * dz;   // contract off: numpy ulp-exact
      f32x2 nd = __builtin_elementwise_min(D2[j], d);
      D2[j] = nd;
      if (nd.x > bv) { bv = nd.x; bi = tbase + 2 * j; }
      if (nd.y > bv) { bv = nd.y; bi = tbase + 2 * j + 1; }
    }
    // wave max (value only), pure VALU
    float m = bv;
    m = DPPMAX(m, 0x111); m = DPPMAX(m, 0x112); m = DPPMAX(m, 0x114);
    m = DPPMAX(m, 0x118); m = DPPMAX(m, 0x142); m = DPPMAX(m, 0x143);
    float wmax = __uint_as_float(__builtin_amdgcn_readlane(__float_as_uint(m), 63));
    unsigned long long msk = __ballot(bv == wmax);
    int srcLane = (int)__builtin_ctzll(msk);          // lowest lane == lowest index
    unsigned wbi = (unsigned)__builtin_amdgcn_readlane(bi, srcLane);
    if (lane == 0) { slotV[par][wid] = wmax; slotI[par][wid] = wbi; }
    __syncthreads();   // the only barrier per step
    // in-register 16-slot combine: lane l holds slot l&15 (broadcast reads)
    float sv = slotV[par][lane & 15];
    unsigned si = slotI[par][lane & 15];
    float g = sv;
    g = DPPMAX(g, 0x111); g = DPPMAX(g, 0x112); g = DPPMAX(g, 0x114);
    g = DPPMAX(g, 0x118);
    float gm = __uint_as_float(__builtin_amdgcn_readlane(__float_as_uint(g), 15));
    int l0 = (int)__builtin_ctzll(__ballot(sv == gm));  // lowest lane = lowest slot
    unsigned gi = (unsigned)__builtin_amdgcn_readlane((int)si, l0);
    if (tid == 0) cIdx[b * SGRP + step] = (int)gi;
    cx = xs[gi]; cy = ys[gi]; cz = zs[gi];   // LDS broadcast
  }
}

// ---------------- kNN v3: DPP value-only min reduce (replaces bpermute butterfly) ----
// Per iteration: in-thread cached min -> 6-level DPP prefix-min (identity +inf,
// pure VALU) -> ballot/ctz/readlane. Lane order != index order here (thread tid
// owns {tid, tid+256, ...}), so exact ties take a rare wave-uniform slow path
// scanning the ballot mask for the minimum index. Cross-wave combine stays the
// u64-key LDS atomicMin (1 atomic/wave + 1 barrier).
__global__ __launch_bounds__(256) void knn_kernel(const float* __restrict__ xyz,
                                                  const int* __restrict__ cIdx,
                                                  float* __restrict__ nbrDiff,
                                                  float* __restrict__ ctrW,
                                                  float* __restrict__ partials) {
  #pragma clang fp contract(off)
  __shared__ unsigned long long keyBuf[4];
  __shared__ int winners[KNBR];
  const int cid = blockIdx.x;
  const int b = cid >> 9;
  const int tid = threadIdx.x;
  const int lane = tid & 63;
  const float* xb = xyz + (size_t)b * NPTS * 3;
  const int cI = cIdx[cid];
  const float cx = xb[cI * 3], cy = xb[cI * 3 + 1], cz = xb[cI * 3 + 2];
  const float cs = (cx * cx + cy * cy) + cz * cz;

  float d2[32];
  float mv = __builtin_inff(); int mi = 0;
  #pragma unroll
  for (int j = 0; j < 32; ++j) {
    int p = tid + (j << 8);
    float x = xb[p * 3], y = xb[p * 3 + 1], z = xb[p * 3 + 2];
    float ps = (x * x + y * y) + z * z;
    float dot = (cx * x + cy * y) + cz * z;
    d2[j] = (cs + ps) - 2.0f * dot;
    if (d2[j] < mv) { mv = d2[j]; mi = p; }   // strict <: lowest p on tie
  }
  if (tid < 4) keyBuf[tid] = 0xFFFFFFFFFFFFFFFFull;
  __syncthreads();

  for (int it = 0; it < KNBR; ++it) {
    if (tid == 0) keyBuf[(it + 2) & 3] = 0xFFFFFFFFFFFFFFFFull;
    // wave min (value only) via DPP prefix-min; lane 63 holds the wave min
    float m = mv;
    m = DPPMIN(m, 0x111); m = DPPMIN(m, 0x112); m = DPPMIN(m, 0x114);
    m = DPPMIN(m, 0x118); m = DPPMIN(m, 0x142); m = DPPMIN(m, 0x143);
    float wmin = __uint_as_float(__builtin_amdgcn_readlane(__float_as_uint(m), 63));
    unsigned long long msk = __ballot(mv == wmin);
    int src = (int)__builtin_ctzll(msk);
    int wbi = __builtin_amdgcn_readlane(mi, src);
    if (__builtin_popcountll(msk) > 1) {      // rare exact-tie: min INDEX wins
      unsigned long long rest = msk & (msk - 1);
      while (rest) {
        int l = (int)__builtin_ctzll(rest);
        int cand = __builtin_amdgcn_readlane(mi, l);
        if (cand < wbi) wbi = cand;
        rest &= rest - 1;
      }
    }
    if (lane == 0) {
      unsigned u = __float_as_uint(wmin);
      unsigned mm = u ^ (unsigned)(((int)u >> 31) | 0x80000000);   // monotone float->uint
      unsigned long long key = (((unsigned long long)mm) << 32) | (unsigned long long)(unsigned)wbi;
      atomicMin(&keyBuf[it & 3], key);
    }
    __syncthreads();
    unsigned long long k = keyBuf[it & 3];
    int wi = (int)(k & 0x1FFFu);
    if (tid == 0) winners[it] = wi;
    if (tid == (wi & 255)) {     // only the owner rescans its 32 values
      #pragma unroll
      for (int j = 0; j < 32; ++j)
        if (wi == tid + (j << 8)) d2[j] = __builtin_inff();
      mv = __builtin_inff(); mi = 0;
      #pragma unroll
      for (int j = 0; j < 32; ++j)
        if (d2[j] < mv) { mv = d2[j]; mi = tid + (j << 8); }
    }
  }
  __syncthreads();

  // gather diffs + per-center stats partials
  float sum = 0.f, sq = 0.f;
  if (tid < KNBR) {
    int w = winners[tid];
    float dx = xb[w * 3] - cx, dy = xb[w * 3 + 1] - cy, dz = xb[w * 3 + 2] - cz;
    size_t o = ((size_t)cid * KNBR + tid) * 3;
    nbrDiff[o + 0] = dx; nbrDiff[o + 1] = dy; nbrDiff[o + 2] = dz;
    sum = (dx + dy) + dz;
    sq = (dx * dx + dy * dy) + dz * dz;
  }
  if (tid < 64) {
    #pragma unroll
    for (int s = 1; s < 64; s <<= 1) { sum += __shfl_xor(sum, s); sq += __shfl_xor(sq, s); }
    if (tid == 0) { partials[cid * 2] = sum; partials[cid * 2 + 1] = sq; }
  }
  if (tid < 3) ctrW[(size_t)cid * 3 + tid] = xb[cI * 3 + tid];
}

// ---------------- per-batch std (ddof=1), deterministic fp64 tree ----------------
__global__ __launch_bounds__(256) void std_kernel(const float* __restrict__ partials,
                                                  float* __restrict__ stdv) {
  __shared__ double sd[256], sq[256];
  const int b = blockIdx.x, t = threadIdx.x;
  int i0 = (b * 512 + t) * 2;
  sd[t] = (double)partials[i0] + (double)partials[i0 + 512];
  sq[t] = (double)partials[i0 + 1] + (double)partials[i0 + 513];
  for (int st = 128; st > 0; st >>= 1) {
    __syncthreads();
    if (t < st) { sd[t] += sd[t + st]; sq[t] += sq[t + st]; }
  }
  if (t == 0) {
    double n = (double)(SGRP * KNBR * 3);
    double mean = sd[0] / n;
    double var = (sq[0] - sd[0] * mean) / (n - 1.0);
    stdv[b] = (float)sqrt(var);
  }
}

// ---------------- fused group MLP (t-net + pre res_block + maxpool) ----------------
// one block = 4 groups (128 l-columns), 8 waves, MFMA 16x16x32 bf16
static __device__ __forceinline__ void gemm_half(const unsigned short* __restrict__ W,
                                                 const unsigned short* ht,
                                                 int oBase, int n0, int r16, int g4,
                                                 f32x4 acc[3][4]) {
  for (int ks = 0; ks < 12; ++ks) {
    const int kOff = ks * 32 + g4 * 8;
    bf16x8 a[3], bb[4];
    #pragma unroll
    for (int i = 0; i < 3; ++i)
      a[i] = *(const bf16x8*)(W + (size_t)(oBase + i * 16 + r16) * CCH + kOff);
    #pragma unroll
    for (int j = 0; j < 4; ++j)
      bb[j] = *(const bf16x8*)(ht + (n0 + j * 16 + r16) * LDSP + kOff);
    #pragma unroll
    for (int i = 0; i < 3; ++i) {
      #pragma unroll
      for (int j = 0; j < 4; ++j)
        acc[i][j] = __builtin_amdgcn_mfma_f32_16x16x32_bf16(a[i], bb[j], acc[i][j], 0, 0, 0);
    }
  }
}

__global__ __launch_bounds__(512) void group_mlp_kernel(
    const float* __restrict__ alpha, const float* __restrict__ beta,
    const float* __restrict__ WtF, const float* __restrict__ btF,
    const unsigned short* __restrict__ W1, const float* __restrict__ b1,
    const unsigned short* __restrict__ W2, const float* __restrict__ b2,
    const float* __restrict__ nbrDiff, const float* __restrict__ ctrW,
    const float* __restrict__ stdv, unsigned short* __restrict__ feat) {
  __shared__ unsigned short ht[128 * LDSP];
  __shared__ float xtw[128 * 8];
  __shared__ float wtl[CCH * 6];
  __shared__ float btl[CCH];

  const int tid = threadIdx.x;
  const int lane = tid & 63, wid = tid >> 6;
  const int r16 = lane & 15, g4 = lane >> 4;
  const int bid = blockIdx.x;
  const int b = bid >> 7;
  const int sBase = (bid & 127) << 2;

  for (int i = tid; i < CCH * 6; i += 512) wtl[i] = WtF[i];
  for (int i = tid; i < CCH; i += 512) btl[i] = btF[i];

  const float inv = 1.0f / (stdv[b] + 1e-5f);
  if (tid < 128) {
    int g = tid >> 5, kk = tid & 31;
    int cid = b * SGRP + sBase + g;
    const float* nb = nbrDiff + ((size_t)cid * KNBR + kk) * 3;
    const float* cc = ctrW + (size_t)cid * 3;
    #pragma unroll
    for (int c = 0; c < 3; ++c) {
      xtw[tid * 8 + c] = alpha[c] * (nb[c] * inv) + beta[c];
      xtw[tid * 8 + 3 + c] = cc[c];
    }
  }
  __syncthreads();

  // conv1 (t-net, K=6) -> h0 bf16 into ht[l][o]
  {
    int l = tid & 127, oi = tid >> 7;
    float xv[6];
    #pragma unroll
    for (int c = 0; c < 6; ++c) xv[c] = xtw[l * 8 + c];
    for (int j = 0; j < 96; ++j) {
      int o = oi * 96 + j;
      float v = btl[o];
      #pragma unroll
      for (int c = 0; c < 6; ++c) v += wtl[o * 6 + c] * xv[c];
      ht[l * LDSP + o] = f2b(fmaxf(v, 0.0f));
    }
  }
  __syncthreads();

  const int oBase = wid * 48;

  // conv2: h1 = relu(W1 h0 + b1), overwrite ht by l-halves (disjoint rows)
  for (int half = 0; half < 2; ++half) {
    const int n0 = half * 64;
    f32x4 acc[3][4];
    #pragma unroll
    for (int i = 0; i < 3; ++i) {
      #pragma unroll
      for (int j = 0; j < 4; ++j) acc[i][j] = (f32x4){0.f, 0.f, 0.f, 0.f};
    }
    gemm_half(W1, ht, oBase, n0, r16, g4, acc);
    __syncthreads();   // all waves done reading this half's h0 rows
    #pragma unroll
    for (int i = 0; i < 3; ++i) {
      int o4 = oBase + i * 16 + g4 * 4;
      float bs0 = b1[o4], bs1 = b1[o4 + 1], bs2 = b1[o4 + 2], bs3 = b1[o4 + 3];
      #pragma unroll
      for (int j = 0; j < 4; ++j) {
        int row = n0 + j * 16 + r16;
        unsigned u0 = pk2(fmaxf(acc[i][j][0] + bs0, 0.f), fmaxf(acc[i][j][1] + bs1, 0.f));
        unsigned u1 = pk2(fmaxf(acc[i][j][2] + bs2, 0.f), fmaxf(acc[i][j][3] + bs3, 0.f));
        *(uint2*)(ht + row * LDSP + o4) = make_uint2(u0, u1);
      }
    }
    __syncthreads();
  }

  // conv3 + bias + residual(h0 recomputed) + relu + maxpool over K=32
  for (int half = 0; half < 2; ++half) {
    const int n0 = half * 64;
    f32x4 acc[3][4];
    #pragma unroll
    for (int i = 0; i < 3; ++i) {
      #pragma unroll
      for (int j = 0; j < 4; ++j) acc[i][j] = (f32x4){0.f, 0.f, 0.f, 0.f};
    }
    gemm_half(W2, ht, oBase, n0, r16, g4, acc);

    float bias2[3][4];
    #pragma unroll
    for (int i = 0; i < 3; ++i) {
      int o4 = oBase + i * 16 + g4 * 4;
      #pragma unroll
      for (int r = 0; r < 4; ++r) bias2[i][r] = b2[o4 + r];
    }
    float mx[3][2][4];
    #pragma unroll
    for (int i = 0; i < 3; ++i) {
      #pragma unroll
      for (int gg = 0; gg < 2; ++gg) {
        #pragma unroll
        for (int r = 0; r < 4; ++r) mx[i][gg][r] = 0.f;   // values are relu'd (>=0)
      }
    }
    #pragma unroll
    for (int j = 0; j < 4; ++j) {
      int l = n0 + j * 16 + r16;
      float xv[6];
      #pragma unroll
      for (int c = 0; c < 6; ++c) xv[c] = xtw[l * 8 + c];
      #pragma unroll
      for (int i = 0; i < 3; ++i) {
        int o4 = oBase + i * 16 + g4 * 4;
        #pragma unroll
        for (int r = 0; r < 4; ++r) {
          float h0 = btl[o4 + r];
          #pragma unroll
          for (int c = 0; c < 6; ++c) h0 += wtl[(o4 + r) * 6 + c] * xv[c];
          h0 = fmaxf(h0, 0.f);
          float v = fmaxf(acc[i][j][r] + bias2[i][r] + h0, 0.f);
          mx[i][j >> 1][r] = fmaxf(mx[i][j >> 1][r], v);
        }
      }
    }
    #pragma unroll
    for (int i = 0; i < 3; ++i) {
      #pragma unroll
      for (int gg = 0; gg < 2; ++gg) {
        float m0 = mx[i][gg][0], m1 = mx[i][gg][1], m2 = mx[i][gg][2], m3 = mx[i][gg][3];
        #pragma unroll
        for (int s = 1; s < 16; s <<= 1) {
          m0 = fmaxf(m0, __shfl_xor(m0, s));
          m1 = fmaxf(m1, __shfl_xor(m1, s));
          m2 = fmaxf(m2, __shfl_xor(m2, s));
          m3 = fmaxf(m3, __shfl_xor(m3, s));
        }
        if (r16 == 0) {
          int sIdx = sBase + half * 2 + gg;
          size_t fi = ((size_t)(b * SGRP + sIdx)) * CCH + oBase + i * 16 + g4 * 4;
          *(uint2*)(feat + fi) = make_uint2(pk2(m0, m1), pk2(m2, m3));
        }
      }
    }
  }
}

// ---------------- pos res_block on feat (B,384,512) + final transpose to (B,S,C) fp32 ----------------
__global__ __launch_bounds__(256) void pos_kernel(const unsigned short* __restrict__ feat,
                                                  const unsigned short* __restrict__ Wp1,
                                                  const float* __restrict__ bp1,
                                                  const unsigned short* __restrict__ Wp2,
                                                  const float* __restrict__ bp2,
                                                  float* __restrict__ out) {
  __shared__ unsigned short h1[16 * LDSP];
  const int tid = threadIdx.x;
  const int lane = tid & 63, wid = tid >> 6;
  const int r16 = lane & 15, g4 = lane >> 4;
  const int bid = blockIdx.x;
  const int b = bid >> 5;
  const int s0 = (bid & 31) << 4;
  const size_t rowBase = ((size_t)(b * SGRP + s0 + r16)) * CCH;

  f32x4 acc[6];
  #pragma unroll
  for (int i = 0; i < 6; ++i) acc[i] = (f32x4){0.f, 0.f, 0.f, 0.f};
  for (int ks = 0; ks < 12; ++ks) {
    const int kOff = ks * 32 + g4 * 8;
    bf16x8 bfr = *(const bf16x8*)(feat + rowBase + kOff);
    #pragma unroll
    for (int i = 0; i < 6; ++i) {
      bf16x8 a = *(const bf16x8*)(Wp1 + (size_t)(wid * 96 + i * 16 + r16) * CCH + kOff);
      acc[i] = __builtin_amdgcn_mfma_f32_16x16x32_bf16(a, bfr, acc[i], 0, 0, 0);
    }
  }
  #pragma unroll
  for (int i = 0; i < 6; ++i) {
    int o4 = wid * 96 + i * 16 + g4 * 4;
    unsigned u0 = pk2(fmaxf(acc[i][0] + bp1[o4 + 0], 0.f), fmaxf(acc[i][1] + bp1[o4 + 1], 0.f));
    unsigned u1 = pk2(fmaxf(acc[i][2] + bp1[o4 + 2], 0.f), fmaxf(acc[i][3] + bp1[o4 + 3], 0.f));
    *(uint2*)(h1 + r16 * LDSP + o4) = make_uint2(u0, u1);
  }
  __syncthreads();

  f32x4 acc2[6];
  #pragma unroll
  for (int i = 0; i < 6; ++i) acc2[i] = (f32x4){0.f, 0.f, 0.f, 0.f};
  for (int ks = 0; ks < 12; ++ks) {
    const int kOff = ks * 32 + g4 * 8;
    bf16x8 bfr = *(const bf16x8*)(h1 + r16 * LDSP + kOff);
    #pragma unroll
    for (int i = 0; i < 6; ++i) {
      bf16x8 a = *(const bf16x8*)(Wp2 + (size_t)(wid * 96 + i * 16 + r16) * CCH + kOff);
      acc2[i] = __builtin_amdgcn_mfma_f32_16x16x32_bf16(a, bfr, acc2[i], 0, 0, 0);
    }
  }
  #pragma unroll
  for (int i = 0; i < 6; ++i) {
    int o4 = wid * 96 + i * 16 + g4 * 4;
    uint2 rr = *(const uint2*)(feat + rowBase + o4);
    float4 v;
    v.x = fmaxf(acc2[i][0] + bp2[o4 + 0] + b2f((unsigned short)(rr.x & 0xffff)), 0.f);
    v.y = fmaxf(acc2[i][1] + bp2[o4 + 1] + b2f((unsigned short)(rr.x >> 16)), 0.f);
    v.z = fmaxf(acc2[i][2] + bp2[o4 + 2] + b2f((unsigned short)(rr.y & 0xffff)), 0.f);
    v.w = fmaxf(acc2[i][3] + bp2[o4 + 3] + b2f((unsigned short)(rr.y >> 16)), 0.f);
    *(float4*)(out + rowBase + o4) = v;
  }
}

// ---------------- launch ----------------
extern "C" void kernel_launch(void* const* d_in, const int* in_sizes, int n_in,
                              void* d_out, int out_size, void* d_ws, size_t ws_size,
                              hipStream_t stream) {
  (void)in_sizes; (void)n_in; (void)out_size; (void)ws_size;
  const float* xyz   = (const float*)d_in[0];
  const float* alpha = (const float*)d_in[1];
  const float* beta  = (const float*)d_in[2];
  const float* Wt    = (const float*)d_in[3];
  const float* bt    = (const float*)d_in[4];
  const float* gt    = (const float*)d_in[5];
  const float* bbt   = (const float*)d_in[6];
  const float* Wpre1 = (const float*)d_in[7];
  const float* bpre1 = (const float*)d_in[8];
  const float* gpre1 = (const float*)d_in[9];
  const float* bbpre1= (const float*)d_in[10];
  const float* Wpre2 = (const float*)d_in[11];
  const float* bpre2 = (const float*)d_in[12];
  const float* gpre2 = (const float*)d_in[13];
  const float* bbpre2= (const float*)d_in[14];
  const float* Wpos1 = (const float*)d_in[15];
  const float* bpos1 = (const float*)d_in[16];
  const float* gpos1 = (const float*)d_in[17];
  const float* bbpos1= (const float*)d_in[18];
  const float* Wpos2 = (const float*)d_in[19];
  const float* bpos2 = (const float*)d_in[20];
  const float* gpos2 = (const float*)d_in[21];
  const float* bbpos2= (const float*)d_in[22];

  char* ws = (char*)d_ws;
  size_t off = 0;
  auto alloc = [&](size_t bytes) -> void* {
    void* p = ws + off;
    off += (bytes + 255) & ~(size_t)255;
    return p;
  };
  float* WtF = (float*)alloc(CCH * 6 * 4);
  float* btF = (float*)alloc(CCH * 4);
  unsigned short* W1 = (unsigned short*)alloc(CCH * CCH * 2);
  float* b1 = (float*)alloc(CCH * 4);
  unsigned short* W2 = (unsigned short*)alloc(CCH * CCH * 2);
  float* b2 = (float*)alloc(CCH * 4);
  unsigned short* Wp1 = (unsigned short*)alloc(CCH * CCH * 2);
  float* bp1 = (float*)alloc(CCH * 4);
  unsigned short* Wp2 = (unsigned short*)alloc(CCH * CCH * 2);
  float* bp2 = (float*)alloc(CCH * 4);
  int* cIdx = (int*)alloc(8 * SGRP * 4);
  float* ctrW = (float*)alloc(8 * SGRP * 3 * 4);
  float* nbrD = (float*)alloc((size_t)8 * SGRP * KNBR * 3 * 4);
  float* partials = (float*)alloc(8 * SGRP * 2 * 4);
  float* stdv = (float*)alloc(8 * 4);
  unsigned short* feat = (unsigned short*)alloc((size_t)8 * SGRP * CCH * 2);

  fold_w_f32<<<CCH, 64, 0, stream>>>(Wt, bt, gt, bbt, WtF, btF, 6);
  FoldArgs fa0{Wpre1, bpre1, gpre1, bbpre1, W1, b1};
  FoldArgs fa1{Wpre2, bpre2, gpre2, bbpre2, W2, b2};
  FoldArgs fa2{Wpos1, bpos1, gpos1, bbpos1, Wp1, bp1};
  FoldArgs fa3{Wpos2, bpos2, gpos2, bbpos2, Wp2, bp2};
  fold4_bf16<<<dim3(CCH, 4), 128, 0, stream>>>(fa0, fa1, fa2, fa3);

  fps_kernel<<<8, 1024, 0, stream>>>(xyz, cIdx);
  knn_kernel<<<8 * SGRP, 256, 0, stream>>>(xyz, cIdx, nbrD, ctrW, partials);
  std_kernel<<<8, 256, 0, stream>>>(partials, stdv);
  group_mlp_kernel<<<1024, 512, 0, stream>>>(alpha, beta, WtF, btF, W1, b1, W2, b2,
                                             nbrD, ctrW, stdv, feat);
  pos_kernel<<<256, 256, 0, stream>>>(feat, Wp1, bp1, Wp2, bp2, (float*)d_out);
}